// Round 1
// baseline (6058.640 us; speedup 1.0000x reference)
//
#include <hip/hip_runtime.h>
#include <math.h>

// Problem constants
constexpr int kB   = 2;
constexpr int kL   = 1024;
constexpr int kOBS = 64;
constexpr int kACT = 16;
constexpr int kC   = 1024;
constexpr int kH   = 16;
constexpr int kDH  = 64;
constexpr int kFF  = 4096;
constexpr int kNL  = 4;
constexpr int kRows = kB * kL;          // 2048
constexpr int kOE = 512, kAE = 256, kRE = 128, kTE = 128;

// ---------------------------------------------------------------------------
// 1. Transition batchnorm stats: tm[f], tv[f] over (B,L) for f in [0,64)
// ---------------------------------------------------------------------------
__global__ __launch_bounds__(256) void tran_stats_kernel(
    const float* __restrict__ obs, float* __restrict__ tm, float* __restrict__ tv)
{
    const int f = blockIdx.x;           // 64 blocks, one per feature
    const int tid = threadIdx.x;
    float sum = 0.f, sq = 0.f;
    for (int r = tid; r < kRows; r += 256) {
        const int t = r & (kL - 1);
        float d = 0.f;
        if (t > 0) {
            const float cur  = obs[(size_t)r * kOBS + f];
            const float prev = obs[(size_t)(r - 1) * kOBS + f];
            d = cur - prev;
        }
        sum += d; sq += d * d;
    }
    for (int off = 32; off > 0; off >>= 1) {
        sum += __shfl_down(sum, off);
        sq  += __shfl_down(sq, off);
    }
    __shared__ float sa[4], sb[4];
    if ((tid & 63) == 0) { sa[tid >> 6] = sum; sb[tid >> 6] = sq; }
    __syncthreads();
    if (tid == 0) {
        const float ts = sa[0] + sa[1] + sa[2] + sa[3];
        const float tq = sb[0] + sb[1] + sb[2] + sb[3];
        const float m = ts / (float)kRows;
        tm[f] = m;
        tv[f] = tq / (float)kRows - m * m;
    }
}

// ---------------------------------------------------------------------------
// 2. Encoder: enc[b,t,:] = concat(obs2@obsW+b, act@actW+b, rew@rewW+b, tran@trW+b)
// ---------------------------------------------------------------------------
__global__ __launch_bounds__(256) void encode_kernel(
    const float* __restrict__ obs, const float* __restrict__ act, const float* __restrict__ rew,
    const float* __restrict__ obs_W, const float* __restrict__ obs_b,
    const float* __restrict__ act_W, const float* __restrict__ act_b,
    const float* __restrict__ rew_W, const float* __restrict__ rew_b,
    const float* __restrict__ tr_W,  const float* __restrict__ tr_b,
    const float* __restrict__ bn_g,  const float* __restrict__ bn_b,
    const float* __restrict__ tm,    const float* __restrict__ tv,
    float* __restrict__ enc)
{
    const int row = blockIdx.x;          // b*L + t
    const int t = row & (kL - 1);
    const int tid = threadIdx.x;
    __shared__ float s_obs2[kOBS];
    __shared__ float s_tran[kOBS];
    __shared__ float s_act[kACT];
    __shared__ float s_rew;
    if (tid < kOBS) {
        const float cur  = obs[(size_t)row * kOBS + tid];
        const float prev = (t > 0) ? obs[(size_t)(row - 1) * kOBS + tid] : cur;
        s_obs2[tid] = prev;
        const float tr = cur - prev;     // t==0 -> 0
        s_tran[tid] = (tr - tm[tid]) * rsqrtf(tv[tid] + 1e-5f) * bn_g[tid] + bn_b[tid];
    } else if (tid < kOBS + kACT) {
        s_act[tid - kOBS] = act[(size_t)row * kACT + (tid - kOBS)];
    } else if (tid == kOBS + kACT) {
        s_rew = rew[row];
    }
    __syncthreads();
    float* er = enc + (size_t)row * kC;
    #pragma unroll
    for (int s = 0; s < 4; ++s) {
        const int c = tid + s * 256;
        float v;
        if (c < kOE) {
            v = obs_b[c];
            #pragma unroll
            for (int k = 0; k < kOBS; ++k) v += s_obs2[k] * obs_W[k * kOE + c];
        } else if (c < kOE + kAE) {
            const int cc = c - kOE;
            v = act_b[cc];
            #pragma unroll
            for (int k = 0; k < kACT; ++k) v += s_act[k] * act_W[k * kAE + cc];
        } else if (c < kOE + kAE + kRE) {
            const int cc = c - (kOE + kAE);
            v = s_rew * rew_W[cc] + rew_b[cc];
        } else {
            const int cc = c - (kOE + kAE + kRE);
            v = tr_b[cc];
            #pragma unroll
            for (int k = 0; k < kOBS; ++k) v += s_tran[k] * tr_W[k * kTE + cc];
        }
        er[c] = v;
    }
}

// ---------------------------------------------------------------------------
// 3. LayerNorm (one block per row, C=1024, 256 threads x float4)
// ---------------------------------------------------------------------------
__global__ __launch_bounds__(256) void ln_kernel(
    const float* __restrict__ x, const float* __restrict__ w,
    const float* __restrict__ b, float* __restrict__ out)
{
    const int row = blockIdx.x;
    const int tid = threadIdx.x;
    const float4 xv = *reinterpret_cast<const float4*>(&x[(size_t)row * kC + tid * 4]);
    float s = xv.x + xv.y + xv.z + xv.w;
    float q = xv.x * xv.x + xv.y * xv.y + xv.z * xv.z + xv.w * xv.w;
    for (int off = 32; off > 0; off >>= 1) {
        s += __shfl_down(s, off);
        q += __shfl_down(q, off);
    }
    __shared__ float sa[4], sb[4];
    if ((tid & 63) == 0) { sa[tid >> 6] = s; sb[tid >> 6] = q; }
    __syncthreads();
    const float ts = sa[0] + sa[1] + sa[2] + sa[3];
    const float tq = sb[0] + sb[1] + sb[2] + sb[3];
    const float mean = ts * (1.f / kC);
    const float var  = tq * (1.f / kC) - mean * mean;
    const float rstd = rsqrtf(var + 1e-5f);
    const float4 wv = *reinterpret_cast<const float4*>(&w[tid * 4]);
    const float4 bv = *reinterpret_cast<const float4*>(&b[tid * 4]);
    float4 ov;
    ov.x = (xv.x - mean) * rstd * wv.x + bv.x;
    ov.y = (xv.y - mean) * rstd * wv.y + bv.y;
    ov.z = (xv.z - mean) * rstd * wv.z + bv.z;
    ov.w = (xv.w - mean) * rstd * wv.w + bv.w;
    *reinterpret_cast<float4*>(&out[(size_t)row * kC + tid * 4]) = ov;
}

// ---------------------------------------------------------------------------
// 4. Tiled fp32 GEMM: C = [RES? C +] A(MxK) @ B(KxN) + bias, optional ReLU
//    64x64 tile, 256 threads, each thread 4x4.
// ---------------------------------------------------------------------------
template<bool RELU, bool RES>
__global__ __launch_bounds__(256) void gemm_kernel(
    const float* __restrict__ A, const float* __restrict__ B,
    const float* __restrict__ bias, float* __restrict__ C,
    int M, int N, int K)
{
    __shared__ float As[16][68];   // [k][m]
    __shared__ float Bs[16][68];   // [k][n]
    const int tid = threadIdx.x;
    const int tx = tid & 15;
    const int ty = tid >> 4;
    const int bm = blockIdx.y * 64;
    const int bn = blockIdx.x * 64;

    float acc[4][4] = {};
    for (int k0 = 0; k0 < K; k0 += 16) {
        {   // A tile: 64 rows x 16 k, float4 along k, scatter-store transposed
            const int row = tid >> 2;
            const int kq  = (tid & 3) * 4;
            const float4 a4 = *reinterpret_cast<const float4*>(&A[(size_t)(bm + row) * K + k0 + kq]);
            As[kq + 0][row] = a4.x;
            As[kq + 1][row] = a4.y;
            As[kq + 2][row] = a4.z;
            As[kq + 3][row] = a4.w;
        }
        {   // B tile: 16 k x 64 n, float4 along n
            const int kk = tid >> 4;
            const int c4 = (tid & 15) * 4;
            const float4 b4 = *reinterpret_cast<const float4*>(&B[(size_t)(k0 + kk) * N + bn + c4]);
            *reinterpret_cast<float4*>(&Bs[kk][c4]) = b4;
        }
        __syncthreads();
        #pragma unroll
        for (int kk = 0; kk < 16; ++kk) {
            const float4 a4 = *reinterpret_cast<const float4*>(&As[kk][ty * 4]);
            const float4 b4 = *reinterpret_cast<const float4*>(&Bs[kk][tx * 4]);
            const float av[4] = {a4.x, a4.y, a4.z, a4.w};
            const float bv[4] = {b4.x, b4.y, b4.z, b4.w};
            #pragma unroll
            for (int i = 0; i < 4; ++i)
                #pragma unroll
                for (int j = 0; j < 4; ++j)
                    acc[i][j] += av[i] * bv[j];
        }
        __syncthreads();
    }
    #pragma unroll
    for (int i = 0; i < 4; ++i) {
        const int row = bm + ty * 4 + i;
        const int colb = bn + tx * 4;
        float4 ov;
        float* o = &ov.x;
        #pragma unroll
        for (int j = 0; j < 4; ++j) {
            float v = acc[i][j] + bias[colb + j];
            if (RES) v += C[(size_t)row * N + colb + j];
            if (RELU) v = fmaxf(v, 0.f);
            o[j] = v;
        }
        *reinterpret_cast<float4*>(&C[(size_t)row * N + colb]) = ov;
    }
}

// ---------------------------------------------------------------------------
// 5. Fused causal attention (online softmax). One wave per (b,h,t).
//    qkv layout: [b*L+t][3C], q at h*64, k at C+h*64, v at 2C+h*64.
// ---------------------------------------------------------------------------
__global__ __launch_bounds__(64) void attn_kernel(
    const float* __restrict__ qkv, float* __restrict__ o)
{
    const int t = blockIdx.x;
    const int bh = blockIdx.y;
    const int b = bh >> 4;            // H = 16
    const int h = bh & 15;
    const int lane = threadIdx.x;
    const size_t rs = 3 * kC;

    __shared__ float q_s[kDH];
    __shared__ float Ks[kDH][kDH + 1];   // [d][key], pad 65 -> conflict-free
    __shared__ float p_s[kDH];

    q_s[lane] = qkv[((size_t)(b * kL + t)) * rs + h * kDH + lane] * 0.125f;
    __syncthreads();

    float m = -INFINITY, l = 0.f, oacc = 0.f;

    for (int k0 = 0; k0 <= t; k0 += 64) {
        {   // load K tile transposed into LDS: Ks[d][key]
            const int r0 = lane >> 4;
            const int c4 = (lane & 15) * 4;
            #pragma unroll
            for (int it = 0; it < 16; ++it) {
                const int row = it * 4 + r0;
                const float4 kv = *reinterpret_cast<const float4*>(
                    &qkv[((size_t)(b * kL + k0 + row)) * rs + kC + h * kDH + c4]);
                Ks[c4 + 0][row] = kv.x;
                Ks[c4 + 1][row] = kv.y;
                Ks[c4 + 2][row] = kv.z;
                Ks[c4 + 3][row] = kv.w;
            }
        }
        __syncthreads();
        const int kmax = min(64, t - k0 + 1);
        float s = -INFINITY;
        if (lane < kmax) {
            float a = 0.f;
            #pragma unroll
            for (int d = 0; d < kDH; ++d) a += q_s[d] * Ks[d][lane];
            s = a;
        }
        float tmax = s;
        for (int off = 32; off > 0; off >>= 1) tmax = fmaxf(tmax, __shfl_xor(tmax, off));
        const float mnew = fmaxf(m, tmax);
        const float fac = __expf(m - mnew);      // m=-inf first tile -> 0
        const float p = (lane < kmax) ? __expf(s - mnew) : 0.f;
        float ps = p;
        for (int off = 32; off > 0; off >>= 1) ps += __shfl_xor(ps, off);
        l = l * fac + ps;
        oacc *= fac;
        m = mnew;
        p_s[lane] = p;
        __syncthreads();
        const float* vb = &qkv[((size_t)(b * kL + k0)) * rs + 2 * kC + h * kDH + lane];
        for (int k = 0; k < kmax; ++k) oacc += p_s[k] * vb[(size_t)k * rs];
        __syncthreads();
    }
    o[((size_t)(b * kL + t)) * kC + h * kDH + lane] = oacc / l;
}

// ---------------------------------------------------------------------------
// 6. Final tanh (in place on d_out)
// ---------------------------------------------------------------------------
__global__ __launch_bounds__(256) void tanh_kernel(float* __restrict__ x)
{
    const size_t i = ((size_t)blockIdx.x * 256 + threadIdx.x) * 4;
    float4 v = *reinterpret_cast<float4*>(&x[i]);
    v.x = tanhf(v.x); v.y = tanhf(v.y); v.z = tanhf(v.z); v.w = tanhf(v.w);
    *reinterpret_cast<float4*>(&x[i]) = v;
}

// ---------------------------------------------------------------------------
extern "C" void kernel_launch(void* const* d_in, const int* in_sizes, int n_in,
                              void* d_out, int out_size, void* d_ws, size_t ws_size,
                              hipStream_t stream)
{
    (void)in_sizes; (void)n_in; (void)out_size; (void)ws_size;
    const float* obs    = (const float*)d_in[0];
    const float* act    = (const float*)d_in[1];
    const float* rew    = (const float*)d_in[2];
    const float* obs_W  = (const float*)d_in[3];
    const float* obs_b  = (const float*)d_in[4];
    const float* act_W  = (const float*)d_in[5];
    const float* act_b  = (const float*)d_in[6];
    const float* rew_W  = (const float*)d_in[7];
    const float* rew_b  = (const float*)d_in[8];
    const float* tr_W   = (const float*)d_in[9];
    const float* tr_b   = (const float*)d_in[10];
    const float* bn_g   = (const float*)d_in[11];
    const float* bn_b   = (const float*)d_in[12];
    const float* ln1_w  = (const float*)d_in[13];
    const float* ln1_b  = (const float*)d_in[14];
    const float* qkv_W  = (const float*)d_in[15];
    const float* qkv_b  = (const float*)d_in[16];
    const float* out_W  = (const float*)d_in[17];
    const float* out_b  = (const float*)d_in[18];
    const float* ln2_w  = (const float*)d_in[19];
    const float* ln2_b  = (const float*)d_in[20];
    const float* fc_W   = (const float*)d_in[21];
    const float* fc_b   = (const float*)d_in[22];
    const float* pj_W   = (const float*)d_in[23];
    const float* pj_b   = (const float*)d_in[24];

    float* x   = (float*)d_out;                    // residual stream lives in d_out
    float* ws  = (float*)d_ws;
    float* tm  = ws;                               // 64
    float* tv  = ws + 64;                          // 64
    float* h   = ws + 128;                         // 2048*1024
    float* qkv = h + (size_t)kRows * kC;           // 2048*3072
    float* ao  = qkv + (size_t)kRows * 3 * kC;     // 2048*1024
    float* ff  = ao + (size_t)kRows * kC;          // 2048*4096

    tran_stats_kernel<<<kOBS, 256, 0, stream>>>(obs, tm, tv);
    encode_kernel<<<kRows, 256, 0, stream>>>(obs, act, rew,
        obs_W, obs_b, act_W, act_b, rew_W, rew_b, tr_W, tr_b, bn_g, bn_b, tm, tv, x);

    for (int lyr = 0; lyr < kNL; ++lyr) {
        const float* qW = qkv_W + (size_t)lyr * kC * 3 * kC;
        const float* qB = qkv_b + (size_t)lyr * 3 * kC;
        const float* oW = out_W + (size_t)lyr * kC * kC;
        const float* oB = out_b + (size_t)lyr * kC;
        const float* fW = fc_W + (size_t)lyr * kC * kFF;
        const float* fB = fc_b + (size_t)lyr * kFF;
        const float* pW = pj_W + (size_t)lyr * kFF * kC;
        const float* pB = pj_b + (size_t)lyr * kC;

        ln_kernel<<<kRows, 256, 0, stream>>>(x, ln1_w + lyr * kC, ln1_b + lyr * kC, h);
        gemm_kernel<false, false><<<dim3(3 * kC / 64, kRows / 64), 256, 0, stream>>>(
            h, qW, qB, qkv, kRows, 3 * kC, kC);
        attn_kernel<<<dim3(kL, kB * kH), 64, 0, stream>>>(qkv, ao);
        gemm_kernel<false, true><<<dim3(kC / 64, kRows / 64), 256, 0, stream>>>(
            ao, oW, oB, x, kRows, kC, kC);
        ln_kernel<<<kRows, 256, 0, stream>>>(x, ln2_w + lyr * kC, ln2_b + lyr * kC, h);
        gemm_kernel<true, false><<<dim3(kFF / 64, kRows / 64), 256, 0, stream>>>(
            h, fW, fB, ff, kRows, kFF, kC);
        gemm_kernel<false, true><<<dim3(kC / 64, kRows / 64), 256, 0, stream>>>(
            ff, pW, pB, x, kRows, kC, kFF);
    }
    tanh_kernel<<<kRows * kC / 1024, 256, 0, stream>>>(x);
}

// Round 2
// 4290.694 us; speedup vs baseline: 1.4120x; 1.4120x over previous
//
#include <hip/hip_runtime.h>
#include <math.h>

// Problem constants
constexpr int kB   = 2;
constexpr int kL   = 1024;
constexpr int kOBS = 64;
constexpr int kACT = 16;
constexpr int kC   = 1024;
constexpr int kH   = 16;
constexpr int kDH  = 64;
constexpr int kFF  = 4096;
constexpr int kNL  = 4;
constexpr int kRows = kB * kL;          // 2048
constexpr int kOE = 512, kAE = 256, kRE = 128, kTE = 128;

// ---------------------------------------------------------------------------
// 1. Transition batchnorm stats: tm[f], tv[f] over (B,L) for f in [0,64)
// ---------------------------------------------------------------------------
__global__ __launch_bounds__(256) void tran_stats_kernel(
    const float* __restrict__ obs, float* __restrict__ tm, float* __restrict__ tv)
{
    const int f = blockIdx.x;           // 64 blocks, one per feature
    const int tid = threadIdx.x;
    float sum = 0.f, sq = 0.f;
    for (int r = tid; r < kRows; r += 256) {
        const int t = r & (kL - 1);
        float d = 0.f;
        if (t > 0) {
            const float cur  = obs[(size_t)r * kOBS + f];
            const float prev = obs[(size_t)(r - 1) * kOBS + f];
            d = cur - prev;
        }
        sum += d; sq += d * d;
    }
    for (int off = 32; off > 0; off >>= 1) {
        sum += __shfl_down(sum, off);
        sq  += __shfl_down(sq, off);
    }
    __shared__ float sa[4], sb[4];
    if ((tid & 63) == 0) { sa[tid >> 6] = sum; sb[tid >> 6] = sq; }
    __syncthreads();
    if (tid == 0) {
        const float ts = sa[0] + sa[1] + sa[2] + sa[3];
        const float tq = sb[0] + sb[1] + sb[2] + sb[3];
        const float m = ts / (float)kRows;
        tm[f] = m;
        tv[f] = tq / (float)kRows - m * m;
    }
}

// ---------------------------------------------------------------------------
// 2. Encoder
// ---------------------------------------------------------------------------
__global__ __launch_bounds__(256) void encode_kernel(
    const float* __restrict__ obs, const float* __restrict__ act, const float* __restrict__ rew,
    const float* __restrict__ obs_W, const float* __restrict__ obs_b,
    const float* __restrict__ act_W, const float* __restrict__ act_b,
    const float* __restrict__ rew_W, const float* __restrict__ rew_b,
    const float* __restrict__ tr_W,  const float* __restrict__ tr_b,
    const float* __restrict__ bn_g,  const float* __restrict__ bn_b,
    const float* __restrict__ tm,    const float* __restrict__ tv,
    float* __restrict__ enc)
{
    const int row = blockIdx.x;          // b*L + t
    const int t = row & (kL - 1);
    const int tid = threadIdx.x;
    __shared__ float s_obs2[kOBS];
    __shared__ float s_tran[kOBS];
    __shared__ float s_act[kACT];
    __shared__ float s_rew;
    if (tid < kOBS) {
        const float cur  = obs[(size_t)row * kOBS + tid];
        const float prev = (t > 0) ? obs[(size_t)(row - 1) * kOBS + tid] : cur;
        s_obs2[tid] = prev;
        const float tr = cur - prev;     // t==0 -> 0
        s_tran[tid] = (tr - tm[tid]) * rsqrtf(tv[tid] + 1e-5f) * bn_g[tid] + bn_b[tid];
    } else if (tid < kOBS + kACT) {
        s_act[tid - kOBS] = act[(size_t)row * kACT + (tid - kOBS)];
    } else if (tid == kOBS + kACT) {
        s_rew = rew[row];
    }
    __syncthreads();
    float* er = enc + (size_t)row * kC;
    #pragma unroll
    for (int s = 0; s < 4; ++s) {
        const int c = tid + s * 256;
        float v;
        if (c < kOE) {
            v = obs_b[c];
            #pragma unroll
            for (int k = 0; k < kOBS; ++k) v += s_obs2[k] * obs_W[k * kOE + c];
        } else if (c < kOE + kAE) {
            const int cc = c - kOE;
            v = act_b[cc];
            #pragma unroll
            for (int k = 0; k < kACT; ++k) v += s_act[k] * act_W[k * kAE + cc];
        } else if (c < kOE + kAE + kRE) {
            const int cc = c - (kOE + kAE);
            v = s_rew * rew_W[cc] + rew_b[cc];
        } else {
            const int cc = c - (kOE + kAE + kRE);
            v = tr_b[cc];
            #pragma unroll
            for (int k = 0; k < kOBS; ++k) v += s_tran[k] * tr_W[k * kTE + cc];
        }
        er[c] = v;
    }
}

// ---------------------------------------------------------------------------
// 3. LayerNorm
// ---------------------------------------------------------------------------
__global__ __launch_bounds__(256) void ln_kernel(
    const float* __restrict__ x, const float* __restrict__ w,
    const float* __restrict__ b, float* __restrict__ out)
{
    const int row = blockIdx.x;
    const int tid = threadIdx.x;
    const float4 xv = *reinterpret_cast<const float4*>(&x[(size_t)row * kC + tid * 4]);
    float s = xv.x + xv.y + xv.z + xv.w;
    float q = xv.x * xv.x + xv.y * xv.y + xv.z * xv.z + xv.w * xv.w;
    for (int off = 32; off > 0; off >>= 1) {
        s += __shfl_down(s, off);
        q += __shfl_down(q, off);
    }
    __shared__ float sa[4], sb[4];
    if ((tid & 63) == 0) { sa[tid >> 6] = s; sb[tid >> 6] = q; }
    __syncthreads();
    const float ts = sa[0] + sa[1] + sa[2] + sa[3];
    const float tq = sb[0] + sb[1] + sb[2] + sb[3];
    const float mean = ts * (1.f / kC);
    const float var  = tq * (1.f / kC) - mean * mean;
    const float rstd = rsqrtf(var + 1e-5f);
    const float4 wv = *reinterpret_cast<const float4*>(&w[tid * 4]);
    const float4 bv = *reinterpret_cast<const float4*>(&b[tid * 4]);
    float4 ov;
    ov.x = (xv.x - mean) * rstd * wv.x + bv.x;
    ov.y = (xv.y - mean) * rstd * wv.y + bv.y;
    ov.z = (xv.z - mean) * rstd * wv.z + bv.z;
    ov.w = (xv.w - mean) * rstd * wv.w + bv.w;
    *reinterpret_cast<float4*>(&out[(size_t)row * kC + tid * 4]) = ov;
}

// ---------------------------------------------------------------------------
// 4. Tiled fp32 GEMM (unchanged this round)
// ---------------------------------------------------------------------------
template<bool RELU, bool RES>
__global__ __launch_bounds__(256) void gemm_kernel(
    const float* __restrict__ A, const float* __restrict__ B,
    const float* __restrict__ bias, float* __restrict__ C,
    int M, int N, int K)
{
    __shared__ float As[16][68];   // [k][m]
    __shared__ float Bs[16][68];   // [k][n]
    const int tid = threadIdx.x;
    const int tx = tid & 15;
    const int ty = tid >> 4;
    const int bm = blockIdx.y * 64;
    const int bn = blockIdx.x * 64;

    float acc[4][4] = {};
    for (int k0 = 0; k0 < K; k0 += 16) {
        {
            const int row = tid >> 2;
            const int kq  = (tid & 3) * 4;
            const float4 a4 = *reinterpret_cast<const float4*>(&A[(size_t)(bm + row) * K + k0 + kq]);
            As[kq + 0][row] = a4.x;
            As[kq + 1][row] = a4.y;
            As[kq + 2][row] = a4.z;
            As[kq + 3][row] = a4.w;
        }
        {
            const int kk = tid >> 4;
            const int c4 = (tid & 15) * 4;
            const float4 b4 = *reinterpret_cast<const float4*>(&B[(size_t)(k0 + kk) * N + bn + c4]);
            *reinterpret_cast<float4*>(&Bs[kk][c4]) = b4;
        }
        __syncthreads();
        #pragma unroll
        for (int kk = 0; kk < 16; ++kk) {
            const float4 a4 = *reinterpret_cast<const float4*>(&As[kk][ty * 4]);
            const float4 b4 = *reinterpret_cast<const float4*>(&Bs[kk][tx * 4]);
            const float av[4] = {a4.x, a4.y, a4.z, a4.w};
            const float bv[4] = {b4.x, b4.y, b4.z, b4.w};
            #pragma unroll
            for (int i = 0; i < 4; ++i)
                #pragma unroll
                for (int j = 0; j < 4; ++j)
                    acc[i][j] += av[i] * bv[j];
        }
        __syncthreads();
    }
    #pragma unroll
    for (int i = 0; i < 4; ++i) {
        const int row = bm + ty * 4 + i;
        const int colb = bn + tx * 4;
        float4 ov;
        float* o = &ov.x;
        #pragma unroll
        for (int j = 0; j < 4; ++j) {
            float v = acc[i][j] + bias[colb + j];
            if (RES) v += C[(size_t)row * N + colb + j];
            if (RELU) v = fmaxf(v, 0.f);
            o[j] = v;
        }
        *reinterpret_cast<float4*>(&C[(size_t)row * N + colb]) = ov;
    }
}

// ---------------------------------------------------------------------------
// 5. Flash attention: 64-query tile per block, 256 threads = 4 waves.
//    Wave wv owns 16 complete S-rows (q = wv*16..wv*16+15); lane = key col.
//    K tile -> per-lane registers; Q, V, P staged in LDS.
//    qkv layout: [b*L+t][3C], q at h*64, k at C+h*64, v at 2C+h*64.
// ---------------------------------------------------------------------------
__global__ __launch_bounds__(256) void attn_kernel(
    const float* __restrict__ qkv, float* __restrict__ o)
{
    const int bid = blockIdx.x;            // 512 blocks
    const int bh  = bid & 31;
    const int qb  = ((bid >> 5) + bh) & 15;   // shear: balance tile counts
    const int b   = bh >> 4;               // H = 16
    const int h   = bh & 15;
    const int tid  = threadIdx.x;
    const int lane = tid & 63;             // key column within tile
    const int wv   = tid >> 6;             // wave id: q rows wv*16..+15

    __shared__ float Qs[64][68];           // [q][d]   (pad 68: 16B-aligned rows)
    __shared__ float Vs[64][68];           // [k][d]   read Vs[k][lane]: conflict-free
    __shared__ float Ps[64][68];           // [k][q]   read broadcast in PV

    const size_t rs = 3 * kC;
    const int qlo = qb * 64;
    const size_t qbase = (size_t)(b * kL + qlo) * rs + h * kDH;

    // stage Q tile, pre-scaled by 1/sqrt(DH)
    #pragma unroll
    for (int s = 0; s < 4; ++s) {
        const int i = tid + s * 256;
        const int r = i >> 4, c = (i & 15) * 4;
        const float4 v = *reinterpret_cast<const float4*>(&qkv[qbase + (size_t)r * rs + c]);
        Qs[r][c + 0] = v.x * 0.125f;
        Qs[r][c + 1] = v.y * 0.125f;
        Qs[r][c + 2] = v.z * 0.125f;
        Qs[r][c + 3] = v.w * 0.125f;
    }

    float m[16], l[16], oa[16];
    #pragma unroll
    for (int i = 0; i < 16; ++i) { m[i] = -INFINITY; l[i] = 0.f; oa[i] = 0.f; }

    for (int k0 = 0; k0 <= qlo; k0 += 64) {
        __syncthreads();   // prev iteration's PV reads of Vs/Ps complete; Qs visible (iter 0)

        // stage V tile (coalesced)
        const size_t kvbase = (size_t)(b * kL + k0) * rs + h * kDH;
        #pragma unroll
        for (int s = 0; s < 4; ++s) {
            const int i = tid + s * 256;
            const int r = i >> 4, c = (i & 15) * 4;
            *reinterpret_cast<float4*>(&Vs[r][c]) =
                *reinterpret_cast<const float4*>(&qkv[kvbase + (size_t)r * rs + 2 * kC + c]);
        }
        // K row for this lane -> registers (L1/L2-served; reused by 16 q rows)
        const float* kptr = &qkv[kvbase + (size_t)lane * rs + kC];

        float acc[16];
        #pragma unroll
        for (int qq = 0; qq < 16; ++qq) acc[qq] = 0.f;

        __syncthreads();   // Vs ready (and Qs on iter 0)

        // S = Q K^T : acc[qq] = dot(Q[wv*16+qq][:], K[lane][:])
        #pragma unroll
        for (int j = 0; j < 16; ++j) {
            const float4 k4 = *reinterpret_cast<const float4*>(&kptr[j * 4]);
            #pragma unroll
            for (int qq = 0; qq < 16; ++qq) {
                const float4 q4 = *reinterpret_cast<const float4*>(&Qs[wv * 16 + qq][j * 4]);
                acc[qq] += q4.x * k4.x + q4.y * k4.y + q4.z * k4.z + q4.w * k4.w;
            }
        }

        const bool diag = (k0 == qlo);
        // online softmax, wave-local per row
        #pragma unroll
        for (int qq = 0; qq < 16; ++qq) {
            float s = acc[qq];
            if (diag && lane > wv * 16 + qq) s = -INFINITY;
            float mx = s;
            #pragma unroll
            for (int off = 32; off > 0; off >>= 1) mx = fmaxf(mx, __shfl_xor(mx, off));
            const float mn  = fmaxf(m[qq], mx);
            const float fac = __expf(m[qq] - mn);
            const float p   = __expf(s - mn);
            float ps = p;
            #pragma unroll
            for (int off = 32; off > 0; off >>= 1) ps += __shfl_xor(ps, off);
            l[qq]  = l[qq] * fac + ps;
            oa[qq] *= fac;
            m[qq]  = mn;
            Ps[lane][wv * 16 + qq] = p;
        }

        __syncthreads();   // Ps ready

        // PV: oa[qq] += sum_k Ps[k][wv*16+qq] * Vs[k][lane]
        #pragma unroll
        for (int k = 0; k < 64; ++k) {
            const float vk = Vs[k][lane];
            const float4 p0 = *reinterpret_cast<const float4*>(&Ps[k][wv * 16 + 0]);
            const float4 p1 = *reinterpret_cast<const float4*>(&Ps[k][wv * 16 + 4]);
            const float4 p2 = *reinterpret_cast<const float4*>(&Ps[k][wv * 16 + 8]);
            const float4 p3 = *reinterpret_cast<const float4*>(&Ps[k][wv * 16 + 12]);
            oa[0]  += p0.x * vk; oa[1]  += p0.y * vk; oa[2]  += p0.z * vk; oa[3]  += p0.w * vk;
            oa[4]  += p1.x * vk; oa[5]  += p1.y * vk; oa[6]  += p1.z * vk; oa[7]  += p1.w * vk;
            oa[8]  += p2.x * vk; oa[9]  += p2.y * vk; oa[10] += p2.z * vk; oa[11] += p2.w * vk;
            oa[12] += p3.x * vk; oa[13] += p3.y * vk; oa[14] += p3.z * vk; oa[15] += p3.w * vk;
        }
    }

    // epilogue: out[q][d] = oa[q] / l[q]
    #pragma unroll
    for (int qq = 0; qq < 16; ++qq) {
        const float rl = 1.f / l[qq];
        o[((size_t)(b * kL + qlo + wv * 16 + qq)) * kC + h * kDH + lane] = oa[qq] * rl;
    }
}

// ---------------------------------------------------------------------------
// 6. Final tanh (in place on d_out)
// ---------------------------------------------------------------------------
__global__ __launch_bounds__(256) void tanh_kernel(float* __restrict__ x)
{
    const size_t i = ((size_t)blockIdx.x * 256 + threadIdx.x) * 4;
    float4 v = *reinterpret_cast<float4*>(&x[i]);
    v.x = tanhf(v.x); v.y = tanhf(v.y); v.z = tanhf(v.z); v.w = tanhf(v.w);
    *reinterpret_cast<float4*>(&x[i]) = v;
}

// ---------------------------------------------------------------------------
extern "C" void kernel_launch(void* const* d_in, const int* in_sizes, int n_in,
                              void* d_out, int out_size, void* d_ws, size_t ws_size,
                              hipStream_t stream)
{
    (void)in_sizes; (void)n_in; (void)out_size; (void)ws_size;
    const float* obs    = (const float*)d_in[0];
    const float* act    = (const float*)d_in[1];
    const float* rew    = (const float*)d_in[2];
    const float* obs_W  = (const float*)d_in[3];
    const float* obs_b  = (const float*)d_in[4];
    const float* act_W  = (const float*)d_in[5];
    const float* act_b  = (const float*)d_in[6];
    const float* rew_W  = (const float*)d_in[7];
    const float* rew_b  = (const float*)d_in[8];
    const float* tr_W   = (const float*)d_in[9];
    const float* tr_b   = (const float*)d_in[10];
    const float* bn_g   = (const float*)d_in[11];
    const float* bn_b   = (const float*)d_in[12];
    const float* ln1_w  = (const float*)d_in[13];
    const float* ln1_b  = (const float*)d_in[14];
    const float* qkv_W  = (const float*)d_in[15];
    const float* qkv_b  = (const float*)d_in[16];
    const float* out_W  = (const float*)d_in[17];
    const float* out_b  = (const float*)d_in[18];
    const float* ln2_w  = (const float*)d_in[19];
    const float* ln2_b  = (const float*)d_in[20];
    const float* fc_W   = (const float*)d_in[21];
    const float* fc_b   = (const float*)d_in[22];
    const float* pj_W   = (const float*)d_in[23];
    const float* pj_b   = (const float*)d_in[24];

    float* x   = (float*)d_out;                    // residual stream lives in d_out
    float* ws  = (float*)d_ws;
    float* tm  = ws;                               // 64
    float* tv  = ws + 64;                          // 64
    float* h   = ws + 128;                         // 2048*1024
    float* qkv = h + (size_t)kRows * kC;           // 2048*3072
    float* ao  = qkv + (size_t)kRows * 3 * kC;     // 2048*1024
    float* ff  = ao + (size_t)kRows * kC;          // 2048*4096

    tran_stats_kernel<<<kOBS, 256, 0, stream>>>(obs, tm, tv);
    encode_kernel<<<kRows, 256, 0, stream>>>(obs, act, rew,
        obs_W, obs_b, act_W, act_b, rew_W, rew_b, tr_W, tr_b, bn_g, bn_b, tm, tv, x);

    for (int lyr = 0; lyr < kNL; ++lyr) {
        const float* qW = qkv_W + (size_t)lyr * kC * 3 * kC;
        const float* qB = qkv_b + (size_t)lyr * 3 * kC;
        const float* oW = out_W + (size_t)lyr * kC * kC;
        const float* oB = out_b + (size_t)lyr * kC;
        const float* fW = fc_W + (size_t)lyr * kC * kFF;
        const float* fB = fc_b + (size_t)lyr * kFF;
        const float* pW = pj_W + (size_t)lyr * kFF * kC;
        const float* pB = pj_b + (size_t)lyr * kC;

        ln_kernel<<<kRows, 256, 0, stream>>>(x, ln1_w + lyr * kC, ln1_b + lyr * kC, h);
        gemm_kernel<false, false><<<dim3(3 * kC / 64, kRows / 64), 256, 0, stream>>>(
            h, qW, qB, qkv, kRows, 3 * kC, kC);
        attn_kernel<<<dim3(512), 256, 0, stream>>>(qkv, ao);
        gemm_kernel<false, true><<<dim3(kC / 64, kRows / 64), 256, 0, stream>>>(
            ao, oW, oB, x, kRows, kC, kC);
        ln_kernel<<<kRows, 256, 0, stream>>>(x, ln2_w + lyr * kC, ln2_b + lyr * kC, h);
        gemm_kernel<true, false><<<dim3(kFF / 64, kRows / 64), 256, 0, stream>>>(
            h, fW, fB, ff, kRows, kFF, kC);
        gemm_kernel<false, true><<<dim3(kC / 64, kRows / 64), 256, 0, stream>>>(
            ff, pW, pB, x, kRows, kC, kFF);
    }
    tanh_kernel<<<kRows * kC / 1024, 256, 0, stream>>>(x);
}

// Round 4
// 2087.926 us; speedup vs baseline: 2.9018x; 2.0550x over previous
//
#include <hip/hip_runtime.h>
#include <hip/hip_bf16.h>
#include <math.h>

// Problem constants
constexpr int kB   = 2;
constexpr int kL   = 1024;
constexpr int kOBS = 64;
constexpr int kACT = 16;
constexpr int kC   = 1024;
constexpr int kH   = 16;
constexpr int kDH  = 64;
constexpr int kFF  = 4096;
constexpr int kNL  = 4;
constexpr int kRows = kB * kL;          // 2048
constexpr int kOE = 512, kAE = 256, kRE = 128, kTE = 128;

typedef _Float16 f16x8 __attribute__((ext_vector_type(8)));
typedef float    f32x4 __attribute__((ext_vector_type(4)));

__device__ __forceinline__ unsigned short f2h(float x) {
    return __builtin_bit_cast(unsigned short, (_Float16)x);
}
__device__ __forceinline__ void gload_lds16(const void* g, void* l) {
    __builtin_amdgcn_global_load_lds(
        (const __attribute__((address_space(1))) unsigned int*)g,
        (__attribute__((address_space(3))) unsigned int*)l, 16, 0, 0);
}

// ---------------------------------------------------------------------------
// 1. Transition batchnorm stats
// ---------------------------------------------------------------------------
__global__ __launch_bounds__(256) void tran_stats_kernel(
    const float* __restrict__ obs, float* __restrict__ tm, float* __restrict__ tv)
{
    const int f = blockIdx.x;
    const int tid = threadIdx.x;
    float sum = 0.f, sq = 0.f;
    for (int r = tid; r < kRows; r += 256) {
        const int t = r & (kL - 1);
        float d = 0.f;
        if (t > 0) {
            const float cur  = obs[(size_t)r * kOBS + f];
            const float prev = obs[(size_t)(r - 1) * kOBS + f];
            d = cur - prev;
        }
        sum += d; sq += d * d;
    }
    for (int off = 32; off > 0; off >>= 1) {
        sum += __shfl_down(sum, off);
        sq  += __shfl_down(sq, off);
    }
    __shared__ float sa[4], sb[4];
    if ((tid & 63) == 0) { sa[tid >> 6] = sum; sb[tid >> 6] = sq; }
    __syncthreads();
    if (tid == 0) {
        const float ts = sa[0] + sa[1] + sa[2] + sa[3];
        const float tq = sb[0] + sb[1] + sb[2] + sb[3];
        const float m = ts / (float)kRows;
        tm[f] = m;
        tv[f] = tq / (float)kRows - m * m;
    }
}

// ---------------------------------------------------------------------------
// 2. Encoder (writes fp32 residual stream)
// ---------------------------------------------------------------------------
__global__ __launch_bounds__(256) void encode_kernel(
    const float* __restrict__ obs, const float* __restrict__ act, const float* __restrict__ rew,
    const float* __restrict__ obs_W, const float* __restrict__ obs_b,
    const float* __restrict__ act_W, const float* __restrict__ act_b,
    const float* __restrict__ rew_W, const float* __restrict__ rew_b,
    const float* __restrict__ tr_W,  const float* __restrict__ tr_b,
    const float* __restrict__ bn_g,  const float* __restrict__ bn_b,
    const float* __restrict__ tm,    const float* __restrict__ tv,
    float* __restrict__ enc)
{
    const int row = blockIdx.x;
    const int t = row & (kL - 1);
    const int tid = threadIdx.x;
    __shared__ float s_obs2[kOBS];
    __shared__ float s_tran[kOBS];
    __shared__ float s_act[kACT];
    __shared__ float s_rew;
    if (tid < kOBS) {
        const float cur  = obs[(size_t)row * kOBS + tid];
        const float prev = (t > 0) ? obs[(size_t)(row - 1) * kOBS + tid] : cur;
        s_obs2[tid] = prev;
        const float tr = cur - prev;
        s_tran[tid] = (tr - tm[tid]) * rsqrtf(tv[tid] + 1e-5f) * bn_g[tid] + bn_b[tid];
    } else if (tid < kOBS + kACT) {
        s_act[tid - kOBS] = act[(size_t)row * kACT + (tid - kOBS)];
    } else if (tid == kOBS + kACT) {
        s_rew = rew[row];
    }
    __syncthreads();
    float* er = enc + (size_t)row * kC;
    #pragma unroll
    for (int s = 0; s < 4; ++s) {
        const int c = tid + s * 256;
        float v;
        if (c < kOE) {
            v = obs_b[c];
            #pragma unroll
            for (int k = 0; k < kOBS; ++k) v += s_obs2[k] * obs_W[k * kOE + c];
        } else if (c < kOE + kAE) {
            const int cc = c - kOE;
            v = act_b[cc];
            #pragma unroll
            for (int k = 0; k < kACT; ++k) v += s_act[k] * act_W[k * kAE + cc];
        } else if (c < kOE + kAE + kRE) {
            const int cc = c - (kOE + kAE);
            v = s_rew * rew_W[cc] + rew_b[cc];
        } else {
            const int cc = c - (kOE + kAE + kRE);
            v = tr_b[cc];
            #pragma unroll
            for (int k = 0; k < kOBS; ++k) v += s_tran[k] * tr_W[k * kTE + cc];
        }
        er[c] = v;
    }
}

// ---------------------------------------------------------------------------
// 3. LayerNorm: fp32 in -> fp16 out
// ---------------------------------------------------------------------------
__global__ __launch_bounds__(256) void ln_kernel(
    const float* __restrict__ x, const float* __restrict__ w,
    const float* __restrict__ b, unsigned short* __restrict__ out)
{
    const int row = blockIdx.x;
    const int tid = threadIdx.x;
    const float4 xv = *reinterpret_cast<const float4*>(&x[(size_t)row * kC + tid * 4]);
    float s = xv.x + xv.y + xv.z + xv.w;
    float q = xv.x * xv.x + xv.y * xv.y + xv.z * xv.z + xv.w * xv.w;
    for (int off = 32; off > 0; off >>= 1) {
        s += __shfl_down(s, off);
        q += __shfl_down(q, off);
    }
    __shared__ float sa[4], sb[4];
    if ((tid & 63) == 0) { sa[tid >> 6] = s; sb[tid >> 6] = q; }
    __syncthreads();
    const float ts = sa[0] + sa[1] + sa[2] + sa[3];
    const float tq = sb[0] + sb[1] + sb[2] + sb[3];
    const float mean = ts * (1.f / kC);
    const float var  = tq * (1.f / kC) - mean * mean;
    const float rstd = rsqrtf(var + 1e-5f);
    const float4 wv = *reinterpret_cast<const float4*>(&w[tid * 4]);
    const float4 bv = *reinterpret_cast<const float4*>(&b[tid * 4]);
    ushort4 o;
    o.x = f2h((xv.x - mean) * rstd * wv.x + bv.x);
    o.y = f2h((xv.y - mean) * rstd * wv.y + bv.y);
    o.z = f2h((xv.z - mean) * rstd * wv.z + bv.z);
    o.w = f2h((xv.w - mean) * rstd * wv.w + bv.w);
    *reinterpret_cast<ushort4*>(&out[(size_t)row * kC + tid * 4]) = o;
}

// ---------------------------------------------------------------------------
// 4a. Weight convert + transpose: W fp32 [K][N] -> WT fp16 [N][K]
// ---------------------------------------------------------------------------
__global__ __launch_bounds__(256) void convertT_kernel(
    const float* __restrict__ W, unsigned short* __restrict__ WT, int K, int N)
{
    __shared__ unsigned short t[64][68];
    const int tid = threadIdx.x;
    const int k0 = blockIdx.y * 64, n0 = blockIdx.x * 64;
    const int r = tid >> 4, c4 = (tid & 15) * 4;
    #pragma unroll
    for (int s = 0; s < 4; ++s) {
        const int rr = r + s * 16;
        const float4 v = *reinterpret_cast<const float4*>(&W[(size_t)(k0 + rr) * N + n0 + c4]);
        t[rr][c4 + 0] = f2h(v.x);
        t[rr][c4 + 1] = f2h(v.y);
        t[rr][c4 + 2] = f2h(v.z);
        t[rr][c4 + 3] = f2h(v.w);
    }
    __syncthreads();
    #pragma unroll
    for (int s = 0; s < 4; ++s) {
        const int rn = r + s * 16;
        ushort4 o;
        o.x = t[c4 + 0][rn];
        o.y = t[c4 + 1][rn];
        o.z = t[c4 + 2][rn];
        o.w = t[c4 + 3][rn];
        *reinterpret_cast<ushort4*>(&WT[(size_t)(n0 + rn) * K + k0 + c4]) = o;
    }
}

// ---------------------------------------------------------------------------
// 4b. fp16 MFMA GEMM: C = [RES? C +] A(MxK,f16) @ BT^T(NxK,f16) + bias
//     128x128 tile, 4 waves (2x2), BK=32, global_load_lds width 16,
//     4-slot XOR swizzle keyed on (row>>2)&3 (both sides — rule #21);
//     within-group aliasing is only 2-way (free, m136).
// ---------------------------------------------------------------------------
template<int RELU, int RES, int OHF>
__global__ __launch_bounds__(256) void gemm_f16_kernel(
    const unsigned short* __restrict__ A,   // [M][K] fp16
    const unsigned short* __restrict__ BT,  // [N][K] fp16
    const float* __restrict__ bias,
    float* __restrict__ Cf, unsigned short* __restrict__ Ch,
    int M, int N, int K)
{
    __shared__ __align__(16) unsigned short As[128 * 32];
    __shared__ __align__(16) unsigned short Bs[128 * 32];
    const int tid = threadIdx.x;
    const int lane = tid & 63;
    const int wv   = tid >> 6;
    const int wr = wv >> 1, wc = wv & 1;         // wave -> 64x64 quadrant
    const int bm = blockIdx.y * 128;
    const int bn = blockIdx.x * 128;

    // staging geometry: row r0 = tid>>2, global slot pre-swizzled
    const int r0 = tid >> 2;                       // 0..63 (+64 for issue 1)
    const int gs = (tid & 3) ^ ((r0 >> 2) & 3);    // inverse-swizzled global slot
    const size_t arow0 = (size_t)(bm + r0) * K;
    const size_t arow1 = (size_t)(bm + 64 + r0) * K;
    const size_t brow0 = (size_t)(bn + r0) * K;
    const size_t brow1 = (size_t)(bn + 64 + r0) * K;

    const int fr = lane & 15;                      // fragment row/col
    const int kb = lane >> 4;                      // k-block 0..3
    const int sw = (kb ^ ((fr >> 2) & 3)) * 8;     // swizzled k-offset (ushorts)

    f32x4 acc[4][4] = {};

    for (int k0 = 0; k0 < K; k0 += 32) {
        __syncthreads();
        gload_lds16(A  + arow0 + k0 + gs * 8, (char*)As + wv * 1024);
        gload_lds16(A  + arow1 + k0 + gs * 8, (char*)As + 4096 + wv * 1024);
        gload_lds16(BT + brow0 + k0 + gs * 8, (char*)Bs + wv * 1024);
        gload_lds16(BT + brow1 + k0 + gs * 8, (char*)Bs + 4096 + wv * 1024);
        __syncthreads();

        f16x8 a[4], b[4];
        #pragma unroll
        for (int m = 0; m < 4; ++m)
            a[m] = *reinterpret_cast<const f16x8*>(&As[(wr * 64 + m * 16 + fr) * 32 + sw]);
        #pragma unroll
        for (int n = 0; n < 4; ++n)
            b[n] = *reinterpret_cast<const f16x8*>(&Bs[(wc * 64 + n * 16 + fr) * 32 + sw]);
        #pragma unroll
        for (int m = 0; m < 4; ++m)
            #pragma unroll
            for (int n = 0; n < 4; ++n)
                acc[m][n] = __builtin_amdgcn_mfma_f32_16x16x32_f16(a[m], b[n], acc[m][n], 0, 0, 0);
    }

    // epilogue: C/D layout col=lane&15, row=(lane>>4)*4+reg
    const int fq = lane >> 4;
    #pragma unroll
    for (int n = 0; n < 4; ++n) {
        const int c = bn + wc * 64 + n * 16 + fr;
        const float bv = bias[c];
        #pragma unroll
        for (int m = 0; m < 4; ++m) {
            #pragma unroll
            for (int j = 0; j < 4; ++j) {
                const int r = bm + wr * 64 + m * 16 + fq * 4 + j;
                float v = acc[m][n][j] + bv;
                if (RES)  v += Cf[(size_t)r * N + c];
                if (RELU) v = fmaxf(v, 0.f);
                if (OHF)  Ch[(size_t)r * N + c] = f2h(v);
                else      Cf[(size_t)r * N + c] = v;
            }
        }
    }
}

// ---------------------------------------------------------------------------
// 5. Flash attention (fp32 qkv in, fp16 out). 64-query tile, 4 waves.
// ---------------------------------------------------------------------------
__global__ __launch_bounds__(256) void attn_kernel(
    const float* __restrict__ qkv, unsigned short* __restrict__ o)
{
    const int bid = blockIdx.x;            // 512 blocks
    const int bh  = bid & 31;
    const int qb  = ((bid >> 5) + bh) & 15;   // shear: balance tile counts
    const int b   = bh >> 4;               // H = 16
    const int h   = bh & 15;
    const int tid  = threadIdx.x;
    const int lane = tid & 63;
    const int wv   = tid >> 6;

    __shared__ float Qs[64][68];
    __shared__ float Vs[64][68];
    __shared__ float Ps[64][68];

    const size_t rs = 3 * kC;
    const int qlo = qb * 64;
    const size_t qbase = (size_t)(b * kL + qlo) * rs + h * kDH;

    #pragma unroll
    for (int s = 0; s < 4; ++s) {
        const int i = tid + s * 256;
        const int r = i >> 4, c = (i & 15) * 4;
        const float4 v = *reinterpret_cast<const float4*>(&qkv[qbase + (size_t)r * rs + c]);
        Qs[r][c + 0] = v.x * 0.125f;
        Qs[r][c + 1] = v.y * 0.125f;
        Qs[r][c + 2] = v.z * 0.125f;
        Qs[r][c + 3] = v.w * 0.125f;
    }

    float m[16], l[16], oa[16];
    #pragma unroll
    for (int i = 0; i < 16; ++i) { m[i] = -INFINITY; l[i] = 0.f; oa[i] = 0.f; }

    for (int k0 = 0; k0 <= qlo; k0 += 64) {
        __syncthreads();

        const size_t kvbase = (size_t)(b * kL + k0) * rs + h * kDH;
        #pragma unroll
        for (int s = 0; s < 4; ++s) {
            const int i = tid + s * 256;
            const int r = i >> 4, c = (i & 15) * 4;
            *reinterpret_cast<float4*>(&Vs[r][c]) =
                *reinterpret_cast<const float4*>(&qkv[kvbase + (size_t)r * rs + 2 * kC + c]);
        }
        const float* kptr = &qkv[kvbase + (size_t)lane * rs + kC];

        float acc[16];
        #pragma unroll
        for (int qq = 0; qq < 16; ++qq) acc[qq] = 0.f;

        __syncthreads();

        #pragma unroll
        for (int j = 0; j < 16; ++j) {
            const float4 k4 = *reinterpret_cast<const float4*>(&kptr[j * 4]);
            #pragma unroll
            for (int qq = 0; qq < 16; ++qq) {
                const float4 q4 = *reinterpret_cast<const float4*>(&Qs[wv * 16 + qq][j * 4]);
                acc[qq] += q4.x * k4.x + q4.y * k4.y + q4.z * k4.z + q4.w * k4.w;
            }
        }

        const bool diag = (k0 == qlo);
        #pragma unroll
        for (int qq = 0; qq < 16; ++qq) {
            float s = acc[qq];
            if (diag && lane > wv * 16 + qq) s = -INFINITY;
            float mx = s;
            #pragma unroll
            for (int off = 32; off > 0; off >>= 1) mx = fmaxf(mx, __shfl_xor(mx, off));
            const float mn  = fmaxf(m[qq], mx);
            const float fac = __expf(m[qq] - mn);
            const float p   = __expf(s - mn);
            float ps = p;
            #pragma unroll
            for (int off = 32; off > 0; off >>= 1) ps += __shfl_xor(ps, off);
            l[qq]  = l[qq] * fac + ps;
            oa[qq] *= fac;
            m[qq]  = mn;
            Ps[lane][wv * 16 + qq] = p;
        }

        __syncthreads();

        #pragma unroll
        for (int k = 0; k < 64; ++k) {
            const float vk = Vs[k][lane];
            const float4 p0 = *reinterpret_cast<const float4*>(&Ps[k][wv * 16 + 0]);
            const float4 p1 = *reinterpret_cast<const float4*>(&Ps[k][wv * 16 + 4]);
            const float4 p2 = *reinterpret_cast<const float4*>(&Ps[k][wv * 16 + 8]);
            const float4 p3 = *reinterpret_cast<const float4*>(&Ps[k][wv * 16 + 12]);
            oa[0]  += p0.x * vk; oa[1]  += p0.y * vk; oa[2]  += p0.z * vk; oa[3]  += p0.w * vk;
            oa[4]  += p1.x * vk; oa[5]  += p1.y * vk; oa[6]  += p1.z * vk; oa[7]  += p1.w * vk;
            oa[8]  += p2.x * vk; oa[9]  += p2.y * vk; oa[10] += p2.z * vk; oa[11] += p2.w * vk;
            oa[12] += p3.x * vk; oa[13] += p3.y * vk; oa[14] += p3.z * vk; oa[15] += p3.w * vk;
        }
    }

    #pragma unroll
    for (int qq = 0; qq < 16; ++qq) {
        const float rl = 1.f / l[qq];
        o[((size_t)(b * kL + qlo + wv * 16 + qq)) * kC + h * kDH + lane] = f2h(oa[qq] * rl);
    }
}

// ---------------------------------------------------------------------------
// 6. Final tanh (in place on d_out)
// ---------------------------------------------------------------------------
__global__ __launch_bounds__(256) void tanh_kernel(float* __restrict__ x)
{
    const size_t i = ((size_t)blockIdx.x * 256 + threadIdx.x) * 4;
    float4 v = *reinterpret_cast<float4*>(&x[i]);
    v.x = tanhf(v.x); v.y = tanhf(v.y); v.z = tanhf(v.z); v.w = tanhf(v.w);
    *reinterpret_cast<float4*>(&x[i]) = v;
}

// ---------------------------------------------------------------------------
extern "C" void kernel_launch(void* const* d_in, const int* in_sizes, int n_in,
                              void* d_out, int out_size, void* d_ws, size_t ws_size,
                              hipStream_t stream)
{
    (void)in_sizes; (void)n_in; (void)out_size; (void)ws_size;
    const float* obs    = (const float*)d_in[0];
    const float* act    = (const float*)d_in[1];
    const float* rew    = (const float*)d_in[2];
    const float* obs_W  = (const float*)d_in[3];
    const float* obs_b  = (const float*)d_in[4];
    const float* act_W  = (const float*)d_in[5];
    const float* act_b  = (const float*)d_in[6];
    const float* rew_W  = (const float*)d_in[7];
    const float* rew_b  = (const float*)d_in[8];
    const float* tr_W   = (const float*)d_in[9];
    const float* tr_b   = (const float*)d_in[10];
    const float* bn_g   = (const float*)d_in[11];
    const float* bn_b   = (const float*)d_in[12];
    const float* ln1_w  = (const float*)d_in[13];
    const float* ln1_b  = (const float*)d_in[14];
    const float* qkv_W  = (const float*)d_in[15];
    const float* qkv_b  = (const float*)d_in[16];
    const float* out_W  = (const float*)d_in[17];
    const float* out_b  = (const float*)d_in[18];
    const float* ln2_w  = (const float*)d_in[19];
    const float* ln2_b  = (const float*)d_in[20];
    const float* fc_W   = (const float*)d_in[21];
    const float* fc_b   = (const float*)d_in[22];
    const float* pj_W   = (const float*)d_in[23];
    const float* pj_b   = (const float*)d_in[24];

    float* x  = (float*)d_out;                     // fp32 residual stream
    float* ws = (float*)d_ws;
    // ws layout (float slots)
    float* tm   = ws;                              // 64
    float* tv   = ws + 64;                         // 64
    float* qkv  = ws + 128;                        // 2048*3072 fp32
    unsigned short* wbuf  = (unsigned short*)(qkv + (size_t)kRows * 3 * kC);   // 12.58M f16
    unsigned short* h_hf  = wbuf + 12582912;       // 2048*1024 f16
    unsigned short* ao_hf = h_hf + (size_t)kRows * kC;
    unsigned short* ff_hf = ao_hf + (size_t)kRows * kC;   // 2048*4096 f16
    // per-layer transposed weight slices inside wbuf
    unsigned short* qWT = wbuf;                    // [3072][1024]
    unsigned short* oWT = qWT + 3 * kC * kC;       // [1024][1024]
    unsigned short* fWT = oWT + kC * kC;           // [4096][1024]
    unsigned short* pWT = fWT + kC * kFF;          // [1024][4096]

    tran_stats_kernel<<<kOBS, 256, 0, stream>>>(obs, tm, tv);
    encode_kernel<<<kRows, 256, 0, stream>>>(obs, act, rew,
        obs_W, obs_b, act_W, act_b, rew_W, rew_b, tr_W, tr_b, bn_g, bn_b, tm, tv, x);

    for (int lyr = 0; lyr < kNL; ++lyr) {
        const float* qW = qkv_W + (size_t)lyr * kC * 3 * kC;
        const float* qB = qkv_b + (size_t)lyr * 3 * kC;
        const float* oW = out_W + (size_t)lyr * kC * kC;
        const float* oB = out_b + (size_t)lyr * kC;
        const float* fW = fc_W + (size_t)lyr * kC * kFF;
        const float* fB = fc_b + (size_t)lyr * kFF;
        const float* pW = pj_W + (size_t)lyr * kFF * kC;
        const float* pB = pj_b + (size_t)lyr * kC;

        // convert+transpose this layer's weights to fp16 [N][K]
        convertT_kernel<<<dim3(3 * kC / 64, kC / 64), 256, 0, stream>>>(qW, qWT, kC, 3 * kC);
        convertT_kernel<<<dim3(kC / 64, kC / 64),     256, 0, stream>>>(oW, oWT, kC, kC);
        convertT_kernel<<<dim3(kFF / 64, kC / 64),    256, 0, stream>>>(fW, fWT, kC, kFF);
        convertT_kernel<<<dim3(kC / 64, kFF / 64),    256, 0, stream>>>(pW, pWT, kFF, kC);

        ln_kernel<<<kRows, 256, 0, stream>>>(x, ln1_w + lyr * kC, ln1_b + lyr * kC, h_hf);
        gemm_f16_kernel<0,0,0><<<dim3(3 * kC / 128, kRows / 128), 256, 0, stream>>>(
            h_hf, qWT, qB, qkv, nullptr, kRows, 3 * kC, kC);
        attn_kernel<<<dim3(512), 256, 0, stream>>>(qkv, ao_hf);
        gemm_f16_kernel<0,1,0><<<dim3(kC / 128, kRows / 128), 256, 0, stream>>>(
            ao_hf, oWT, oB, x, nullptr, kRows, kC, kC);
        ln_kernel<<<kRows, 256, 0, stream>>>(x, ln2_w + lyr * kC, ln2_b + lyr * kC, h_hf);
        gemm_f16_kernel<1,0,1><<<dim3(kFF / 128, kRows / 128), 256, 0, stream>>>(
            h_hf, fWT, fB, nullptr, ff_hf, kRows, kFF, kC);
        gemm_f16_kernel<0,1,0><<<dim3(kC / 128, kRows / 128), 256, 0, stream>>>(
            ff_hf, pWT, pB, x, nullptr, kRows, kC, kFF);
    }
    tanh_kernel<<<kRows * kC / 1024, 256, 0, stream>>>(x);
}

// Round 5
// 974.257 us; speedup vs baseline: 6.2187x; 2.1431x over previous
//
#include <hip/hip_runtime.h>
#include <hip/hip_bf16.h>
#include <math.h>

// Problem constants
constexpr int kB   = 2;
constexpr int kL   = 1024;
constexpr int kOBS = 64;
constexpr int kACT = 16;
constexpr int kC   = 1024;
constexpr int kH   = 16;
constexpr int kDH  = 64;
constexpr int kFF  = 4096;
constexpr int kNL  = 4;
constexpr int kRows = kB * kL;          // 2048
constexpr int kOE = 512, kAE = 256, kRE = 128, kTE = 128;

typedef _Float16 f16x8 __attribute__((ext_vector_type(8)));
typedef _Float16 f16x4 __attribute__((ext_vector_type(4)));
typedef float    f32x4 __attribute__((ext_vector_type(4)));

__device__ __forceinline__ unsigned short f2h(float x) {
    return __builtin_bit_cast(unsigned short, (_Float16)x);
}
__device__ __forceinline__ void gload_lds16(const void* g, void* l) {
    __builtin_amdgcn_global_load_lds(
        (const __attribute__((address_space(1))) unsigned int*)g,
        (__attribute__((address_space(3))) unsigned int*)l, 16, 0, 0);
}

// ---------------------------------------------------------------------------
// 1. Transition batchnorm stats
// ---------------------------------------------------------------------------
__global__ __launch_bounds__(256) void tran_stats_kernel(
    const float* __restrict__ obs, float* __restrict__ tm, float* __restrict__ tv)
{
    const int f = blockIdx.x;
    const int tid = threadIdx.x;
    float sum = 0.f, sq = 0.f;
    for (int r = tid; r < kRows; r += 256) {
        const int t = r & (kL - 1);
        float d = 0.f;
        if (t > 0) {
            const float cur  = obs[(size_t)r * kOBS + f];
            const float prev = obs[(size_t)(r - 1) * kOBS + f];
            d = cur - prev;
        }
        sum += d; sq += d * d;
    }
    for (int off = 32; off > 0; off >>= 1) {
        sum += __shfl_down(sum, off);
        sq  += __shfl_down(sq, off);
    }
    __shared__ float sa[4], sb[4];
    if ((tid & 63) == 0) { sa[tid >> 6] = sum; sb[tid >> 6] = sq; }
    __syncthreads();
    if (tid == 0) {
        const float ts = sa[0] + sa[1] + sa[2] + sa[3];
        const float tq = sb[0] + sb[1] + sb[2] + sb[3];
        const float m = ts / (float)kRows;
        tm[f] = m;
        tv[f] = tq / (float)kRows - m * m;
    }
}

// ---------------------------------------------------------------------------
// 2. Encoder (writes fp32 residual stream)
// ---------------------------------------------------------------------------
__global__ __launch_bounds__(256) void encode_kernel(
    const float* __restrict__ obs, const float* __restrict__ act, const float* __restrict__ rew,
    const float* __restrict__ obs_W, const float* __restrict__ obs_b,
    const float* __restrict__ act_W, const float* __restrict__ act_b,
    const float* __restrict__ rew_W, const float* __restrict__ rew_b,
    const float* __restrict__ tr_W,  const float* __restrict__ tr_b,
    const float* __restrict__ bn_g,  const float* __restrict__ bn_b,
    const float* __restrict__ tm,    const float* __restrict__ tv,
    float* __restrict__ enc)
{
    const int row = blockIdx.x;
    const int t = row & (kL - 1);
    const int tid = threadIdx.x;
    __shared__ float s_obs2[kOBS];
    __shared__ float s_tran[kOBS];
    __shared__ float s_act[kACT];
    __shared__ float s_rew;
    if (tid < kOBS) {
        const float cur  = obs[(size_t)row * kOBS + tid];
        const float prev = (t > 0) ? obs[(size_t)(row - 1) * kOBS + tid] : cur;
        s_obs2[tid] = prev;
        const float tr = cur - prev;
        s_tran[tid] = (tr - tm[tid]) * rsqrtf(tv[tid] + 1e-5f) * bn_g[tid] + bn_b[tid];
    } else if (tid < kOBS + kACT) {
        s_act[tid - kOBS] = act[(size_t)row * kACT + (tid - kOBS)];
    } else if (tid == kOBS + kACT) {
        s_rew = rew[row];
    }
    __syncthreads();
    float* er = enc + (size_t)row * kC;
    #pragma unroll
    for (int s = 0; s < 4; ++s) {
        const int c = tid + s * 256;
        float v;
        if (c < kOE) {
            v = obs_b[c];
            #pragma unroll
            for (int k = 0; k < kOBS; ++k) v += s_obs2[k] * obs_W[k * kOE + c];
        } else if (c < kOE + kAE) {
            const int cc = c - kOE;
            v = act_b[cc];
            #pragma unroll
            for (int k = 0; k < kACT; ++k) v += s_act[k] * act_W[k * kAE + cc];
        } else if (c < kOE + kAE + kRE) {
            const int cc = c - (kOE + kAE);
            v = s_rew * rew_W[cc] + rew_b[cc];
        } else {
            const int cc = c - (kOE + kAE + kRE);
            v = tr_b[cc];
            #pragma unroll
            for (int k = 0; k < kOBS; ++k) v += s_tran[k] * tr_W[k * kTE + cc];
        }
        er[c] = v;
    }
}

// ---------------------------------------------------------------------------
// 3. LayerNorm: fp32 in -> fp16 out
// ---------------------------------------------------------------------------
__global__ __launch_bounds__(256) void ln_kernel(
    const float* __restrict__ x, const float* __restrict__ w,
    const float* __restrict__ b, unsigned short* __restrict__ out)
{
    const int row = blockIdx.x;
    const int tid = threadIdx.x;
    const float4 xv = *reinterpret_cast<const float4*>(&x[(size_t)row * kC + tid * 4]);
    float s = xv.x + xv.y + xv.z + xv.w;
    float q = xv.x * xv.x + xv.y * xv.y + xv.z * xv.z + xv.w * xv.w;
    for (int off = 32; off > 0; off >>= 1) {
        s += __shfl_down(s, off);
        q += __shfl_down(q, off);
    }
    __shared__ float sa[4], sb[4];
    if ((tid & 63) == 0) { sa[tid >> 6] = s; sb[tid >> 6] = q; }
    __syncthreads();
    const float ts = sa[0] + sa[1] + sa[2] + sa[3];
    const float tq = sb[0] + sb[1] + sb[2] + sb[3];
    const float mean = ts * (1.f / kC);
    const float var  = tq * (1.f / kC) - mean * mean;
    const float rstd = rsqrtf(var + 1e-5f);
    const float4 wv = *reinterpret_cast<const float4*>(&w[tid * 4]);
    const float4 bv = *reinterpret_cast<const float4*>(&b[tid * 4]);
    ushort4 o;
    o.x = f2h((xv.x - mean) * rstd * wv.x + bv.x);
    o.y = f2h((xv.y - mean) * rstd * wv.y + bv.y);
    o.z = f2h((xv.z - mean) * rstd * wv.z + bv.z);
    o.w = f2h((xv.w - mean) * rstd * wv.w + bv.w);
    *reinterpret_cast<ushort4*>(&out[(size_t)row * kC + tid * 4]) = o;
}

// ---------------------------------------------------------------------------
// 4a. Weight convert + transpose: W fp32 [K][N] -> WT fp16 [N][K]
// ---------------------------------------------------------------------------
__global__ __launch_bounds__(256) void convertT_kernel(
    const float* __restrict__ W, unsigned short* __restrict__ WT, int K, int N)
{
    __shared__ unsigned short t[64][68];
    const int tid = threadIdx.x;
    const int k0 = blockIdx.y * 64, n0 = blockIdx.x * 64;
    const int r = tid >> 4, c4 = (tid & 15) * 4;
    #pragma unroll
    for (int s = 0; s < 4; ++s) {
        const int rr = r + s * 16;
        const float4 v = *reinterpret_cast<const float4*>(&W[(size_t)(k0 + rr) * N + n0 + c4]);
        t[rr][c4 + 0] = f2h(v.x);
        t[rr][c4 + 1] = f2h(v.y);
        t[rr][c4 + 2] = f2h(v.z);
        t[rr][c4 + 3] = f2h(v.w);
    }
    __syncthreads();
    #pragma unroll
    for (int s = 0; s < 4; ++s) {
        const int rn = r + s * 16;
        ushort4 o;
        o.x = t[c4 + 0][rn];
        o.y = t[c4 + 1][rn];
        o.z = t[c4 + 2][rn];
        o.w = t[c4 + 3][rn];
        *reinterpret_cast<ushort4*>(&WT[(size_t)(n0 + rn) * K + k0 + c4]) = o;
    }
}

// ---------------------------------------------------------------------------
// 4b. fp16 MFMA GEMM. MODE 0: f32 out (Cf, +RES/RELU). MODE 1: f16 out (Ch).
//     MODE 2: qkv special — cols [0,2048) -> f16 qk (Ch, stride 2048);
//             cols [2048,3072) -> f16 V transposed (Cv = vt[b][h][d][t]).
// ---------------------------------------------------------------------------
template<int RELU, int RES, int MODE>
__global__ __launch_bounds__(256) void gemm_f16_kernel(
    const unsigned short* __restrict__ A,   // [M][K] fp16
    const unsigned short* __restrict__ BT,  // [N][K] fp16
    const float* __restrict__ bias,
    float* __restrict__ Cf, unsigned short* __restrict__ Ch,
    unsigned short* __restrict__ Cv,
    int M, int N, int K)
{
    __shared__ __align__(16) unsigned short As[128 * 32];
    __shared__ __align__(16) unsigned short Bs[128 * 32];
    const int tid = threadIdx.x;
    const int lane = tid & 63;
    const int wv   = tid >> 6;
    const int wr = wv >> 1, wc = wv & 1;
    const int bm = blockIdx.y * 128;
    const int bn = blockIdx.x * 128;

    const int r0 = tid >> 2;
    const int gs = (tid & 3) ^ ((r0 >> 2) & 3);
    const size_t arow0 = (size_t)(bm + r0) * K;
    const size_t arow1 = (size_t)(bm + 64 + r0) * K;
    const size_t brow0 = (size_t)(bn + r0) * K;
    const size_t brow1 = (size_t)(bn + 64 + r0) * K;

    const int fr = lane & 15;
    const int kb = lane >> 4;
    const int sw = (kb ^ ((fr >> 2) & 3)) * 8;

    f32x4 acc[4][4] = {};

    for (int k0 = 0; k0 < K; k0 += 32) {
        __syncthreads();
        gload_lds16(A  + arow0 + k0 + gs * 8, (char*)As + wv * 1024);
        gload_lds16(A  + arow1 + k0 + gs * 8, (char*)As + 4096 + wv * 1024);
        gload_lds16(BT + brow0 + k0 + gs * 8, (char*)Bs + wv * 1024);
        gload_lds16(BT + brow1 + k0 + gs * 8, (char*)Bs + 4096 + wv * 1024);
        __syncthreads();

        f16x8 a[4], b[4];
        #pragma unroll
        for (int m = 0; m < 4; ++m)
            a[m] = *reinterpret_cast<const f16x8*>(&As[(wr * 64 + m * 16 + fr) * 32 + sw]);
        #pragma unroll
        for (int n = 0; n < 4; ++n)
            b[n] = *reinterpret_cast<const f16x8*>(&Bs[(wc * 64 + n * 16 + fr) * 32 + sw]);
        #pragma unroll
        for (int m = 0; m < 4; ++m)
            #pragma unroll
            for (int n = 0; n < 4; ++n)
                acc[m][n] = __builtin_amdgcn_mfma_f32_16x16x32_f16(a[m], b[n], acc[m][n], 0, 0, 0);
    }

    const int fq = lane >> 4;
    if (MODE == 2) {
        if (bn < 2 * kC) {          // Q,K region -> qk f16 [row][2048]
            #pragma unroll
            for (int n = 0; n < 4; ++n) {
                const int c = bn + wc * 64 + n * 16 + fr;
                const float bv = bias[c];
                #pragma unroll
                for (int m = 0; m < 4; ++m) {
                    #pragma unroll
                    for (int j = 0; j < 4; ++j) {
                        const int r = bm + wr * 64 + m * 16 + fq * 4 + j;
                        Ch[(size_t)r * (2 * kC) + c] = f2h(acc[m][n][j] + bv);
                    }
                }
            }
        } else {                    // V region -> vt[b][h][d][t] f16
            #pragma unroll
            for (int n = 0; n < 4; ++n) {
                const int c  = bn + wc * 64 + n * 16 + fr;
                const int cc = c - 2 * kC;
                const int hh = cc >> 6, dd = cc & 63;
                const float bv = bias[c];
                #pragma unroll
                for (int m = 0; m < 4; ++m) {
                    const int rr = bm + wr * 64 + m * 16 + fq * 4;
                    const int bb = rr >> 10, t0 = rr & 1023;
                    f16x4 pk;
                    #pragma unroll
                    for (int j = 0; j < 4; ++j) pk[j] = (_Float16)(acc[m][n][j] + bv);
                    *reinterpret_cast<f16x4*>(
                        &Cv[((size_t)(bb * kH + hh) * kDH + dd) * kL + t0]) = pk;
                }
            }
        }
        return;
    }
    #pragma unroll
    for (int n = 0; n < 4; ++n) {
        const int c = bn + wc * 64 + n * 16 + fr;
        const float bv = bias[c];
        #pragma unroll
        for (int m = 0; m < 4; ++m) {
            #pragma unroll
            for (int j = 0; j < 4; ++j) {
                const int r = bm + wr * 64 + m * 16 + fq * 4 + j;
                float v = acc[m][n][j] + bv;
                if (RES)  v += Cf[(size_t)r * N + c];
                if (RELU) v = fmaxf(v, 0.f);
                if (MODE == 1) Ch[(size_t)r * N + c] = f2h(v);
                else           Cf[(size_t)r * N + c] = v;
            }
        }
    }
}

// ---------------------------------------------------------------------------
// 5. MFMA flash attention. 64-q tile per block, 4 waves; each wave owns 16 q.
//    Swapped QK^T (mfma(K,Q) -> D[key][q], col=q=lane&15) so softmax state is
//    per-lane. LDS tiles [64 rows][8 slots x 16B], slot ^= (row&7) swizzle.
// ---------------------------------------------------------------------------
__device__ __forceinline__ int swz(int row, int slot) {
    return row * 64 + ((slot ^ (row & 7)) * 8);   // ushort index, 16B-aligned
}

__global__ __launch_bounds__(256) void attn_mfma_kernel(
    const unsigned short* __restrict__ qk,   // [2048][2048] f16 (Q | K)
    const unsigned short* __restrict__ vt,   // [2][16][64][1024] f16  V^T
    unsigned short* __restrict__ o)          // [2048][1024] f16
{
    const int bid = blockIdx.x;            // 512 blocks
    const int bh  = bid & 31;
    const int qb  = ((bid >> 5) + bh) & 15;   // shear: balance causal work
    const int b   = bh >> 4;
    const int h   = bh & 15;
    const int tid  = threadIdx.x;
    const int lane = tid & 63;
    const int wv   = tid >> 6;
    const int fr = lane & 15;              // own-index (q for this kernel)
    const int g  = lane >> 4;              // k-group

    __shared__ __align__(16) unsigned short Qs[64 * 64];
    __shared__ __align__(16) unsigned short Ks[64 * 64];
    __shared__ __align__(16) unsigned short Vts[64 * 64];
    __shared__ __align__(16) unsigned short Ps[64 * 64];

    const int qlo = qb * 64;

    // ---- stage Q tile (prescaled by 1/8, exact in f16) ----
    {
        const int r = tid >> 2, s = tid & 3;
        const unsigned short* qg = &qk[(size_t)(b * kL + qlo + r) * (2 * kC) + h * kDH];
        f16x8 v0 = *reinterpret_cast<const f16x8*>(&qg[s * 8]);
        f16x8 v1 = *reinterpret_cast<const f16x8*>(&qg[(s + 4) * 8]);
        #pragma unroll
        for (int i = 0; i < 8; ++i) { v0[i] *= (_Float16)0.125f; v1[i] *= (_Float16)0.125f; }
        *reinterpret_cast<f16x8*>(&Qs[swz(r, s)])     = v0;
        *reinterpret_cast<f16x8*>(&Qs[swz(r, s + 4)]) = v1;
    }
    __syncthreads();

    f16x8 qfrag[2];
    #pragma unroll
    for (int kf = 0; kf < 2; ++kf)
        qfrag[kf] = *reinterpret_cast<const f16x8*>(&Qs[swz(wv * 16 + fr, kf * 4 + g)]);

    float m = -INFINITY, l = 0.f;
    f32x4 acc_o[4] = {};
    const int qg_row = qlo + wv * 16 + fr;          // global q index

    for (int k0 = 0; k0 <= qlo; k0 += 64) {
        __syncthreads();   // all waves done reading Ks/Vts of previous tile
        {   // stage K [key][d] and Vt [d][key] tiles
            const int r = tid >> 2, s = tid & 3;
            const unsigned short* kg = &qk[(size_t)(b * kL + k0 + r) * (2 * kC) + kC + h * kDH];
            *reinterpret_cast<f16x8*>(&Ks[swz(r, s)])     = *reinterpret_cast<const f16x8*>(&kg[s * 8]);
            *reinterpret_cast<f16x8*>(&Ks[swz(r, s + 4)]) = *reinterpret_cast<const f16x8*>(&kg[(s + 4) * 8]);
            const unsigned short* vg = &vt[((size_t)(b * kH + h) * kDH + r) * kL + k0];
            *reinterpret_cast<f16x8*>(&Vts[swz(r, s)])     = *reinterpret_cast<const f16x8*>(&vg[s * 8]);
            *reinterpret_cast<f16x8*>(&Vts[swz(r, s + 4)]) = *reinterpret_cast<const f16x8*>(&vg[(s + 4) * 8]);
        }
        __syncthreads();

        // QK^T (swapped): acc_s[n] = D[key = n*16+g*4+j][q = fr]
        f32x4 acc_s[4] = {};
        #pragma unroll
        for (int kf = 0; kf < 2; ++kf) {
            const f16x8 qf = qfrag[kf];
            #pragma unroll
            for (int n = 0; n < 4; ++n) {
                const f16x8 kfr = *reinterpret_cast<const f16x8*>(&Ks[swz(n * 16 + fr, kf * 4 + g)]);
                acc_s[n] = __builtin_amdgcn_mfma_f32_16x16x32_f16(kfr, qf, acc_s[n], 0, 0, 0);
            }
        }

        // causal mask (diagonal tile only)
        if (k0 == qlo) {
            #pragma unroll
            for (int n = 0; n < 4; ++n)
                #pragma unroll
                for (int j = 0; j < 4; ++j)
                    if (k0 + n * 16 + g * 4 + j > qg_row) acc_s[n][j] = -INFINITY;
        }

        // online softmax (row q = fr lives in 4 lanes: reduce via xor 16,32)
        float mx = -INFINITY;
        #pragma unroll
        for (int n = 0; n < 4; ++n)
            #pragma unroll
            for (int j = 0; j < 4; ++j) mx = fmaxf(mx, acc_s[n][j]);
        mx = fmaxf(mx, __shfl_xor(mx, 16));
        mx = fmaxf(mx, __shfl_xor(mx, 32));
        const float mn  = fmaxf(m, mx);
        const float fac = __expf(m - mn);
        float p[4][4];
        float psum = 0.f;
        #pragma unroll
        for (int n = 0; n < 4; ++n)
            #pragma unroll
            for (int j = 0; j < 4; ++j) { p[n][j] = __expf(acc_s[n][j] - mn); psum += p[n][j]; }
        psum += __shfl_xor(psum, 16);
        psum += __shfl_xor(psum, 32);
        l = l * fac + psum;
        m = mn;
        #pragma unroll
        for (int dt = 0; dt < 4; ++dt)
            #pragma unroll
            for (int j = 0; j < 4; ++j) acc_o[dt][j] *= fac;

        // P -> LDS f16 (row = wave's q, same-wave write/read: in-order DS)
        #pragma unroll
        for (int n = 0; n < 4; ++n) {
            f16x4 pk;
            #pragma unroll
            for (int j = 0; j < 4; ++j) pk[j] = (_Float16)p[n][j];
            *reinterpret_cast<f16x4*>(&Ps[swz(wv * 16 + fr, 2 * n + (g >> 1)) + (g & 1) * 4]) = pk;
        }

        // PV: acc_o[dt] = D[d = dt*16+g*4+j][q = fr] += Vt[d][key]·P[q][key]
        #pragma unroll
        for (int kf = 0; kf < 2; ++kf) {
            const f16x8 pf = *reinterpret_cast<const f16x8*>(&Ps[swz(wv * 16 + fr, kf * 4 + g)]);
            #pragma unroll
            for (int dt = 0; dt < 4; ++dt) {
                const f16x8 vf = *reinterpret_cast<const f16x8*>(&Vts[swz(dt * 16 + fr, kf * 4 + g)]);
                acc_o[dt] = __builtin_amdgcn_mfma_f32_16x16x32_f16(vf, pf, acc_o[dt], 0, 0, 0);
            }
        }
    }

    // epilogue: O[q][d] = acc_o / l
    const float rl = 1.f / l;
    unsigned short* ob = &o[(size_t)(b * kL + qg_row) * kC + h * kDH];
    #pragma unroll
    for (int dt = 0; dt < 4; ++dt) {
        f16x4 pk;
        #pragma unroll
        for (int j = 0; j < 4; ++j) pk[j] = (_Float16)(acc_o[dt][j] * rl);
        *reinterpret_cast<f16x4*>(&ob[dt * 16 + g * 4]) = pk;
    }
}

// ---------------------------------------------------------------------------
// 6. Final tanh (in place on d_out)
// ---------------------------------------------------------------------------
__global__ __launch_bounds__(256) void tanh_kernel(float* __restrict__ x)
{
    const size_t i = ((size_t)blockIdx.x * 256 + threadIdx.x) * 4;
    float4 v = *reinterpret_cast<float4*>(&x[i]);
    v.x = tanhf(v.x); v.y = tanhf(v.y); v.z = tanhf(v.z); v.w = tanhf(v.w);
    *reinterpret_cast<float4*>(&x[i]) = v;
}

// ---------------------------------------------------------------------------
extern "C" void kernel_launch(void* const* d_in, const int* in_sizes, int n_in,
                              void* d_out, int out_size, void* d_ws, size_t ws_size,
                              hipStream_t stream)
{
    (void)in_sizes; (void)n_in; (void)out_size; (void)ws_size;
    const float* obs    = (const float*)d_in[0];
    const float* act    = (const float*)d_in[1];
    const float* rew    = (const float*)d_in[2];
    const float* obs_W  = (const float*)d_in[3];
    const float* obs_b  = (const float*)d_in[4];
    const float* act_W  = (const float*)d_in[5];
    const float* act_b  = (const float*)d_in[6];
    const float* rew_W  = (const float*)d_in[7];
    const float* rew_b  = (const float*)d_in[8];
    const float* tr_W   = (const float*)d_in[9];
    const float* tr_b   = (const float*)d_in[10];
    const float* bn_g   = (const float*)d_in[11];
    const float* bn_b   = (const float*)d_in[12];
    const float* ln1_w  = (const float*)d_in[13];
    const float* ln1_b  = (const float*)d_in[14];
    const float* qkv_W  = (const float*)d_in[15];
    const float* qkv_b  = (const float*)d_in[16];
    const float* out_W  = (const float*)d_in[17];
    const float* out_b  = (const float*)d_in[18];
    const float* ln2_w  = (const float*)d_in[19];
    const float* ln2_b  = (const float*)d_in[20];
    const float* fc_W   = (const float*)d_in[21];
    const float* fc_b   = (const float*)d_in[22];
    const float* pj_W   = (const float*)d_in[23];
    const float* pj_b   = (const float*)d_in[24];

    float* x  = (float*)d_out;                     // fp32 residual stream
    float* ws = (float*)d_ws;
    float* tm   = ws;                              // 64
    float* tv   = ws + 64;                         // 64
    unsigned short* wbuf  = (unsigned short*)(ws + 128);  // 12.58M f16 weights
    unsigned short* h_hf  = wbuf + 12582912;       // 2048*1024
    unsigned short* ao_hf = h_hf + (size_t)kRows * kC;    // 2048*1024
    unsigned short* ff_hf = ao_hf + (size_t)kRows * kC;   // 2048*4096
    unsigned short* qk_hf = ff_hf + (size_t)kRows * kFF;  // 2048*2048
    unsigned short* vt_hf = qk_hf + (size_t)kRows * 2 * kC; // 2*16*64*1024
    unsigned short* qWT = wbuf;                    // [3072][1024]
    unsigned short* oWT = qWT + 3 * kC * kC;       // [1024][1024]
    unsigned short* fWT = oWT + kC * kC;           // [4096][1024]
    unsigned short* pWT = fWT + kC * kFF;          // [1024][4096]

    tran_stats_kernel<<<kOBS, 256, 0, stream>>>(obs, tm, tv);
    encode_kernel<<<kRows, 256, 0, stream>>>(obs, act, rew,
        obs_W, obs_b, act_W, act_b, rew_W, rew_b, tr_W, tr_b, bn_g, bn_b, tm, tv, x);

    for (int lyr = 0; lyr < kNL; ++lyr) {
        const float* qW = qkv_W + (size_t)lyr * kC * 3 * kC;
        const float* qB = qkv_b + (size_t)lyr * 3 * kC;
        const float* oW = out_W + (size_t)lyr * kC * kC;
        const float* oB = out_b + (size_t)lyr * kC;
        const float* fW = fc_W + (size_t)lyr * kC * kFF;
        const float* fB = fc_b + (size_t)lyr * kFF;
        const float* pW = pj_W + (size_t)lyr * kFF * kC;
        const float* pB = pj_b + (size_t)lyr * kC;

        convertT_kernel<<<dim3(3 * kC / 64, kC / 64), 256, 0, stream>>>(qW, qWT, kC, 3 * kC);
        convertT_kernel<<<dim3(kC / 64, kC / 64),     256, 0, stream>>>(oW, oWT, kC, kC);
        convertT_kernel<<<dim3(kFF / 64, kC / 64),    256, 0, stream>>>(fW, fWT, kC, kFF);
        convertT_kernel<<<dim3(kC / 64, kFF / 64),    256, 0, stream>>>(pW, pWT, kFF, kC);

        ln_kernel<<<kRows, 256, 0, stream>>>(x, ln1_w + lyr * kC, ln1_b + lyr * kC, h_hf);
        gemm_f16_kernel<0,0,2><<<dim3(3 * kC / 128, kRows / 128), 256, 0, stream>>>(
            h_hf, qWT, qB, nullptr, qk_hf, vt_hf, kRows, 3 * kC, kC);
        attn_mfma_kernel<<<dim3(512), 256, 0, stream>>>(qk_hf, vt_hf, ao_hf);
        gemm_f16_kernel<0,1,0><<<dim3(kC / 128, kRows / 128), 256, 0, stream>>>(
            ao_hf, oWT, oB, x, nullptr, nullptr, kRows, kC, kC);
        ln_kernel<<<kRows, 256, 0, stream>>>(x, ln2_w + lyr * kC, ln2_b + lyr * kC, h_hf);
        gemm_f16_kernel<1,0,1><<<dim3(kFF / 128, kRows / 128), 256, 0, stream>>>(
            h_hf, fWT, fB, nullptr, ff_hf, nullptr, kRows, kFF, kC);
        gemm_f16_kernel<0,1,0><<<dim3(kC / 128, kRows / 128), 256, 0, stream>>>(
            ff_hf, pWT, pB, x, nullptr, nullptr, kRows, kC, kFF);
    }
    tanh_kernel<<<kRows * kC / 1024, 256, 0, stream>>>(x);
}

// Round 6
// 795.728 us; speedup vs baseline: 7.6140x; 1.2244x over previous
//
#include <hip/hip_runtime.h>
#include <hip/hip_bf16.h>
#include <math.h>

// Problem constants
constexpr int kB   = 2;
constexpr int kL   = 1024;
constexpr int kOBS = 64;
constexpr int kACT = 16;
constexpr int kC   = 1024;
constexpr int kH   = 16;
constexpr int kDH  = 64;
constexpr int kFF  = 4096;
constexpr int kNL  = 4;
constexpr int kRows = kB * kL;          // 2048
constexpr int kOE = 512, kAE = 256, kRE = 128, kTE = 128;

typedef _Float16 f16x8 __attribute__((ext_vector_type(8)));
typedef _Float16 f16x4 __attribute__((ext_vector_type(4)));
typedef float    f32x4 __attribute__((ext_vector_type(4)));

__device__ __forceinline__ unsigned short f2h(float x) {
    return __builtin_bit_cast(unsigned short, (_Float16)x);
}
__device__ __forceinline__ void gload_lds16(const void* g, void* l) {
    __builtin_amdgcn_global_load_lds(
        (const __attribute__((address_space(1))) unsigned int*)g,
        (__attribute__((address_space(3))) unsigned int*)l, 16, 0, 0);
}

// ---------------------------------------------------------------------------
// 1. Transition batchnorm stats
// ---------------------------------------------------------------------------
__global__ __launch_bounds__(256) void tran_stats_kernel(
    const float* __restrict__ obs, float* __restrict__ tm, float* __restrict__ tv)
{
    const int f = blockIdx.x;
    const int tid = threadIdx.x;
    float sum = 0.f, sq = 0.f;
    for (int r = tid; r < kRows; r += 256) {
        const int t = r & (kL - 1);
        float d = 0.f;
        if (t > 0) {
            const float cur  = obs[(size_t)r * kOBS + f];
            const float prev = obs[(size_t)(r - 1) * kOBS + f];
            d = cur - prev;
        }
        sum += d; sq += d * d;
    }
    for (int off = 32; off > 0; off >>= 1) {
        sum += __shfl_down(sum, off);
        sq  += __shfl_down(sq, off);
    }
    __shared__ float sa[4], sb[4];
    if ((tid & 63) == 0) { sa[tid >> 6] = sum; sb[tid >> 6] = sq; }
    __syncthreads();
    if (tid == 0) {
        const float ts = sa[0] + sa[1] + sa[2] + sa[3];
        const float tq = sb[0] + sb[1] + sb[2] + sb[3];
        const float m = ts / (float)kRows;
        tm[f] = m;
        tv[f] = tq / (float)kRows - m * m;
    }
}

// ---------------------------------------------------------------------------
// 2. Encoder (writes fp32 residual stream)
// ---------------------------------------------------------------------------
__global__ __launch_bounds__(256) void encode_kernel(
    const float* __restrict__ obs, const float* __restrict__ act, const float* __restrict__ rew,
    const float* __restrict__ obs_W, const float* __restrict__ obs_b,
    const float* __restrict__ act_W, const float* __restrict__ act_b,
    const float* __restrict__ rew_W, const float* __restrict__ rew_b,
    const float* __restrict__ tr_W,  const float* __restrict__ tr_b,
    const float* __restrict__ bn_g,  const float* __restrict__ bn_b,
    const float* __restrict__ tm,    const float* __restrict__ tv,
    float* __restrict__ enc)
{
    const int row = blockIdx.x;
    const int t = row & (kL - 1);
    const int tid = threadIdx.x;
    __shared__ float s_obs2[kOBS];
    __shared__ float s_tran[kOBS];
    __shared__ float s_act[kACT];
    __shared__ float s_rew;
    if (tid < kOBS) {
        const float cur  = obs[(size_t)row * kOBS + tid];
        const float prev = (t > 0) ? obs[(size_t)(row - 1) * kOBS + tid] : cur;
        s_obs2[tid] = prev;
        const float tr = cur - prev;
        s_tran[tid] = (tr - tm[tid]) * rsqrtf(tv[tid] + 1e-5f) * bn_g[tid] + bn_b[tid];
    } else if (tid < kOBS + kACT) {
        s_act[tid - kOBS] = act[(size_t)row * kACT + (tid - kOBS)];
    } else if (tid == kOBS + kACT) {
        s_rew = rew[row];
    }
    __syncthreads();
    float* er = enc + (size_t)row * kC;
    #pragma unroll
    for (int s = 0; s < 4; ++s) {
        const int c = tid + s * 256;
        float v;
        if (c < kOE) {
            v = obs_b[c];
            #pragma unroll
            for (int k = 0; k < kOBS; ++k) v += s_obs2[k] * obs_W[k * kOE + c];
        } else if (c < kOE + kAE) {
            const int cc = c - kOE;
            v = act_b[cc];
            #pragma unroll
            for (int k = 0; k < kACT; ++k) v += s_act[k] * act_W[k * kAE + cc];
        } else if (c < kOE + kAE + kRE) {
            const int cc = c - (kOE + kAE);
            v = s_rew * rew_W[cc] + rew_b[cc];
        } else {
            const int cc = c - (kOE + kAE + kRE);
            v = tr_b[cc];
            #pragma unroll
            for (int k = 0; k < kOBS; ++k) v += s_tran[k] * tr_W[k * kTE + cc];
        }
        er[c] = v;
    }
}

// ---------------------------------------------------------------------------
// 3. LayerNorm: fp32 in -> fp16 out
// ---------------------------------------------------------------------------
__global__ __launch_bounds__(256) void ln_kernel(
    const float* __restrict__ x, const float* __restrict__ w,
    const float* __restrict__ b, unsigned short* __restrict__ out)
{
    const int row = blockIdx.x;
    const int tid = threadIdx.x;
    const float4 xv = *reinterpret_cast<const float4*>(&x[(size_t)row * kC + tid * 4]);
    float s = xv.x + xv.y + xv.z + xv.w;
    float q = xv.x * xv.x + xv.y * xv.y + xv.z * xv.z + xv.w * xv.w;
    for (int off = 32; off > 0; off >>= 1) {
        s += __shfl_down(s, off);
        q += __shfl_down(q, off);
    }
    __shared__ float sa[4], sb[4];
    if ((tid & 63) == 0) { sa[tid >> 6] = s; sb[tid >> 6] = q; }
    __syncthreads();
    const float ts = sa[0] + sa[1] + sa[2] + sa[3];
    const float tq = sb[0] + sb[1] + sb[2] + sb[3];
    const float mean = ts * (1.f / kC);
    const float var  = tq * (1.f / kC) - mean * mean;
    const float rstd = rsqrtf(var + 1e-5f);
    const float4 wv = *reinterpret_cast<const float4*>(&w[tid * 4]);
    const float4 bv = *reinterpret_cast<const float4*>(&b[tid * 4]);
    ushort4 o;
    o.x = f2h((xv.x - mean) * rstd * wv.x + bv.x);
    o.y = f2h((xv.y - mean) * rstd * wv.y + bv.y);
    o.z = f2h((xv.z - mean) * rstd * wv.z + bv.z);
    o.w = f2h((xv.w - mean) * rstd * wv.w + bv.w);
    *reinterpret_cast<ushort4*>(&out[(size_t)row * kC + tid * 4]) = o;
}

// ---------------------------------------------------------------------------
// 4a. Weight convert + transpose: W fp32 [K][N] -> WT fp16 [N][K]
// ---------------------------------------------------------------------------
__global__ __launch_bounds__(256) void convertT_kernel(
    const float* __restrict__ W, unsigned short* __restrict__ WT, int K, int N)
{
    __shared__ unsigned short t[64][68];
    const int tid = threadIdx.x;
    const int k0 = blockIdx.y * 64, n0 = blockIdx.x * 64;
    const int r = tid >> 4, c4 = (tid & 15) * 4;
    #pragma unroll
    for (int s = 0; s < 4; ++s) {
        const int rr = r + s * 16;
        const float4 v = *reinterpret_cast<const float4*>(&W[(size_t)(k0 + rr) * N + n0 + c4]);
        t[rr][c4 + 0] = f2h(v.x);
        t[rr][c4 + 1] = f2h(v.y);
        t[rr][c4 + 2] = f2h(v.z);
        t[rr][c4 + 3] = f2h(v.w);
    }
    __syncthreads();
    #pragma unroll
    for (int s = 0; s < 4; ++s) {
        const int rn = r + s * 16;
        ushort4 o;
        o.x = t[c4 + 0][rn];
        o.y = t[c4 + 1][rn];
        o.z = t[c4 + 2][rn];
        o.w = t[c4 + 3][rn];
        *reinterpret_cast<ushort4*>(&WT[(size_t)(n0 + rn) * K + k0 + c4]) = o;
    }
}

// ---------------------------------------------------------------------------
// 4b. fp16 MFMA GEMM. MODE 0: f32 out (Cf, +RES/RELU). MODE 1: f16 out (Ch).
//     MODE 2: qkv special — cols [0,2048) -> f16 qk; cols [2048,3072) -> V^T.
//     MODE 4: split-K atomic accumulate into Cf (bias added by z==0 blocks);
//             K-range [z*K/gridDim.z, (z+1)*K/gridDim.z).
// ---------------------------------------------------------------------------
template<int RELU, int RES, int MODE>
__global__ __launch_bounds__(256) void gemm_f16_kernel(
    const unsigned short* __restrict__ A,   // [M][K] fp16
    const unsigned short* __restrict__ BT,  // [N][K] fp16
    const float* __restrict__ bias,
    float* __restrict__ Cf, unsigned short* __restrict__ Ch,
    unsigned short* __restrict__ Cv,
    int M, int N, int K)
{
    __shared__ __align__(16) unsigned short As[128 * 32];
    __shared__ __align__(16) unsigned short Bs[128 * 32];
    const int tid = threadIdx.x;
    const int lane = tid & 63;
    const int wv   = tid >> 6;
    const int wr = wv >> 1, wc = wv & 1;
    const int bm = blockIdx.y * 128;
    const int bn = blockIdx.x * 128;
    // split-K range (gridDim.z == 1 for non-split launches)
    const int ksz  = K / gridDim.z;
    const int kbeg = blockIdx.z * ksz;

    const int r0 = tid >> 2;
    const int gs = (tid & 3) ^ ((r0 >> 2) & 3);
    const size_t arow0 = (size_t)(bm + r0) * K;
    const size_t arow1 = (size_t)(bm + 64 + r0) * K;
    const size_t brow0 = (size_t)(bn + r0) * K;
    const size_t brow1 = (size_t)(bn + 64 + r0) * K;

    const int fr = lane & 15;
    const int kb = lane >> 4;
    const int sw = (kb ^ ((fr >> 2) & 3)) * 8;

    f32x4 acc[4][4] = {};

    for (int k0 = kbeg; k0 < kbeg + ksz; k0 += 32) {
        __syncthreads();
        gload_lds16(A  + arow0 + k0 + gs * 8, (char*)As + wv * 1024);
        gload_lds16(A  + arow1 + k0 + gs * 8, (char*)As + 4096 + wv * 1024);
        gload_lds16(BT + brow0 + k0 + gs * 8, (char*)Bs + wv * 1024);
        gload_lds16(BT + brow1 + k0 + gs * 8, (char*)Bs + 4096 + wv * 1024);
        __syncthreads();

        f16x8 a[4], b[4];
        #pragma unroll
        for (int m = 0; m < 4; ++m)
            a[m] = *reinterpret_cast<const f16x8*>(&As[(wr * 64 + m * 16 + fr) * 32 + sw]);
        #pragma unroll
        for (int n = 0; n < 4; ++n)
            b[n] = *reinterpret_cast<const f16x8*>(&Bs[(wc * 64 + n * 16 + fr) * 32 + sw]);
        #pragma unroll
        for (int m = 0; m < 4; ++m)
            #pragma unroll
            for (int n = 0; n < 4; ++n)
                acc[m][n] = __builtin_amdgcn_mfma_f32_16x16x32_f16(a[m], b[n], acc[m][n], 0, 0, 0);
    }

    const int fq = lane >> 4;
    if (MODE == 4) {                 // split-K atomic accumulate (RES via x)
        const bool addb = (blockIdx.z == 0);
        #pragma unroll
        for (int n = 0; n < 4; ++n) {
            const int c = bn + wc * 64 + n * 16 + fr;
            const float bv = addb ? bias[c] : 0.f;
            #pragma unroll
            for (int m = 0; m < 4; ++m) {
                #pragma unroll
                for (int j = 0; j < 4; ++j) {
                    const int r = bm + wr * 64 + m * 16 + fq * 4 + j;
                    atomicAdd(&Cf[(size_t)r * N + c], acc[m][n][j] + bv);
                }
            }
        }
        return;
    }
    if (MODE == 2) {
        if (bn < 2 * kC) {          // Q,K region -> qk f16 [row][2048]
            #pragma unroll
            for (int n = 0; n < 4; ++n) {
                const int c = bn + wc * 64 + n * 16 + fr;
                const float bv = bias[c];
                #pragma unroll
                for (int m = 0; m < 4; ++m) {
                    #pragma unroll
                    for (int j = 0; j < 4; ++j) {
                        const int r = bm + wr * 64 + m * 16 + fq * 4 + j;
                        Ch[(size_t)r * (2 * kC) + c] = f2h(acc[m][n][j] + bv);
                    }
                }
            }
        } else {                    // V region -> vt[b][h][d][t] f16
            #pragma unroll
            for (int n = 0; n < 4; ++n) {
                const int c  = bn + wc * 64 + n * 16 + fr;
                const int cc = c - 2 * kC;
                const int hh = cc >> 6, dd = cc & 63;
                const float bv = bias[c];
                #pragma unroll
                for (int m = 0; m < 4; ++m) {
                    const int rr = bm + wr * 64 + m * 16 + fq * 4;
                    const int bb = rr >> 10, t0 = rr & 1023;
                    f16x4 pk;
                    #pragma unroll
                    for (int j = 0; j < 4; ++j) pk[j] = (_Float16)(acc[m][n][j] + bv);
                    *reinterpret_cast<f16x4*>(
                        &Cv[((size_t)(bb * kH + hh) * kDH + dd) * kL + t0]) = pk;
                }
            }
        }
        return;
    }
    #pragma unroll
    for (int n = 0; n < 4; ++n) {
        const int c = bn + wc * 64 + n * 16 + fr;
        const float bv = bias[c];
        #pragma unroll
        for (int m = 0; m < 4; ++m) {
            #pragma unroll
            for (int j = 0; j < 4; ++j) {
                const int r = bm + wr * 64 + m * 16 + fq * 4 + j;
                float v = acc[m][n][j] + bv;
                if (RES)  v += Cf[(size_t)r * N + c];
                if (RELU) v = fmaxf(v, 0.f);
                if (MODE == 1) Ch[(size_t)r * N + c] = f2h(v);
                else           Cf[(size_t)r * N + c] = v;
            }
        }
    }
}

// ---------------------------------------------------------------------------
// 5. MFMA flash attention (unchanged from round 5)
// ---------------------------------------------------------------------------
__device__ __forceinline__ int swz(int row, int slot) {
    return row * 64 + ((slot ^ (row & 7)) * 8);   // ushort index, 16B-aligned
}

__global__ __launch_bounds__(256) void attn_mfma_kernel(
    const unsigned short* __restrict__ qk,   // [2048][2048] f16 (Q | K)
    const unsigned short* __restrict__ vt,   // [2][16][64][1024] f16  V^T
    unsigned short* __restrict__ o)          // [2048][1024] f16
{
    const int bid = blockIdx.x;            // 512 blocks
    const int bh  = bid & 31;
    const int qb  = ((bid >> 5) + bh) & 15;   // shear: balance causal work
    const int b   = bh >> 4;
    const int h   = bh & 15;
    const int tid  = threadIdx.x;
    const int lane = tid & 63;
    const int wv   = tid >> 6;
    const int fr = lane & 15;              // q index within wave
    const int g  = lane >> 4;              // k-group

    __shared__ __align__(16) unsigned short Qs[64 * 64];
    __shared__ __align__(16) unsigned short Ks[64 * 64];
    __shared__ __align__(16) unsigned short Vts[64 * 64];
    __shared__ __align__(16) unsigned short Ps[64 * 64];

    const int qlo = qb * 64;

    {
        const int r = tid >> 2, s = tid & 3;
        const unsigned short* qg = &qk[(size_t)(b * kL + qlo + r) * (2 * kC) + h * kDH];
        f16x8 v0 = *reinterpret_cast<const f16x8*>(&qg[s * 8]);
        f16x8 v1 = *reinterpret_cast<const f16x8*>(&qg[(s + 4) * 8]);
        #pragma unroll
        for (int i = 0; i < 8; ++i) { v0[i] *= (_Float16)0.125f; v1[i] *= (_Float16)0.125f; }
        *reinterpret_cast<f16x8*>(&Qs[swz(r, s)])     = v0;
        *reinterpret_cast<f16x8*>(&Qs[swz(r, s + 4)]) = v1;
    }
    __syncthreads();

    f16x8 qfrag[2];
    #pragma unroll
    for (int kf = 0; kf < 2; ++kf)
        qfrag[kf] = *reinterpret_cast<const f16x8*>(&Qs[swz(wv * 16 + fr, kf * 4 + g)]);

    float m = -INFINITY, l = 0.f;
    f32x4 acc_o[4] = {};
    const int qg_row = qlo + wv * 16 + fr;

    for (int k0 = 0; k0 <= qlo; k0 += 64) {
        __syncthreads();
        {
            const int r = tid >> 2, s = tid & 3;
            const unsigned short* kg = &qk[(size_t)(b * kL + k0 + r) * (2 * kC) + kC + h * kDH];
            *reinterpret_cast<f16x8*>(&Ks[swz(r, s)])     = *reinterpret_cast<const f16x8*>(&kg[s * 8]);
            *reinterpret_cast<f16x8*>(&Ks[swz(r, s + 4)]) = *reinterpret_cast<const f16x8*>(&kg[(s + 4) * 8]);
            const unsigned short* vg = &vt[((size_t)(b * kH + h) * kDH + r) * kL + k0];
            *reinterpret_cast<f16x8*>(&Vts[swz(r, s)])     = *reinterpret_cast<const f16x8*>(&vg[s * 8]);
            *reinterpret_cast<f16x8*>(&Vts[swz(r, s + 4)]) = *reinterpret_cast<const f16x8*>(&vg[(s + 4) * 8]);
        }
        __syncthreads();

        f32x4 acc_s[4] = {};
        #pragma unroll
        for (int kf = 0; kf < 2; ++kf) {
            const f16x8 qf = qfrag[kf];
            #pragma unroll
            for (int n = 0; n < 4; ++n) {
                const f16x8 kfr = *reinterpret_cast<const f16x8*>(&Ks[swz(n * 16 + fr, kf * 4 + g)]);
                acc_s[n] = __builtin_amdgcn_mfma_f32_16x16x32_f16(kfr, qf, acc_s[n], 0, 0, 0);
            }
        }

        if (k0 == qlo) {
            #pragma unroll
            for (int n = 0; n < 4; ++n)
                #pragma unroll
                for (int j = 0; j < 4; ++j)
                    if (k0 + n * 16 + g * 4 + j > qg_row) acc_s[n][j] = -INFINITY;
        }

        float mx = -INFINITY;
        #pragma unroll
        for (int n = 0; n < 4; ++n)
            #pragma unroll
            for (int j = 0; j < 4; ++j) mx = fmaxf(mx, acc_s[n][j]);
        mx = fmaxf(mx, __shfl_xor(mx, 16));
        mx = fmaxf(mx, __shfl_xor(mx, 32));
        const float mn  = fmaxf(m, mx);
        const float fac = __expf(m - mn);
        float p[4][4];
        float psum = 0.f;
        #pragma unroll
        for (int n = 0; n < 4; ++n)
            #pragma unroll
            for (int j = 0; j < 4; ++j) { p[n][j] = __expf(acc_s[n][j] - mn); psum += p[n][j]; }
        psum += __shfl_xor(psum, 16);
        psum += __shfl_xor(psum, 32);
        l = l * fac + psum;
        m = mn;
        #pragma unroll
        for (int dt = 0; dt < 4; ++dt)
            #pragma unroll
            for (int j = 0; j < 4; ++j) acc_o[dt][j] *= fac;

        #pragma unroll
        for (int n = 0; n < 4; ++n) {
            f16x4 pk;
            #pragma unroll
            for (int j = 0; j < 4; ++j) pk[j] = (_Float16)p[n][j];
            *reinterpret_cast<f16x4*>(&Ps[swz(wv * 16 + fr, 2 * n + (g >> 1)) + (g & 1) * 4]) = pk;
        }

        #pragma unroll
        for (int kf = 0; kf < 2; ++kf) {
            const f16x8 pf = *reinterpret_cast<const f16x8*>(&Ps[swz(wv * 16 + fr, kf * 4 + g)]);
            #pragma unroll
            for (int dt = 0; dt < 4; ++dt) {
                const f16x8 vf = *reinterpret_cast<const f16x8*>(&Vts[swz(dt * 16 + fr, kf * 4 + g)]);
                acc_o[dt] = __builtin_amdgcn_mfma_f32_16x16x32_f16(vf, pf, acc_o[dt], 0, 0, 0);
            }
        }
    }

    const float rl = 1.f / l;
    unsigned short* ob = &o[(size_t)(b * kL + qg_row) * kC + h * kDH];
    #pragma unroll
    for (int dt = 0; dt < 4; ++dt) {
        f16x4 pk;
        #pragma unroll
        for (int j = 0; j < 4; ++j) pk[j] = (_Float16)(acc_o[dt][j] * rl);
        *reinterpret_cast<f16x4*>(&ob[dt * 16 + g * 4]) = pk;
    }
}

// ---------------------------------------------------------------------------
// 6. Final tanh (in place on d_out)
// ---------------------------------------------------------------------------
__global__ __launch_bounds__(256) void tanh_kernel(float* __restrict__ x)
{
    const size_t i = ((size_t)blockIdx.x * 256 + threadIdx.x) * 4;
    float4 v = *reinterpret_cast<float4*>(&x[i]);
    v.x = tanhf(v.x); v.y = tanhf(v.y); v.z = tanhf(v.z); v.w = tanhf(v.w);
    *reinterpret_cast<float4*>(&x[i]) = v;
}

// ---------------------------------------------------------------------------
extern "C" void kernel_launch(void* const* d_in, const int* in_sizes, int n_in,
                              void* d_out, int out_size, void* d_ws, size_t ws_size,
                              hipStream_t stream)
{
    (void)in_sizes; (void)n_in; (void)out_size; (void)ws_size;
    const float* obs    = (const float*)d_in[0];
    const float* act    = (const float*)d_in[1];
    const float* rew    = (const float*)d_in[2];
    const float* obs_W  = (const float*)d_in[3];
    const float* obs_b  = (const float*)d_in[4];
    const float* act_W  = (const float*)d_in[5];
    const float* act_b  = (const float*)d_in[6];
    const float* rew_W  = (const float*)d_in[7];
    const float* rew_b  = (const float*)d_in[8];
    const float* tr_W   = (const float*)d_in[9];
    const float* tr_b   = (const float*)d_in[10];
    const float* bn_g   = (const float*)d_in[11];
    const float* bn_b   = (const float*)d_in[12];
    const float* ln1_w  = (const float*)d_in[13];
    const float* ln1_b  = (const float*)d_in[14];
    const float* qkv_W  = (const float*)d_in[15];
    const float* qkv_b  = (const float*)d_in[16];
    const float* out_W  = (const float*)d_in[17];
    const float* out_b  = (const float*)d_in[18];
    const float* ln2_w  = (const float*)d_in[19];
    const float* ln2_b  = (const float*)d_in[20];
    const float* fc_W   = (const float*)d_in[21];
    const float* fc_b   = (const float*)d_in[22];
    const float* pj_W   = (const float*)d_in[23];
    const float* pj_b   = (const float*)d_in[24];

    float* x  = (float*)d_out;                     // fp32 residual stream
    float* ws = (float*)d_ws;
    float* tm   = ws;                              // 64
    float* tv   = ws + 64;                         // 64
    unsigned short* wbuf  = (unsigned short*)(ws + 128);  // 12.58M f16 weights
    unsigned short* h_hf  = wbuf + 12582912;       // 2048*1024
    unsigned short* ao_hf = h_hf + (size_t)kRows * kC;    // 2048*1024
    unsigned short* ff_hf = ao_hf + (size_t)kRows * kC;   // 2048*4096
    unsigned short* qk_hf = ff_hf + (size_t)kRows * kFF;  // 2048*2048
    unsigned short* vt_hf = qk_hf + (size_t)kRows * 2 * kC; // 2*16*64*1024
    unsigned short* qWT = wbuf;                    // [3072][1024]
    unsigned short* oWT = qWT + 3 * kC * kC;       // [1024][1024]
    unsigned short* fWT = oWT + kC * kC;           // [4096][1024]
    unsigned short* pWT = fWT + kC * kFF;          // [1024][4096]

    tran_stats_kernel<<<kOBS, 256, 0, stream>>>(obs, tm, tv);
    encode_kernel<<<kRows, 256, 0, stream>>>(obs, act, rew,
        obs_W, obs_b, act_W, act_b, rew_W, rew_b, tr_W, tr_b, bn_g, bn_b, tm, tv, x);

    for (int lyr = 0; lyr < kNL; ++lyr) {
        const float* qW = qkv_W + (size_t)lyr * kC * 3 * kC;
        const float* qB = qkv_b + (size_t)lyr * 3 * kC;
        const float* oW = out_W + (size_t)lyr * kC * kC;
        const float* oB = out_b + (size_t)lyr * kC;
        const float* fW = fc_W + (size_t)lyr * kC * kFF;
        const float* fB = fc_b + (size_t)lyr * kFF;
        const float* pW = pj_W + (size_t)lyr * kFF * kC;
        const float* pB = pj_b + (size_t)lyr * kC;

        convertT_kernel<<<dim3(3 * kC / 64, kC / 64), 256, 0, stream>>>(qW, qWT, kC, 3 * kC);
        convertT_kernel<<<dim3(kC / 64, kC / 64),     256, 0, stream>>>(oW, oWT, kC, kC);
        convertT_kernel<<<dim3(kFF / 64, kC / 64),    256, 0, stream>>>(fW, fWT, kC, kFF);
        convertT_kernel<<<dim3(kC / 64, kFF / 64),    256, 0, stream>>>(pW, pWT, kFF, kC);

        ln_kernel<<<kRows, 256, 0, stream>>>(x, ln1_w + lyr * kC, ln1_b + lyr * kC, h_hf);
        gemm_f16_kernel<0,0,2><<<dim3(3 * kC / 128, kRows / 128), 256, 0, stream>>>(
            h_hf, qWT, qB, nullptr, qk_hf, vt_hf, kRows, 3 * kC, kC);
        attn_mfma_kernel<<<dim3(512), 256, 0, stream>>>(qk_hf, vt_hf, ao_hf);
        // out projection: split-K=4, atomic accumulate into residual stream
        gemm_f16_kernel<0,0,4><<<dim3(kC / 128, kRows / 128, 4), 256, 0, stream>>>(
            ao_hf, oWT, oB, x, nullptr, nullptr, kRows, kC, kC);
        ln_kernel<<<kRows, 256, 0, stream>>>(x, ln2_w + lyr * kC, ln2_b + lyr * kC, h_hf);
        gemm_f16_kernel<1,0,1><<<dim3(kFF / 128, kRows / 128), 256, 0, stream>>>(
            h_hf, fWT, fB, nullptr, ff_hf, nullptr, kRows, kFF, kC);
        // pj projection: split-K=4, atomic accumulate into residual stream
        gemm_f16_kernel<0,0,4><<<dim3(kC / 128, kRows / 128, 4), 256, 0, stream>>>(
            ff_hf, pWT, pB, x, nullptr, nullptr, kRows, kC, kFF);
    }
    tanh_kernel<<<kRows * kC / 1024, 256, 0, stream>>>(x);
}

// Round 7
// 770.287 us; speedup vs baseline: 7.8654x; 1.0330x over previous
//
#include <hip/hip_runtime.h>
#include <hip/hip_bf16.h>
#include <math.h>

// Problem constants
constexpr int kB   = 2;
constexpr int kL   = 1024;
constexpr int kOBS = 64;
constexpr int kACT = 16;
constexpr int kC   = 1024;
constexpr int kH   = 16;
constexpr int kDH  = 64;
constexpr int kFF  = 4096;
constexpr int kNL  = 4;
constexpr int kRows = kB * kL;          // 2048
constexpr int kOE = 512, kAE = 256, kRE = 128, kTE = 128;

typedef _Float16 f16x8 __attribute__((ext_vector_type(8)));
typedef _Float16 f16x4 __attribute__((ext_vector_type(4)));
typedef float    f32x4 __attribute__((ext_vector_type(4)));

__device__ __forceinline__ unsigned short f2h(float x) {
    return __builtin_bit_cast(unsigned short, (_Float16)x);
}
__device__ __forceinline__ void gload_lds16(const void* g, void* l) {
    __builtin_amdgcn_global_load_lds(
        (const __attribute__((address_space(1))) unsigned int*)g,
        (__attribute__((address_space(3))) unsigned int*)l, 16, 0, 0);
}

// ---------------------------------------------------------------------------
// 1. Transition batchnorm stats
// ---------------------------------------------------------------------------
__global__ __launch_bounds__(256) void tran_stats_kernel(
    const float* __restrict__ obs, float* __restrict__ tm, float* __restrict__ tv)
{
    const int f = blockIdx.x;
    const int tid = threadIdx.x;
    float sum = 0.f, sq = 0.f;
    for (int r = tid; r < kRows; r += 256) {
        const int t = r & (kL - 1);
        float d = 0.f;
        if (t > 0) {
            const float cur  = obs[(size_t)r * kOBS + f];
            const float prev = obs[(size_t)(r - 1) * kOBS + f];
            d = cur - prev;
        }
        sum += d; sq += d * d;
    }
    for (int off = 32; off > 0; off >>= 1) {
        sum += __shfl_down(sum, off);
        sq  += __shfl_down(sq, off);
    }
    __shared__ float sa[4], sb[4];
    if ((tid & 63) == 0) { sa[tid >> 6] = sum; sb[tid >> 6] = sq; }
    __syncthreads();
    if (tid == 0) {
        const float ts = sa[0] + sa[1] + sa[2] + sa[3];
        const float tq = sb[0] + sb[1] + sb[2] + sb[3];
        const float m = ts / (float)kRows;
        tm[f] = m;
        tv[f] = tq / (float)kRows - m * m;
    }
}

// ---------------------------------------------------------------------------
// 2. Encoder (writes fp32 residual stream)
// ---------------------------------------------------------------------------
__global__ __launch_bounds__(256) void encode_kernel(
    const float* __restrict__ obs, const float* __restrict__ act, const float* __restrict__ rew,
    const float* __restrict__ obs_W, const float* __restrict__ obs_b,
    const float* __restrict__ act_W, const float* __restrict__ act_b,
    const float* __restrict__ rew_W, const float* __restrict__ rew_b,
    const float* __restrict__ tr_W,  const float* __restrict__ tr_b,
    const float* __restrict__ bn_g,  const float* __restrict__ bn_b,
    const float* __restrict__ tm,    const float* __restrict__ tv,
    float* __restrict__ enc)
{
    const int row = blockIdx.x;
    const int t = row & (kL - 1);
    const int tid = threadIdx.x;
    __shared__ float s_obs2[kOBS];
    __shared__ float s_tran[kOBS];
    __shared__ float s_act[kACT];
    __shared__ float s_rew;
    if (tid < kOBS) {
        const float cur  = obs[(size_t)row * kOBS + tid];
        const float prev = (t > 0) ? obs[(size_t)(row - 1) * kOBS + tid] : cur;
        s_obs2[tid] = prev;
        const float tr = cur - prev;
        s_tran[tid] = (tr - tm[tid]) * rsqrtf(tv[tid] + 1e-5f) * bn_g[tid] + bn_b[tid];
    } else if (tid < kOBS + kACT) {
        s_act[tid - kOBS] = act[(size_t)row * kACT + (tid - kOBS)];
    } else if (tid == kOBS + kACT) {
        s_rew = rew[row];
    }
    __syncthreads();
    float* er = enc + (size_t)row * kC;
    #pragma unroll
    for (int s = 0; s < 4; ++s) {
        const int c = tid + s * 256;
        float v;
        if (c < kOE) {
            v = obs_b[c];
            #pragma unroll
            for (int k = 0; k < kOBS; ++k) v += s_obs2[k] * obs_W[k * kOE + c];
        } else if (c < kOE + kAE) {
            const int cc = c - kOE;
            v = act_b[cc];
            #pragma unroll
            for (int k = 0; k < kACT; ++k) v += s_act[k] * act_W[k * kAE + cc];
        } else if (c < kOE + kAE + kRE) {
            const int cc = c - (kOE + kAE);
            v = s_rew * rew_W[cc] + rew_b[cc];
        } else {
            const int cc = c - (kOE + kAE + kRE);
            v = tr_b[cc];
            #pragma unroll
            for (int k = 0; k < kOBS; ++k) v += s_tran[k] * tr_W[k * kTE + cc];
        }
        er[c] = v;
    }
}

// ---------------------------------------------------------------------------
// 3. LayerNorm: fp32 in -> fp16 out
// ---------------------------------------------------------------------------
__global__ __launch_bounds__(256) void ln_kernel(
    const float* __restrict__ x, const float* __restrict__ w,
    const float* __restrict__ b, unsigned short* __restrict__ out)
{
    const int row = blockIdx.x;
    const int tid = threadIdx.x;
    const float4 xv = *reinterpret_cast<const float4*>(&x[(size_t)row * kC + tid * 4]);
    float s = xv.x + xv.y + xv.z + xv.w;
    float q = xv.x * xv.x + xv.y * xv.y + xv.z * xv.z + xv.w * xv.w;
    for (int off = 32; off > 0; off >>= 1) {
        s += __shfl_down(s, off);
        q += __shfl_down(q, off);
    }
    __shared__ float sa[4], sb[4];
    if ((tid & 63) == 0) { sa[tid >> 6] = s; sb[tid >> 6] = q; }
    __syncthreads();
    const float ts = sa[0] + sa[1] + sa[2] + sa[3];
    const float tq = sb[0] + sb[1] + sb[2] + sb[3];
    const float mean = ts * (1.f / kC);
    const float var  = tq * (1.f / kC) - mean * mean;
    const float rstd = rsqrtf(var + 1e-5f);
    const float4 wv = *reinterpret_cast<const float4*>(&w[tid * 4]);
    const float4 bv = *reinterpret_cast<const float4*>(&b[tid * 4]);
    ushort4 o;
    o.x = f2h((xv.x - mean) * rstd * wv.x + bv.x);
    o.y = f2h((xv.y - mean) * rstd * wv.y + bv.y);
    o.z = f2h((xv.z - mean) * rstd * wv.z + bv.z);
    o.w = f2h((xv.w - mean) * rstd * wv.w + bv.w);
    *reinterpret_cast<ushort4*>(&out[(size_t)row * kC + tid * 4]) = o;
}

// ---------------------------------------------------------------------------
// 4a. Weight convert + transpose: W fp32 [K][N] -> WT fp16 [N][K]
// ---------------------------------------------------------------------------
__global__ __launch_bounds__(256) void convertT_kernel(
    const float* __restrict__ W, unsigned short* __restrict__ WT, int K, int N)
{
    __shared__ unsigned short t[64][68];
    const int tid = threadIdx.x;
    const int k0 = blockIdx.y * 64, n0 = blockIdx.x * 64;
    const int r = tid >> 4, c4 = (tid & 15) * 4;
    #pragma unroll
    for (int s = 0; s < 4; ++s) {
        const int rr = r + s * 16;
        const float4 v = *reinterpret_cast<const float4*>(&W[(size_t)(k0 + rr) * N + n0 + c4]);
        t[rr][c4 + 0] = f2h(v.x);
        t[rr][c4 + 1] = f2h(v.y);
        t[rr][c4 + 2] = f2h(v.z);
        t[rr][c4 + 3] = f2h(v.w);
    }
    __syncthreads();
    #pragma unroll
    for (int s = 0; s < 4; ++s) {
        const int rn = r + s * 16;
        ushort4 o;
        o.x = t[c4 + 0][rn];
        o.y = t[c4 + 1][rn];
        o.z = t[c4 + 2][rn];
        o.w = t[c4 + 3][rn];
        *reinterpret_cast<ushort4*>(&WT[(size_t)(n0 + rn) * K + k0 + c4]) = o;
    }
}

// ---------------------------------------------------------------------------
// 4b. fp16 MFMA GEMM, 2-phase double-buffered LDS pipeline (T3 minimum recipe):
//     prologue-stage buf0; per K-step issue STAGE(next)->buf^1 BEFORE the
//     ds_read+MFMA of buf[cur]; single __syncthreads() (vmcnt(0)+barrier) per
//     step. Load latency hides under 16 MFMAs + 8 ds_read_b128.
//     MODE 0: f32 out (Cf, +RES/RELU). MODE 1: f16 out (Ch).
//     MODE 2: qkv special — cols [0,2048) -> f16 qk; cols [2048,3072) -> V^T.
//     MODE 4: split-K atomic accumulate into Cf (bias added by z==0 blocks).
// ---------------------------------------------------------------------------
template<int RELU, int RES, int MODE>
__global__ __launch_bounds__(256) void gemm_f16_kernel(
    const unsigned short* __restrict__ A,   // [M][K] fp16
    const unsigned short* __restrict__ BT,  // [N][K] fp16
    const float* __restrict__ bias,
    float* __restrict__ Cf, unsigned short* __restrict__ Ch,
    unsigned short* __restrict__ Cv,
    int M, int N, int K)
{
    __shared__ __align__(16) unsigned short As[2][128 * 32];
    __shared__ __align__(16) unsigned short Bs[2][128 * 32];
    const int tid = threadIdx.x;
    const int lane = tid & 63;
    const int wv   = tid >> 6;
    const int wr = wv >> 1, wc = wv & 1;
    const int bm = blockIdx.y * 128;
    const int bn = blockIdx.x * 128;
    // split-K range (gridDim.z == 1 for non-split launches)
    const int ksz  = K / gridDim.z;
    const int kbeg = blockIdx.z * ksz;
    const int kend = kbeg + ksz;

    const int r0 = tid >> 2;
    const int gs = (tid & 3) ^ ((r0 >> 2) & 3);
    const size_t arow0 = (size_t)(bm + r0) * K;
    const size_t arow1 = (size_t)(bm + 64 + r0) * K;
    const size_t brow0 = (size_t)(bn + r0) * K;
    const size_t brow1 = (size_t)(bn + 64 + r0) * K;

    const int fr = lane & 15;
    const int kb = lane >> 4;
    const int sw = (kb ^ ((fr >> 2) & 3)) * 8;

    auto stage = [&](int k0, int buf) {
        gload_lds16(A  + arow0 + k0 + gs * 8, (char*)&As[buf][0] + wv * 1024);
        gload_lds16(A  + arow1 + k0 + gs * 8, (char*)&As[buf][0] + 4096 + wv * 1024);
        gload_lds16(BT + brow0 + k0 + gs * 8, (char*)&Bs[buf][0] + wv * 1024);
        gload_lds16(BT + brow1 + k0 + gs * 8, (char*)&Bs[buf][0] + 4096 + wv * 1024);
    };

    f32x4 acc[4][4] = {};

    stage(kbeg, 0);
    __syncthreads();                 // prologue loads resident
    int cur = 0;
    for (int k0 = kbeg; k0 < kend; k0 += 32) {
        if (k0 + 32 < kend) stage(k0 + 32, cur ^ 1);   // prefetch next tile

        f16x8 a[4], b[4];
        #pragma unroll
        for (int m = 0; m < 4; ++m)
            a[m] = *reinterpret_cast<const f16x8*>(&As[cur][(wr * 64 + m * 16 + fr) * 32 + sw]);
        #pragma unroll
        for (int n = 0; n < 4; ++n)
            b[n] = *reinterpret_cast<const f16x8*>(&Bs[cur][(wc * 64 + n * 16 + fr) * 32 + sw]);
        #pragma unroll
        for (int m = 0; m < 4; ++m)
            #pragma unroll
            for (int n = 0; n < 4; ++n)
                acc[m][n] = __builtin_amdgcn_mfma_f32_16x16x32_f16(a[m], b[n], acc[m][n], 0, 0, 0);

        __syncthreads();             // vmcnt(0)+lgkmcnt(0)+barrier: next buf ready
        cur ^= 1;
    }

    const int fq = lane >> 4;
    if (MODE == 4) {                 // split-K atomic accumulate (RES via x)
        const bool addb = (blockIdx.z == 0);
        #pragma unroll
        for (int n = 0; n < 4; ++n) {
            const int c = bn + wc * 64 + n * 16 + fr;
            const float bv = addb ? bias[c] : 0.f;
            #pragma unroll
            for (int m = 0; m < 4; ++m) {
                #pragma unroll
                for (int j = 0; j < 4; ++j) {
                    const int r = bm + wr * 64 + m * 16 + fq * 4 + j;
                    atomicAdd(&Cf[(size_t)r * N + c], acc[m][n][j] + bv);
                }
            }
        }
        return;
    }
    if (MODE == 2) {
        if (bn < 2 * kC) {          // Q,K region -> qk f16 [row][2048]
            #pragma unroll
            for (int n = 0; n < 4; ++n) {
                const int c = bn + wc * 64 + n * 16 + fr;
                const float bv = bias[c];
                #pragma unroll
                for (int m = 0; m < 4; ++m) {
                    #pragma unroll
                    for (int j = 0; j < 4; ++j) {
                        const int r = bm + wr * 64 + m * 16 + fq * 4 + j;
                        Ch[(size_t)r * (2 * kC) + c] = f2h(acc[m][n][j] + bv);
                    }
                }
            }
        } else {                    // V region -> vt[b][h][d][t] f16
            #pragma unroll
            for (int n = 0; n < 4; ++n) {
                const int c  = bn + wc * 64 + n * 16 + fr;
                const int cc = c - 2 * kC;
                const int hh = cc >> 6, dd = cc & 63;
                const float bv = bias[c];
                #pragma unroll
                for (int m = 0; m < 4; ++m) {
                    const int rr = bm + wr * 64 + m * 16 + fq * 4;
                    const int bb = rr >> 10, t0 = rr & 1023;
                    f16x4 pk;
                    #pragma unroll
                    for (int j = 0; j < 4; ++j) pk[j] = (_Float16)(acc[m][n][j] + bv);
                    *reinterpret_cast<f16x4*>(
                        &Cv[((size_t)(bb * kH + hh) * kDH + dd) * kL + t0]) = pk;
                }
            }
        }
        return;
    }
    #pragma unroll
    for (int n = 0; n < 4; ++n) {
        const int c = bn + wc * 64 + n * 16 + fr;
        const float bv = bias[c];
        #pragma unroll
        for (int m = 0; m < 4; ++m) {
            #pragma unroll
            for (int j = 0; j < 4; ++j) {
                const int r = bm + wr * 64 + m * 16 + fq * 4 + j;
                float v = acc[m][n][j] + bv;
                if (RES)  v += Cf[(size_t)r * N + c];
                if (RELU) v = fmaxf(v, 0.f);
                if (MODE == 1) Ch[(size_t)r * N + c] = f2h(v);
                else           Cf[(size_t)r * N + c] = v;
            }
        }
    }
}

// ---------------------------------------------------------------------------
// 5. MFMA flash attention (unchanged)
// ---------------------------------------------------------------------------
__device__ __forceinline__ int swz(int row, int slot) {
    return row * 64 + ((slot ^ (row & 7)) * 8);   // ushort index, 16B-aligned
}

__global__ __launch_bounds__(256) void attn_mfma_kernel(
    const unsigned short* __restrict__ qk,   // [2048][2048] f16 (Q | K)
    const unsigned short* __restrict__ vt,   // [2][16][64][1024] f16  V^T
    unsigned short* __restrict__ o)          // [2048][1024] f16
{
    const int bid = blockIdx.x;            // 512 blocks
    const int bh  = bid & 31;
    const int qb  = ((bid >> 5) + bh) & 15;   // shear: balance causal work
    const int b   = bh >> 4;
    const int h   = bh & 15;
    const int tid  = threadIdx.x;
    const int lane = tid & 63;
    const int wv   = tid >> 6;
    const int fr = lane & 15;              // q index within wave
    const int g  = lane >> 4;              // k-group

    __shared__ __align__(16) unsigned short Qs[64 * 64];
    __shared__ __align__(16) unsigned short Ks[64 * 64];
    __shared__ __align__(16) unsigned short Vts[64 * 64];
    __shared__ __align__(16) unsigned short Ps[64 * 64];

    const int qlo = qb * 64;

    {
        const int r = tid >> 2, s = tid & 3;
        const unsigned short* qg = &qk[(size_t)(b * kL + qlo + r) * (2 * kC) + h * kDH];
        f16x8 v0 = *reinterpret_cast<const f16x8*>(&qg[s * 8]);
        f16x8 v1 = *reinterpret_cast<const f16x8*>(&qg[(s + 4) * 8]);
        #pragma unroll
        for (int i = 0; i < 8; ++i) { v0[i] *= (_Float16)0.125f; v1[i] *= (_Float16)0.125f; }
        *reinterpret_cast<f16x8*>(&Qs[swz(r, s)])     = v0;
        *reinterpret_cast<f16x8*>(&Qs[swz(r, s + 4)]) = v1;
    }
    __syncthreads();

    f16x8 qfrag[2];
    #pragma unroll
    for (int kf = 0; kf < 2; ++kf)
        qfrag[kf] = *reinterpret_cast<const f16x8*>(&Qs[swz(wv * 16 + fr, kf * 4 + g)]);

    float m = -INFINITY, l = 0.f;
    f32x4 acc_o[4] = {};
    const int qg_row = qlo + wv * 16 + fr;

    for (int k0 = 0; k0 <= qlo; k0 += 64) {
        __syncthreads();
        {
            const int r = tid >> 2, s = tid & 3;
            const unsigned short* kg = &qk[(size_t)(b * kL + k0 + r) * (2 * kC) + kC + h * kDH];
            *reinterpret_cast<f16x8*>(&Ks[swz(r, s)])     = *reinterpret_cast<const f16x8*>(&kg[s * 8]);
            *reinterpret_cast<f16x8*>(&Ks[swz(r, s + 4)]) = *reinterpret_cast<const f16x8*>(&kg[(s + 4) * 8]);
            const unsigned short* vg = &vt[((size_t)(b * kH + h) * kDH + r) * kL + k0];
            *reinterpret_cast<f16x8*>(&Vts[swz(r, s)])     = *reinterpret_cast<const f16x8*>(&vg[s * 8]);
            *reinterpret_cast<f16x8*>(&Vts[swz(r, s + 4)]) = *reinterpret_cast<const f16x8*>(&vg[(s + 4) * 8]);
        }
        __syncthreads();

        f32x4 acc_s[4] = {};
        #pragma unroll
        for (int kf = 0; kf < 2; ++kf) {
            const f16x8 qf = qfrag[kf];
            #pragma unroll
            for (int n = 0; n < 4; ++n) {
                const f16x8 kfr = *reinterpret_cast<const f16x8*>(&Ks[swz(n * 16 + fr, kf * 4 + g)]);
                acc_s[n] = __builtin_amdgcn_mfma_f32_16x16x32_f16(kfr, qf, acc_s[n], 0, 0, 0);
            }
        }

        if (k0 == qlo) {
            #pragma unroll
            for (int n = 0; n < 4; ++n)
                #pragma unroll
                for (int j = 0; j < 4; ++j)
                    if (k0 + n * 16 + g * 4 + j > qg_row) acc_s[n][j] = -INFINITY;
        }

        float mx = -INFINITY;
        #pragma unroll
        for (int n = 0; n < 4; ++n)
            #pragma unroll
            for (int j = 0; j < 4; ++j) mx = fmaxf(mx, acc_s[n][j]);
        mx = fmaxf(mx, __shfl_xor(mx, 16));
        mx = fmaxf(mx, __shfl_xor(mx, 32));
        const float mn  = fmaxf(m, mx);
        const float fac = __expf(m - mn);
        float p[4][4];
        float psum = 0.f;
        #pragma unroll
        for (int n = 0; n < 4; ++n)
            #pragma unroll
            for (int j = 0; j < 4; ++j) { p[n][j] = __expf(acc_s[n][j] - mn); psum += p[n][j]; }
        psum += __shfl_xor(psum, 16);
        psum += __shfl_xor(psum, 32);
        l = l * fac + psum;
        m = mn;
        #pragma unroll
        for (int dt = 0; dt < 4; ++dt)
            #pragma unroll
            for (int j = 0; j < 4; ++j) acc_o[dt][j] *= fac;

        #pragma unroll
        for (int n = 0; n < 4; ++n) {
            f16x4 pk;
            #pragma unroll
            for (int j = 0; j < 4; ++j) pk[j] = (_Float16)p[n][j];
            *reinterpret_cast<f16x4*>(&Ps[swz(wv * 16 + fr, 2 * n + (g >> 1)) + (g & 1) * 4]) = pk;
        }

        #pragma unroll
        for (int kf = 0; kf < 2; ++kf) {
            const f16x8 pf = *reinterpret_cast<const f16x8*>(&Ps[swz(wv * 16 + fr, kf * 4 + g)]);
            #pragma unroll
            for (int dt = 0; dt < 4; ++dt) {
                const f16x8 vf = *reinterpret_cast<const f16x8*>(&Vts[swz(dt * 16 + fr, kf * 4 + g)]);
                acc_o[dt] = __builtin_amdgcn_mfma_f32_16x16x32_f16(vf, pf, acc_o[dt], 0, 0, 0);
            }
        }
    }

    const float rl = 1.f / l;
    unsigned short* ob = &o[(size_t)(b * kL + qg_row) * kC + h * kDH];
    #pragma unroll
    for (int dt = 0; dt < 4; ++dt) {
        f16x4 pk;
        #pragma unroll
        for (int j = 0; j < 4; ++j) pk[j] = (_Float16)(acc_o[dt][j] * rl);
        *reinterpret_cast<f16x4*>(&ob[dt * 16 + g * 4]) = pk;
    }
}

// ---------------------------------------------------------------------------
// 6. Final tanh (in place on d_out)
// ---------------------------------------------------------------------------
__global__ __launch_bounds__(256) void tanh_kernel(float* __restrict__ x)
{
    const size_t i = ((size_t)blockIdx.x * 256 + threadIdx.x) * 4;
    float4 v = *reinterpret_cast<float4*>(&x[i]);
    v.x = tanhf(v.x); v.y = tanhf(v.y); v.z = tanhf(v.z); v.w = tanhf(v.w);
    *reinterpret_cast<float4*>(&x[i]) = v;
}

// ---------------------------------------------------------------------------
extern "C" void kernel_launch(void* const* d_in, const int* in_sizes, int n_in,
                              void* d_out, int out_size, void* d_ws, size_t ws_size,
                              hipStream_t stream)
{
    (void)in_sizes; (void)n_in; (void)out_size; (void)ws_size;
    const float* obs    = (const float*)d_in[0];
    const float* act    = (const float*)d_in[1];
    const float* rew    = (const float*)d_in[2];
    const float* obs_W  = (const float*)d_in[3];
    const float* obs_b  = (const float*)d_in[4];
    const float* act_W  = (const float*)d_in[5];
    const float* act_b  = (const float*)d_in[6];
    const float* rew_W  = (const float*)d_in[7];
    const float* rew_b  = (const float*)d_in[8];
    const float* tr_W   = (const float*)d_in[9];
    const float* tr_b   = (const float*)d_in[10];
    const float* bn_g   = (const float*)d_in[11];
    const float* bn_b   = (const float*)d_in[12];
    const float* ln1_w  = (const float*)d_in[13];
    const float* ln1_b  = (const float*)d_in[14];
    const float* qkv_W  = (const float*)d_in[15];
    const float* qkv_b  = (const float*)d_in[16];
    const float* out_W  = (const float*)d_in[17];
    const float* out_b  = (const float*)d_in[18];
    const float* ln2_w  = (const float*)d_in[19];
    const float* ln2_b  = (const float*)d_in[20];
    const float* fc_W   = (const float*)d_in[21];
    const float* fc_b   = (const float*)d_in[22];
    const float* pj_W   = (const float*)d_in[23];
    const float* pj_b   = (const float*)d_in[24];

    float* x  = (float*)d_out;                     // fp32 residual stream
    float* ws = (float*)d_ws;
    float* tm   = ws;                              // 64
    float* tv   = ws + 64;                         // 64
    unsigned short* wbuf  = (unsigned short*)(ws + 128);  // 12.58M f16 weights
    unsigned short* h_hf  = wbuf + 12582912;       // 2048*1024
    unsigned short* ao_hf = h_hf + (size_t)kRows * kC;    // 2048*1024
    unsigned short* ff_hf = ao_hf + (size_t)kRows * kC;   // 2048*4096
    unsigned short* qk_hf = ff_hf + (size_t)kRows * kFF;  // 2048*2048
    unsigned short* vt_hf = qk_hf + (size_t)kRows * 2 * kC; // 2*16*64*1024
    unsigned short* qWT = wbuf;                    // [3072][1024]
    unsigned short* oWT = qWT + 3 * kC * kC;       // [1024][1024]
    unsigned short* fWT = oWT + kC * kC;           // [4096][1024]
    unsigned short* pWT = fWT + kC * kFF;          // [1024][4096]

    tran_stats_kernel<<<kOBS, 256, 0, stream>>>(obs, tm, tv);
    encode_kernel<<<kRows, 256, 0, stream>>>(obs, act, rew,
        obs_W, obs_b, act_W, act_b, rew_W, rew_b, tr_W, tr_b, bn_g, bn_b, tm, tv, x);

    for (int lyr = 0; lyr < kNL; ++lyr) {
        const float* qW = qkv_W + (size_t)lyr * kC * 3 * kC;
        const float* qB = qkv_b + (size_t)lyr * 3 * kC;
        const float* oW = out_W + (size_t)lyr * kC * kC;
        const float* oB = out_b + (size_t)lyr * kC;
        const float* fW = fc_W + (size_t)lyr * kC * kFF;
        const float* fB = fc_b + (size_t)lyr * kFF;
        const float* pW = pj_W + (size_t)lyr * kFF * kC;
        const float* pB = pj_b + (size_t)lyr * kC;

        convertT_kernel<<<dim3(3 * kC / 64, kC / 64), 256, 0, stream>>>(qW, qWT, kC, 3 * kC);
        convertT_kernel<<<dim3(kC / 64, kC / 64),     256, 0, stream>>>(oW, oWT, kC, kC);
        convertT_kernel<<<dim3(kFF / 64, kC / 64),    256, 0, stream>>>(fW, fWT, kC, kFF);
        convertT_kernel<<<dim3(kC / 64, kFF / 64),    256, 0, stream>>>(pW, pWT, kFF, kC);

        ln_kernel<<<kRows, 256, 0, stream>>>(x, ln1_w + lyr * kC, ln1_b + lyr * kC, h_hf);
        gemm_f16_kernel<0,0,2><<<dim3(3 * kC / 128, kRows / 128), 256, 0, stream>>>(
            h_hf, qWT, qB, nullptr, qk_hf, vt_hf, kRows, 3 * kC, kC);
        attn_mfma_kernel<<<dim3(512), 256, 0, stream>>>(qk_hf, vt_hf, ao_hf);
        // out projection: split-K=4, atomic accumulate into residual stream
        gemm_f16_kernel<0,0,4><<<dim3(kC / 128, kRows / 128, 4), 256, 0, stream>>>(
            ao_hf, oWT, oB, x, nullptr, nullptr, kRows, kC, kC);
        ln_kernel<<<kRows, 256, 0, stream>>>(x, ln2_w + lyr * kC, ln2_b + lyr * kC, h_hf);
        gemm_f16_kernel<1,0,1><<<dim3(kFF / 128, kRows / 128), 256, 0, stream>>>(
            h_hf, fWT, fB, nullptr, ff_hf, nullptr, kRows, kFF, kC);
        // pj projection: split-K=4, atomic accumulate into residual stream
        gemm_f16_kernel<0,0,4><<<dim3(kC / 128, kRows / 128, 4), 256, 0, stream>>>(
            ff_hf, pWT, pB, x, nullptr, nullptr, kRows, kC, kFF);
    }
    tanh_kernel<<<kRows * kC / 1024, 256, 0, stream>>>(x);
}

// Round 8
// 694.130 us; speedup vs baseline: 8.7284x; 1.1097x over previous
//
#include <hip/hip_runtime.h>
#include <hip/hip_bf16.h>
#include <math.h>

// Problem constants
constexpr int kB   = 2;
constexpr int kL   = 1024;
constexpr int kOBS = 64;
constexpr int kACT = 16;
constexpr int kC   = 1024;
constexpr int kH   = 16;
constexpr int kDH  = 64;
constexpr int kFF  = 4096;
constexpr int kNL  = 4;
constexpr int kRows = kB * kL;          // 2048
constexpr int kOE = 512, kAE = 256, kRE = 128, kTE = 128;

typedef _Float16 f16x8 __attribute__((ext_vector_type(8)));
typedef _Float16 f16x4 __attribute__((ext_vector_type(4)));
typedef float    f32x4 __attribute__((ext_vector_type(4)));

__device__ __forceinline__ unsigned short f2h(float x) {
    return __builtin_bit_cast(unsigned short, (_Float16)x);
}
__device__ __forceinline__ void gload_lds16(const void* g, void* l) {
    __builtin_amdgcn_global_load_lds(
        (const __attribute__((address_space(1))) unsigned int*)g,
        (__attribute__((address_space(3))) unsigned int*)l, 16, 0, 0);
}

// ---------------------------------------------------------------------------
// 1. Transition batchnorm stats
// ---------------------------------------------------------------------------
__global__ __launch_bounds__(256) void tran_stats_kernel(
    const float* __restrict__ obs, float* __restrict__ tm, float* __restrict__ tv)
{
    const int f = blockIdx.x;
    const int tid = threadIdx.x;
    float sum = 0.f, sq = 0.f;
    for (int r = tid; r < kRows; r += 256) {
        const int t = r & (kL - 1);
        float d = 0.f;
        if (t > 0) {
            const float cur  = obs[(size_t)r * kOBS + f];
            const float prev = obs[(size_t)(r - 1) * kOBS + f];
            d = cur - prev;
        }
        sum += d; sq += d * d;
    }
    for (int off = 32; off > 0; off >>= 1) {
        sum += __shfl_down(sum, off);
        sq  += __shfl_down(sq, off);
    }
    __shared__ float sa[4], sb[4];
    if ((tid & 63) == 0) { sa[tid >> 6] = sum; sb[tid >> 6] = sq; }
    __syncthreads();
    if (tid == 0) {
        const float ts = sa[0] + sa[1] + sa[2] + sa[3];
        const float tq = sb[0] + sb[1] + sb[2] + sb[3];
        const float m = ts / (float)kRows;
        tm[f] = m;
        tv[f] = tq / (float)kRows - m * m;
    }
}

// ---------------------------------------------------------------------------
// 2. Encoder (writes fp32 residual stream)
// ---------------------------------------------------------------------------
__global__ __launch_bounds__(256) void encode_kernel(
    const float* __restrict__ obs, const float* __restrict__ act, const float* __restrict__ rew,
    const float* __restrict__ obs_W, const float* __restrict__ obs_b,
    const float* __restrict__ act_W, const float* __restrict__ act_b,
    const float* __restrict__ rew_W, const float* __restrict__ rew_b,
    const float* __restrict__ tr_W,  const float* __restrict__ tr_b,
    const float* __restrict__ bn_g,  const float* __restrict__ bn_b,
    const float* __restrict__ tm,    const float* __restrict__ tv,
    float* __restrict__ enc)
{
    const int row = blockIdx.x;
    const int t = row & (kL - 1);
    const int tid = threadIdx.x;
    __shared__ float s_obs2[kOBS];
    __shared__ float s_tran[kOBS];
    __shared__ float s_act[kACT];
    __shared__ float s_rew;
    if (tid < kOBS) {
        const float cur  = obs[(size_t)row * kOBS + tid];
        const float prev = (t > 0) ? obs[(size_t)(row - 1) * kOBS + tid] : cur;
        s_obs2[tid] = prev;
        const float tr = cur - prev;
        s_tran[tid] = (tr - tm[tid]) * rsqrtf(tv[tid] + 1e-5f) * bn_g[tid] + bn_b[tid];
    } else if (tid < kOBS + kACT) {
        s_act[tid - kOBS] = act[(size_t)row * kACT + (tid - kOBS)];
    } else if (tid == kOBS + kACT) {
        s_rew = rew[row];
    }
    __syncthreads();
    float* er = enc + (size_t)row * kC;
    #pragma unroll
    for (int s = 0; s < 4; ++s) {
        const int c = tid + s * 256;
        float v;
        if (c < kOE) {
            v = obs_b[c];
            #pragma unroll
            for (int k = 0; k < kOBS; ++k) v += s_obs2[k] * obs_W[k * kOE + c];
        } else if (c < kOE + kAE) {
            const int cc = c - kOE;
            v = act_b[cc];
            #pragma unroll
            for (int k = 0; k < kACT; ++k) v += s_act[k] * act_W[k * kAE + cc];
        } else if (c < kOE + kAE + kRE) {
            const int cc = c - (kOE + kAE);
            v = s_rew * rew_W[cc] + rew_b[cc];
        } else {
            const int cc = c - (kOE + kAE + kRE);
            v = tr_b[cc];
            #pragma unroll
            for (int k = 0; k < kOBS; ++k) v += s_tran[k] * tr_W[k * kTE + cc];
        }
        er[c] = v;
    }
}

// ---------------------------------------------------------------------------
// 3. LayerNorm: fp32 in -> fp16 out
// ---------------------------------------------------------------------------
__global__ __launch_bounds__(256) void ln_kernel(
    const float* __restrict__ x, const float* __restrict__ w,
    const float* __restrict__ b, unsigned short* __restrict__ out)
{
    const int row = blockIdx.x;
    const int tid = threadIdx.x;
    const float4 xv = *reinterpret_cast<const float4*>(&x[(size_t)row * kC + tid * 4]);
    float s = xv.x + xv.y + xv.z + xv.w;
    float q = xv.x * xv.x + xv.y * xv.y + xv.z * xv.z + xv.w * xv.w;
    for (int off = 32; off > 0; off >>= 1) {
        s += __shfl_down(s, off);
        q += __shfl_down(q, off);
    }
    __shared__ float sa[4], sb[4];
    if ((tid & 63) == 0) { sa[tid >> 6] = s; sb[tid >> 6] = q; }
    __syncthreads();
    const float ts = sa[0] + sa[1] + sa[2] + sa[3];
    const float tq = sb[0] + sb[1] + sb[2] + sb[3];
    const float mean = ts * (1.f / kC);
    const float var  = tq * (1.f / kC) - mean * mean;
    const float rstd = rsqrtf(var + 1e-5f);
    const float4 wv = *reinterpret_cast<const float4*>(&w[tid * 4]);
    const float4 bv = *reinterpret_cast<const float4*>(&b[tid * 4]);
    ushort4 o;
    o.x = f2h((xv.x - mean) * rstd * wv.x + bv.x);
    o.y = f2h((xv.y - mean) * rstd * wv.y + bv.y);
    o.z = f2h((xv.z - mean) * rstd * wv.z + bv.z);
    o.w = f2h((xv.w - mean) * rstd * wv.w + bv.w);
    *reinterpret_cast<ushort4*>(&out[(size_t)row * kC + tid * 4]) = o;
}

// ---------------------------------------------------------------------------
// 4a. Per-layer weight convert+transpose, single launch (3072 tiles).
//     W fp32 [K][N] -> WT fp16 [N][K], 64x64 tiles.
// ---------------------------------------------------------------------------
__device__ __forceinline__ void convT_tile(
    const float* __restrict__ W, unsigned short* __restrict__ WT,
    int K, int N, int k0, int n0, int tid)
{
    __shared__ unsigned short t[64][68];
    const int r = tid >> 4, c4 = (tid & 15) * 4;
    #pragma unroll
    for (int s = 0; s < 4; ++s) {
        const int rr = r + s * 16;
        const float4 v = *reinterpret_cast<const float4*>(&W[(size_t)(k0 + rr) * N + n0 + c4]);
        t[rr][c4 + 0] = f2h(v.x);
        t[rr][c4 + 1] = f2h(v.y);
        t[rr][c4 + 2] = f2h(v.z);
        t[rr][c4 + 3] = f2h(v.w);
    }
    __syncthreads();
    #pragma unroll
    for (int s = 0; s < 4; ++s) {
        const int rn = r + s * 16;
        ushort4 o;
        o.x = t[c4 + 0][rn];
        o.y = t[c4 + 1][rn];
        o.z = t[c4 + 2][rn];
        o.w = t[c4 + 3][rn];
        *reinterpret_cast<ushort4*>(&WT[(size_t)(n0 + rn) * K + k0 + c4]) = o;
    }
}

__global__ __launch_bounds__(256) void convert_layer_kernel(
    const float* __restrict__ qW, const float* __restrict__ oW,
    const float* __restrict__ fW, const float* __restrict__ pW,
    unsigned short* __restrict__ qWT, unsigned short* __restrict__ oWT,
    unsigned short* __restrict__ fWT, unsigned short* __restrict__ pWT)
{
    int bid = blockIdx.x;                    // 3072 tiles total
    const int tid = threadIdx.x;
    if (bid < 768)  {                        // qW: K=1024, N=3072 (48 n-tiles)
        convT_tile(qW, qWT, 1024, 3072, (bid / 48) * 64, (bid % 48) * 64, tid);
    } else if (bid < 1024) {                 // oW: 1024x1024 (16)
        bid -= 768;
        convT_tile(oW, oWT, 1024, 1024, (bid / 16) * 64, (bid % 16) * 64, tid);
    } else if (bid < 2048) {                 // fW: K=1024, N=4096 (64)
        bid -= 1024;
        convT_tile(fW, fWT, 1024, 4096, (bid / 64) * 64, (bid % 64) * 64, tid);
    } else {                                 // pW: K=4096, N=1024 (16)
        bid -= 2048;
        convT_tile(pW, pWT, 4096, 1024, (bid / 16) * 64, (bid % 16) * 64, tid);
    }
}

// ---------------------------------------------------------------------------
// 4b. fp16 MFMA GEMM, BK=64, 2-phase double-buffered, 8-slot XOR swizzle
//     (slot ^ (row&7), both sides — rule #21; worst aliasing 2-way = free).
//     32 MFMA per barrier. MODE 0: f32 out (+RES/RELU). MODE 1: f16 out.
//     MODE 2: qkv special (f16 qk + V^T). MODE 4: split-K atomicAdd into Cf.
// ---------------------------------------------------------------------------
template<int RELU, int RES, int MODE>
__global__ __launch_bounds__(256) void gemm_f16_kernel(
    const unsigned short* __restrict__ A,   // [M][K] fp16
    const unsigned short* __restrict__ BT,  // [N][K] fp16
    const float* __restrict__ bias,
    float* __restrict__ Cf, unsigned short* __restrict__ Ch,
    unsigned short* __restrict__ Cv,
    int M, int N, int K)
{
    __shared__ __align__(16) unsigned short As[2][128 * 64];   // 32 KB
    __shared__ __align__(16) unsigned short Bs[2][128 * 64];   // 32 KB
    const int tid = threadIdx.x;
    const int lane = tid & 63;
    const int wv   = tid >> 6;
    const int wr = wv >> 1, wc = wv & 1;
    const int bm = blockIdx.y * 128;
    const int bn = blockIdx.x * 128;
    const int ksz  = K / gridDim.z;
    const int kbeg = blockIdx.z * ksz;
    const int kend = kbeg + ksz;

    // staging: row stride 64 halves = 128 B = 8 slots of 16 B.
    // LDS linear dest (gload_lds): row = c*32 + (tid>>3), lds_slot = tid&7.
    // content = global slot g = lds_slot ^ (row&7)  (involution).
    const int grow = tid >> 3;                  // 0..31
    const int gs   = (tid & 7) ^ (grow & 7);    // pre-swizzled global slot

    const int fr = lane & 15;
    const int kb = lane >> 4;                   // 0..3

    auto stage = [&](int k0, int buf) {
        #pragma unroll
        for (int c = 0; c < 4; ++c) {
            gload_lds16(A  + (size_t)(bm + c * 32 + grow) * K + k0 + gs * 8,
                        (char*)&As[buf][0] + c * 4096 + wv * 1024);
            gload_lds16(BT + (size_t)(bn + c * 32 + grow) * K + k0 + gs * 8,
                        (char*)&Bs[buf][0] + c * 4096 + wv * 1024);
        }
    };

    f32x4 acc[4][4] = {};

    stage(kbeg, 0);
    __syncthreads();                 // prologue loads resident
    int cur = 0;
    for (int k0 = kbeg; k0 < kend; k0 += 64) {
        if (k0 + 64 < kend) stage(k0 + 64, cur ^ 1);   // prefetch next tile

        #pragma unroll
        for (int kf = 0; kf < 2; ++kf) {
            f16x8 a[4], b[4];
            #pragma unroll
            for (int m = 0; m < 4; ++m) {
                const int row = wr * 64 + m * 16 + fr;
                a[m] = *reinterpret_cast<const f16x8*>(
                    &As[cur][row * 64 + (((kf * 4 + kb) ^ (row & 7)) * 8)]);
            }
            #pragma unroll
            for (int n = 0; n < 4; ++n) {
                const int row = wc * 64 + n * 16 + fr;
                b[n] = *reinterpret_cast<const f16x8*>(
                    &Bs[cur][row * 64 + (((kf * 4 + kb) ^ (row & 7)) * 8)]);
            }
            #pragma unroll
            for (int m = 0; m < 4; ++m)
                #pragma unroll
                for (int n = 0; n < 4; ++n)
                    acc[m][n] = __builtin_amdgcn_mfma_f32_16x16x32_f16(a[m], b[n], acc[m][n], 0, 0, 0);
        }

        __syncthreads();             // next buf ready (vmcnt(0)+barrier)
        cur ^= 1;
    }

    const int fq = lane >> 4;
    if (MODE == 4) {                 // split-K atomic accumulate (RES via x)
        const bool addb = (blockIdx.z == 0);
        #pragma unroll
        for (int n = 0; n < 4; ++n) {
            const int c = bn + wc * 64 + n * 16 + fr;
            const float bv = addb ? bias[c] : 0.f;
            #pragma unroll
            for (int m = 0; m < 4; ++m) {
                #pragma unroll
                for (int j = 0; j < 4; ++j) {
                    const int r = bm + wr * 64 + m * 16 + fq * 4 + j;
                    atomicAdd(&Cf[(size_t)r * N + c], acc[m][n][j] + bv);
                }
            }
        }
        return;
    }
    if (MODE == 2) {
        if (bn < 2 * kC) {          // Q,K region -> qk f16 [row][2048]
            #pragma unroll
            for (int n = 0; n < 4; ++n) {
                const int c = bn + wc * 64 + n * 16 + fr;
                const float bv = bias[c];
                #pragma unroll
                for (int m = 0; m < 4; ++m) {
                    #pragma unroll
                    for (int j = 0; j < 4; ++j) {
                        const int r = bm + wr * 64 + m * 16 + fq * 4 + j;
                        Ch[(size_t)r * (2 * kC) + c] = f2h(acc[m][n][j] + bv);
                    }
                }
            }
        } else {                    // V region -> vt[b][h][d][t] f16
            #pragma unroll
            for (int n = 0; n < 4; ++n) {
                const int c  = bn + wc * 64 + n * 16 + fr;
                const int cc = c - 2 * kC;
                const int hh = cc >> 6, dd = cc & 63;
                const float bv = bias[c];
                #pragma unroll
                for (int m = 0; m < 4; ++m) {
                    const int rr = bm + wr * 64 + m * 16 + fq * 4;
                    const int bb = rr >> 10, t0 = rr & 1023;
                    f16x4 pk;
                    #pragma unroll
                    for (int j = 0; j < 4; ++j) pk[j] = (_Float16)(acc[m][n][j] + bv);
                    *reinterpret_cast<f16x4*>(
                        &Cv[((size_t)(bb * kH + hh) * kDH + dd) * kL + t0]) = pk;
                }
            }
        }
        return;
    }
    #pragma unroll
    for (int n = 0; n < 4; ++n) {
        const int c = bn + wc * 64 + n * 16 + fr;
        const float bv = bias[c];
        #pragma unroll
        for (int m = 0; m < 4; ++m) {
            #pragma unroll
            for (int j = 0; j < 4; ++j) {
                const int r = bm + wr * 64 + m * 16 + fq * 4 + j;
                float v = acc[m][n][j] + bv;
                if (RES)  v += Cf[(size_t)r * N + c];
                if (RELU) v = fmaxf(v, 0.f);
                if (MODE == 1) Ch[(size_t)r * N + c] = f2h(v);
                else           Cf[(size_t)r * N + c] = v;
            }
        }
    }
}

// ---------------------------------------------------------------------------
// 5. MFMA flash attention (unchanged)
// ---------------------------------------------------------------------------
__device__ __forceinline__ int swz(int row, int slot) {
    return row * 64 + ((slot ^ (row & 7)) * 8);   // ushort index, 16B-aligned
}

__global__ __launch_bounds__(256) void attn_mfma_kernel(
    const unsigned short* __restrict__ qk,   // [2048][2048] f16 (Q | K)
    const unsigned short* __restrict__ vt,   // [2][16][64][1024] f16  V^T
    unsigned short* __restrict__ o)          // [2048][1024] f16
{
    const int bid = blockIdx.x;            // 512 blocks
    const int bh  = bid & 31;
    const int qb  = ((bid >> 5) + bh) & 15;   // shear: balance causal work
    const int b   = bh >> 4;
    const int h   = bh & 15;
    const int tid  = threadIdx.x;
    const int lane = tid & 63;
    const int wv   = tid >> 6;
    const int fr = lane & 15;              // q index within wave
    const int g  = lane >> 4;              // k-group

    __shared__ __align__(16) unsigned short Qs[64 * 64];
    __shared__ __align__(16) unsigned short Ks[64 * 64];
    __shared__ __align__(16) unsigned short Vts[64 * 64];
    __shared__ __align__(16) unsigned short Ps[64 * 64];

    const int qlo = qb * 64;

    {
        const int r = tid >> 2, s = tid & 3;
        const unsigned short* qg = &qk[(size_t)(b * kL + qlo + r) * (2 * kC) + h * kDH];
        f16x8 v0 = *reinterpret_cast<const f16x8*>(&qg[s * 8]);
        f16x8 v1 = *reinterpret_cast<const f16x8*>(&qg[(s + 4) * 8]);
        #pragma unroll
        for (int i = 0; i < 8; ++i) { v0[i] *= (_Float16)0.125f; v1[i] *= (_Float16)0.125f; }
        *reinterpret_cast<f16x8*>(&Qs[swz(r, s)])     = v0;
        *reinterpret_cast<f16x8*>(&Qs[swz(r, s + 4)]) = v1;
    }
    __syncthreads();

    f16x8 qfrag[2];
    #pragma unroll
    for (int kf = 0; kf < 2; ++kf)
        qfrag[kf] = *reinterpret_cast<const f16x8*>(&Qs[swz(wv * 16 + fr, kf * 4 + g)]);

    float m = -INFINITY, l = 0.f;
    f32x4 acc_o[4] = {};
    const int qg_row = qlo + wv * 16 + fr;

    for (int k0 = 0; k0 <= qlo; k0 += 64) {
        __syncthreads();
        {
            const int r = tid >> 2, s = tid & 3;
            const unsigned short* kg = &qk[(size_t)(b * kL + k0 + r) * (2 * kC) + kC + h * kDH];
            *reinterpret_cast<f16x8*>(&Ks[swz(r, s)])     = *reinterpret_cast<const f16x8*>(&kg[s * 8]);
            *reinterpret_cast<f16x8*>(&Ks[swz(r, s + 4)]) = *reinterpret_cast<const f16x8*>(&kg[(s + 4) * 8]);
            const unsigned short* vg = &vt[((size_t)(b * kH + h) * kDH + r) * kL + k0];
            *reinterpret_cast<f16x8*>(&Vts[swz(r, s)])     = *reinterpret_cast<const f16x8*>(&vg[s * 8]);
            *reinterpret_cast<f16x8*>(&Vts[swz(r, s + 4)]) = *reinterpret_cast<const f16x8*>(&vg[(s + 4) * 8]);
        }
        __syncthreads();

        f32x4 acc_s[4] = {};
        #pragma unroll
        for (int kf = 0; kf < 2; ++kf) {
            const f16x8 qf = qfrag[kf];
            #pragma unroll
            for (int n = 0; n < 4; ++n) {
                const f16x8 kfr = *reinterpret_cast<const f16x8*>(&Ks[swz(n * 16 + fr, kf * 4 + g)]);
                acc_s[n] = __builtin_amdgcn_mfma_f32_16x16x32_f16(kfr, qf, acc_s[n], 0, 0, 0);
            }
        }

        if (k0 == qlo) {
            #pragma unroll
            for (int n = 0; n < 4; ++n)
                #pragma unroll
                for (int j = 0; j < 4; ++j)
                    if (k0 + n * 16 + g * 4 + j > qg_row) acc_s[n][j] = -INFINITY;
        }

        float mx = -INFINITY;
        #pragma unroll
        for (int n = 0; n < 4; ++n)
            #pragma unroll
            for (int j = 0; j < 4; ++j) mx = fmaxf(mx, acc_s[n][j]);
        mx = fmaxf(mx, __shfl_xor(mx, 16));
        mx = fmaxf(mx, __shfl_xor(mx, 32));
        const float mn  = fmaxf(m, mx);
        const float fac = __expf(m - mn);
        float p[4][4];
        float psum = 0.f;
        #pragma unroll
        for (int n = 0; n < 4; ++n)
            #pragma unroll
            for (int j = 0; j < 4; ++j) { p[n][j] = __expf(acc_s[n][j] - mn); psum += p[n][j]; }
        psum += __shfl_xor(psum, 16);
        psum += __shfl_xor(psum, 32);
        l = l * fac + psum;
        m = mn;
        #pragma unroll
        for (int dt = 0; dt < 4; ++dt)
            #pragma unroll
            for (int j = 0; j < 4; ++j) acc_o[dt][j] *= fac;

        #pragma unroll
        for (int n = 0; n < 4; ++n) {
            f16x4 pk;
            #pragma unroll
            for (int j = 0; j < 4; ++j) pk[j] = (_Float16)p[n][j];
            *reinterpret_cast<f16x4*>(&Ps[swz(wv * 16 + fr, 2 * n + (g >> 1)) + (g & 1) * 4]) = pk;
        }

        #pragma unroll
        for (int kf = 0; kf < 2; ++kf) {
            const f16x8 pf = *reinterpret_cast<const f16x8*>(&Ps[swz(wv * 16 + fr, kf * 4 + g)]);
            #pragma unroll
            for (int dt = 0; dt < 4; ++dt) {
                const f16x8 vf = *reinterpret_cast<const f16x8*>(&Vts[swz(dt * 16 + fr, kf * 4 + g)]);
                acc_o[dt] = __builtin_amdgcn_mfma_f32_16x16x32_f16(vf, pf, acc_o[dt], 0, 0, 0);
            }
        }
    }

    const float rl = 1.f / l;
    unsigned short* ob = &o[(size_t)(b * kL + qg_row) * kC + h * kDH];
    #pragma unroll
    for (int dt = 0; dt < 4; ++dt) {
        f16x4 pk;
        #pragma unroll
        for (int j = 0; j < 4; ++j) pk[j] = (_Float16)(acc_o[dt][j] * rl);
        *reinterpret_cast<f16x4*>(&ob[dt * 16 + g * 4]) = pk;
    }
}

// ---------------------------------------------------------------------------
// 6. Final tanh (in place on d_out)
// ---------------------------------------------------------------------------
__global__ __launch_bounds__(256) void tanh_kernel(float* __restrict__ x)
{
    const size_t i = ((size_t)blockIdx.x * 256 + threadIdx.x) * 4;
    float4 v = *reinterpret_cast<float4*>(&x[i]);
    v.x = tanhf(v.x); v.y = tanhf(v.y); v.z = tanhf(v.z); v.w = tanhf(v.w);
    *reinterpret_cast<float4*>(&x[i]) = v;
}

// ---------------------------------------------------------------------------
extern "C" void kernel_launch(void* const* d_in, const int* in_sizes, int n_in,
                              void* d_out, int out_size, void* d_ws, size_t ws_size,
                              hipStream_t stream)
{
    (void)in_sizes; (void)n_in; (void)out_size; (void)ws_size;
    const float* obs    = (const float*)d_in[0];
    const float* act    = (const float*)d_in[1];
    const float* rew    = (const float*)d_in[2];
    const float* obs_W  = (const float*)d_in[3];
    const float* obs_b  = (const float*)d_in[4];
    const float* act_W  = (const float*)d_in[5];
    const float* act_b  = (const float*)d_in[6];
    const float* rew_W  = (const float*)d_in[7];
    const float* rew_b  = (const float*)d_in[8];
    const float* tr_W   = (const float*)d_in[9];
    const float* tr_b   = (const float*)d_in[10];
    const float* bn_g   = (const float*)d_in[11];
    const float* bn_b   = (const float*)d_in[12];
    const float* ln1_w  = (const float*)d_in[13];
    const float* ln1_b  = (const float*)d_in[14];
    const float* qkv_W  = (const float*)d_in[15];
    const float* qkv_b  = (const float*)d_in[16];
    const float* out_W  = (const float*)d_in[17];
    const float* out_b  = (const float*)d_in[18];
    const float* ln2_w  = (const float*)d_in[19];
    const float* ln2_b  = (const float*)d_in[20];
    const float* fc_W   = (const float*)d_in[21];
    const float* fc_b   = (const float*)d_in[22];
    const float* pj_W   = (const float*)d_in[23];
    const float* pj_b   = (const float*)d_in[24];

    float* x  = (float*)d_out;                     // fp32 residual stream
    float* ws = (float*)d_ws;
    float* tm   = ws;                              // 64
    float* tv   = ws + 64;                         // 64
    unsigned short* wbuf  = (unsigned short*)(ws + 128);  // 12.58M f16 weights
    unsigned short* h_hf  = wbuf + 12582912;       // 2048*1024
    unsigned short* ao_hf = h_hf + (size_t)kRows * kC;    // 2048*1024
    unsigned short* ff_hf = ao_hf + (size_t)kRows * kC;   // 2048*4096
    unsigned short* qk_hf = ff_hf + (size_t)kRows * kFF;  // 2048*2048
    unsigned short* vt_hf = qk_hf + (size_t)kRows * 2 * kC; // 2*16*64*1024
    unsigned short* qWT = wbuf;                    // [3072][1024]
    unsigned short* oWT = qWT + 3 * kC * kC;       // [1024][1024]
    unsigned short* fWT = oWT + kC * kC;           // [4096][1024]
    unsigned short* pWT = fWT + kC * kFF;          // [1024][4096]

    tran_stats_kernel<<<kOBS, 256, 0, stream>>>(obs, tm, tv);
    encode_kernel<<<kRows, 256, 0, stream>>>(obs, act, rew,
        obs_W, obs_b, act_W, act_b, rew_W, rew_b, tr_W, tr_b, bn_g, bn_b, tm, tv, x);

    for (int lyr = 0; lyr < kNL; ++lyr) {
        const float* qW = qkv_W + (size_t)lyr * kC * 3 * kC;
        const float* qB = qkv_b + (size_t)lyr * 3 * kC;
        const float* oW = out_W + (size_t)lyr * kC * kC;
        const float* oB = out_b + (size_t)lyr * kC;
        const float* fW = fc_W + (size_t)lyr * kC * kFF;
        const float* fB = fc_b + (size_t)lyr * kFF;
        const float* pW = pj_W + (size_t)lyr * kFF * kC;
        const float* pB = pj_b + (size_t)lyr * kC;

        convert_layer_kernel<<<3072, 256, 0, stream>>>(
            qW, oW, fW, pW, qWT, oWT, fWT, pWT);

        ln_kernel<<<kRows, 256, 0, stream>>>(x, ln1_w + lyr * kC, ln1_b + lyr * kC, h_hf);
        gemm_f16_kernel<0,0,2><<<dim3(3 * kC / 128, kRows / 128), 256, 0, stream>>>(
            h_hf, qWT, qB, nullptr, qk_hf, vt_hf, kRows, 3 * kC, kC);
        attn_mfma_kernel<<<dim3(512), 256, 0, stream>>>(qk_hf, vt_hf, ao_hf);
        // out projection: split-K=4, atomic accumulate into residual stream
        gemm_f16_kernel<0,0,4><<<dim3(kC / 128, kRows / 128, 4), 256, 0, stream>>>(
            ao_hf, oWT, oB, x, nullptr, nullptr, kRows, kC, kC);
        ln_kernel<<<kRows, 256, 0, stream>>>(x, ln2_w + lyr * kC, ln2_b + lyr * kC, h_hf);
        gemm_f16_kernel<1,0,1><<<dim3(kFF / 128, kRows / 128), 256, 0, stream>>>(
            h_hf, fWT, fB, nullptr, ff_hf, nullptr, kRows, kFF, kC);
        // pj projection: split-K=4, atomic accumulate into residual stream
        gemm_f16_kernel<0,0,4><<<dim3(kC / 128, kRows / 128, 4), 256, 0, stream>>>(
            ff_hf, pWT, pB, x, nullptr, nullptr, kRows, kC, kFF);
    }
    tanh_kernel<<<kRows * kC / 1024, 256, 0, stream>>>(x);
}

// Round 9
// 685.803 us; speedup vs baseline: 8.8344x; 1.0121x over previous
//
#include <hip/hip_runtime.h>
#include <hip/hip_bf16.h>
#include <math.h>

// Problem constants
constexpr int kB   = 2;
constexpr int kL   = 1024;
constexpr int kOBS = 64;
constexpr int kACT = 16;
constexpr int kC   = 1024;
constexpr int kH   = 16;
constexpr int kDH  = 64;
constexpr int kFF  = 4096;
constexpr int kNL  = 4;
constexpr int kRows = kB * kL;          // 2048
constexpr int kOE = 512, kAE = 256, kRE = 128, kTE = 128;

typedef _Float16 f16x8 __attribute__((ext_vector_type(8)));
typedef _Float16 f16x4 __attribute__((ext_vector_type(4)));
typedef float    f32x4 __attribute__((ext_vector_type(4)));

__device__ __forceinline__ unsigned short f2h(float x) {
    return __builtin_bit_cast(unsigned short, (_Float16)x);
}
__device__ __forceinline__ void gload_lds16(const void* g, void* l) {
    __builtin_amdgcn_global_load_lds(
        (const __attribute__((address_space(1))) unsigned int*)g,
        (__attribute__((address_space(3))) unsigned int*)l, 16, 0, 0);
}

// ---------------------------------------------------------------------------
// 1. Transition batchnorm stats
// ---------------------------------------------------------------------------
__global__ __launch_bounds__(256) void tran_stats_kernel(
    const float* __restrict__ obs, float* __restrict__ tm, float* __restrict__ tv)
{
    const int f = blockIdx.x;
    const int tid = threadIdx.x;
    float sum = 0.f, sq = 0.f;
    for (int r = tid; r < kRows; r += 256) {
        const int t = r & (kL - 1);
        float d = 0.f;
        if (t > 0) {
            const float cur  = obs[(size_t)r * kOBS + f];
            const float prev = obs[(size_t)(r - 1) * kOBS + f];
            d = cur - prev;
        }
        sum += d; sq += d * d;
    }
    for (int off = 32; off > 0; off >>= 1) {
        sum += __shfl_down(sum, off);
        sq  += __shfl_down(sq, off);
    }
    __shared__ float sa[4], sb[4];
    if ((tid & 63) == 0) { sa[tid >> 6] = sum; sb[tid >> 6] = sq; }
    __syncthreads();
    if (tid == 0) {
        const float ts = sa[0] + sa[1] + sa[2] + sa[3];
        const float tq = sb[0] + sb[1] + sb[2] + sb[3];
        const float m = ts / (float)kRows;
        tm[f] = m;
        tv[f] = tq / (float)kRows - m * m;
    }
}

// ---------------------------------------------------------------------------
// 2. Encoder (writes fp32 residual stream)
// ---------------------------------------------------------------------------
__global__ __launch_bounds__(256) void encode_kernel(
    const float* __restrict__ obs, const float* __restrict__ act, const float* __restrict__ rew,
    const float* __restrict__ obs_W, const float* __restrict__ obs_b,
    const float* __restrict__ act_W, const float* __restrict__ act_b,
    const float* __restrict__ rew_W, const float* __restrict__ rew_b,
    const float* __restrict__ tr_W,  const float* __restrict__ tr_b,
    const float* __restrict__ bn_g,  const float* __restrict__ bn_b,
    const float* __restrict__ tm,    const float* __restrict__ tv,
    float* __restrict__ enc)
{
    const int row = blockIdx.x;
    const int t = row & (kL - 1);
    const int tid = threadIdx.x;
    __shared__ float s_obs2[kOBS];
    __shared__ float s_tran[kOBS];
    __shared__ float s_act[kACT];
    __shared__ float s_rew;
    if (tid < kOBS) {
        const float cur  = obs[(size_t)row * kOBS + tid];
        const float prev = (t > 0) ? obs[(size_t)(row - 1) * kOBS + tid] : cur;
        s_obs2[tid] = prev;
        const float tr = cur - prev;
        s_tran[tid] = (tr - tm[tid]) * rsqrtf(tv[tid] + 1e-5f) * bn_g[tid] + bn_b[tid];
    } else if (tid < kOBS + kACT) {
        s_act[tid - kOBS] = act[(size_t)row * kACT + (tid - kOBS)];
    } else if (tid == kOBS + kACT) {
        s_rew = rew[row];
    }
    __syncthreads();
    float* er = enc + (size_t)row * kC;
    #pragma unroll
    for (int s = 0; s < 4; ++s) {
        const int c = tid + s * 256;
        float v;
        if (c < kOE) {
            v = obs_b[c];
            #pragma unroll
            for (int k = 0; k < kOBS; ++k) v += s_obs2[k] * obs_W[k * kOE + c];
        } else if (c < kOE + kAE) {
            const int cc = c - kOE;
            v = act_b[cc];
            #pragma unroll
            for (int k = 0; k < kACT; ++k) v += s_act[k] * act_W[k * kAE + cc];
        } else if (c < kOE + kAE + kRE) {
            const int cc = c - (kOE + kAE);
            v = s_rew * rew_W[cc] + rew_b[cc];
        } else {
            const int cc = c - (kOE + kAE + kRE);
            v = tr_b[cc];
            #pragma unroll
            for (int k = 0; k < kOBS; ++k) v += s_tran[k] * tr_W[k * kTE + cc];
        }
        er[c] = v;
    }
}

// ---------------------------------------------------------------------------
// 3. LayerNorm: fp32 in -> fp16 out
// ---------------------------------------------------------------------------
__global__ __launch_bounds__(256) void ln_kernel(
    const float* __restrict__ x, const float* __restrict__ w,
    const float* __restrict__ b, unsigned short* __restrict__ out)
{
    const int row = blockIdx.x;
    const int tid = threadIdx.x;
    const float4 xv = *reinterpret_cast<const float4*>(&x[(size_t)row * kC + tid * 4]);
    float s = xv.x + xv.y + xv.z + xv.w;
    float q = xv.x * xv.x + xv.y * xv.y + xv.z * xv.z + xv.w * xv.w;
    for (int off = 32; off > 0; off >>= 1) {
        s += __shfl_down(s, off);
        q += __shfl_down(q, off);
    }
    __shared__ float sa[4], sb[4];
    if ((tid & 63) == 0) { sa[tid >> 6] = s; sb[tid >> 6] = q; }
    __syncthreads();
    const float ts = sa[0] + sa[1] + sa[2] + sa[3];
    const float tq = sb[0] + sb[1] + sb[2] + sb[3];
    const float mean = ts * (1.f / kC);
    const float var  = tq * (1.f / kC) - mean * mean;
    const float rstd = rsqrtf(var + 1e-5f);
    const float4 wv = *reinterpret_cast<const float4*>(&w[tid * 4]);
    const float4 bv = *reinterpret_cast<const float4*>(&b[tid * 4]);
    ushort4 o;
    o.x = f2h((xv.x - mean) * rstd * wv.x + bv.x);
    o.y = f2h((xv.y - mean) * rstd * wv.y + bv.y);
    o.z = f2h((xv.z - mean) * rstd * wv.z + bv.z);
    o.w = f2h((xv.w - mean) * rstd * wv.w + bv.w);
    *reinterpret_cast<ushort4*>(&out[(size_t)row * kC + tid * 4]) = o;
}

// ---------------------------------------------------------------------------
// 4a. Per-layer weight convert+transpose, single launch (3072 tiles).
// ---------------------------------------------------------------------------
__device__ __forceinline__ void convT_tile(
    const float* __restrict__ W, unsigned short* __restrict__ WT,
    int K, int N, int k0, int n0, int tid)
{
    __shared__ unsigned short t[64][68];
    const int r = tid >> 4, c4 = (tid & 15) * 4;
    #pragma unroll
    for (int s = 0; s < 4; ++s) {
        const int rr = r + s * 16;
        const float4 v = *reinterpret_cast<const float4*>(&W[(size_t)(k0 + rr) * N + n0 + c4]);
        t[rr][c4 + 0] = f2h(v.x);
        t[rr][c4 + 1] = f2h(v.y);
        t[rr][c4 + 2] = f2h(v.z);
        t[rr][c4 + 3] = f2h(v.w);
    }
    __syncthreads();
    #pragma unroll
    for (int s = 0; s < 4; ++s) {
        const int rn = r + s * 16;
        ushort4 o;
        o.x = t[c4 + 0][rn];
        o.y = t[c4 + 1][rn];
        o.z = t[c4 + 2][rn];
        o.w = t[c4 + 3][rn];
        *reinterpret_cast<ushort4*>(&WT[(size_t)(n0 + rn) * K + k0 + c4]) = o;
    }
}

__global__ __launch_bounds__(256) void convert_layer_kernel(
    const float* __restrict__ qW, const float* __restrict__ oW,
    const float* __restrict__ fW, const float* __restrict__ pW,
    unsigned short* __restrict__ qWT, unsigned short* __restrict__ oWT,
    unsigned short* __restrict__ fWT, unsigned short* __restrict__ pWT)
{
    int bid = blockIdx.x;                    // 3072 tiles total
    const int tid = threadIdx.x;
    if (bid < 768)  {                        // qW: K=1024, N=3072 (48 n-tiles)
        convT_tile(qW, qWT, 1024, 3072, (bid / 48) * 64, (bid % 48) * 64, tid);
    } else if (bid < 1024) {                 // oW: 1024x1024 (16)
        bid -= 768;
        convT_tile(oW, oWT, 1024, 1024, (bid / 16) * 64, (bid % 16) * 64, tid);
    } else if (bid < 2048) {                 // fW: K=1024, N=4096 (64)
        bid -= 1024;
        convT_tile(fW, fWT, 1024, 4096, (bid / 64) * 64, (bid % 64) * 64, tid);
    } else {                                 // pW: K=4096, N=1024 (16)
        bid -= 2048;
        convT_tile(pW, pWT, 4096, 1024, (bid / 16) * 64, (bid % 16) * 64, tid);
    }
}

// ---------------------------------------------------------------------------
// 4b. fp16 MFMA GEMM, BK=64, 2-phase double-buffered, 8-slot XOR swizzle,
//     XCD-aware block swizzle (T1): flat = (flat&7)*cpx + flat>>3, decoded
//     x-fastest so each XCD's chunk shares A-panels and sweeps bn -> panels
//     become XCD-private and L2-resident. All grids here are %8 == 0.
//     MODE 0: f32 out (+RES/RELU). MODE 1: f16 out. MODE 2: qkv special.
//     MODE 4: split-K atomicAdd into Cf.
// ---------------------------------------------------------------------------
template<int RELU, int RES, int MODE>
__global__ __launch_bounds__(256) void gemm_f16_kernel(
    const unsigned short* __restrict__ A,   // [M][K] fp16
    const unsigned short* __restrict__ BT,  // [N][K] fp16
    const float* __restrict__ bias,
    float* __restrict__ Cf, unsigned short* __restrict__ Ch,
    unsigned short* __restrict__ Cv,
    int M, int N, int K)
{
    __shared__ __align__(16) unsigned short As[2][128 * 64];   // 32 KB
    __shared__ __align__(16) unsigned short Bs[2][128 * 64];   // 32 KB
    const int tid = threadIdx.x;
    const int lane = tid & 63;
    const int wv   = tid >> 6;
    const int wr = wv >> 1, wc = wv & 1;

    // XCD-aware swizzle (bijective: all our grids are divisible by 8)
    const int nx  = gridDim.x;
    const int nxy = gridDim.x * gridDim.y;
    int flat = blockIdx.x + nx * blockIdx.y + nxy * blockIdx.z;
    const int cpx = (nxy * gridDim.z) >> 3;
    flat = (flat & 7) * cpx + (flat >> 3);
    const int bx = flat % nx;
    const int by = (flat / nx) % gridDim.y;
    const int bz = flat / nxy;

    const int bm = by * 128;
    const int bn = bx * 128;
    const int ksz  = K / gridDim.z;
    const int kbeg = bz * ksz;
    const int kend = kbeg + ksz;

    // staging: row stride 64 halves = 128 B = 8 slots of 16 B.
    const int grow = tid >> 3;                  // 0..31
    const int gs   = (tid & 7) ^ (grow & 7);    // pre-swizzled global slot

    const int fr = lane & 15;
    const int kb = lane >> 4;                   // 0..3

    auto stage = [&](int k0, int buf) {
        #pragma unroll
        for (int c = 0; c < 4; ++c) {
            gload_lds16(A  + (size_t)(bm + c * 32 + grow) * K + k0 + gs * 8,
                        (char*)&As[buf][0] + c * 4096 + wv * 1024);
            gload_lds16(BT + (size_t)(bn + c * 32 + grow) * K + k0 + gs * 8,
                        (char*)&Bs[buf][0] + c * 4096 + wv * 1024);
        }
    };

    f32x4 acc[4][4] = {};

    stage(kbeg, 0);
    __syncthreads();                 // prologue loads resident
    int cur = 0;
    for (int k0 = kbeg; k0 < kend; k0 += 64) {
        if (k0 + 64 < kend) stage(k0 + 64, cur ^ 1);   // prefetch next tile

        #pragma unroll
        for (int kf = 0; kf < 2; ++kf) {
            f16x8 a[4], b[4];
            #pragma unroll
            for (int m = 0; m < 4; ++m) {
                const int row = wr * 64 + m * 16 + fr;
                a[m] = *reinterpret_cast<const f16x8*>(
                    &As[cur][row * 64 + (((kf * 4 + kb) ^ (row & 7)) * 8)]);
            }
            #pragma unroll
            for (int n = 0; n < 4; ++n) {
                const int row = wc * 64 + n * 16 + fr;
                b[n] = *reinterpret_cast<const f16x8*>(
                    &Bs[cur][row * 64 + (((kf * 4 + kb) ^ (row & 7)) * 8)]);
            }
            #pragma unroll
            for (int m = 0; m < 4; ++m)
                #pragma unroll
                for (int n = 0; n < 4; ++n)
                    acc[m][n] = __builtin_amdgcn_mfma_f32_16x16x32_f16(a[m], b[n], acc[m][n], 0, 0, 0);
        }

        __syncthreads();             // next buf ready (vmcnt(0)+barrier)
        cur ^= 1;
    }

    const int fq = lane >> 4;
    if (MODE == 4) {                 // split-K atomic accumulate (RES via x)
        const bool addb = (bz == 0);
        #pragma unroll
        for (int n = 0; n < 4; ++n) {
            const int c = bn + wc * 64 + n * 16 + fr;
            const float bv = addb ? bias[c] : 0.f;
            #pragma unroll
            for (int m = 0; m < 4; ++m) {
                #pragma unroll
                for (int j = 0; j < 4; ++j) {
                    const int r = bm + wr * 64 + m * 16 + fq * 4 + j;
                    atomicAdd(&Cf[(size_t)r * N + c], acc[m][n][j] + bv);
                }
            }
        }
        return;
    }
    if (MODE == 2) {
        if (bn < 2 * kC) {          // Q,K region -> qk f16 [row][2048]
            #pragma unroll
            for (int n = 0; n < 4; ++n) {
                const int c = bn + wc * 64 + n * 16 + fr;
                const float bv = bias[c];
                #pragma unroll
                for (int m = 0; m < 4; ++m) {
                    #pragma unroll
                    for (int j = 0; j < 4; ++j) {
                        const int r = bm + wr * 64 + m * 16 + fq * 4 + j;
                        Ch[(size_t)r * (2 * kC) + c] = f2h(acc[m][n][j] + bv);
                    }
                }
            }
        } else {                    // V region -> vt[b][h][d][t] f16
            #pragma unroll
            for (int n = 0; n < 4; ++n) {
                const int c  = bn + wc * 64 + n * 16 + fr;
                const int cc = c - 2 * kC;
                const int hh = cc >> 6, dd = cc & 63;
                const float bv = bias[c];
                #pragma unroll
                for (int m = 0; m < 4; ++m) {
                    const int rr = bm + wr * 64 + m * 16 + fq * 4;
                    const int bb = rr >> 10, t0 = rr & 1023;
                    f16x4 pk;
                    #pragma unroll
                    for (int j = 0; j < 4; ++j) pk[j] = (_Float16)(acc[m][n][j] + bv);
                    *reinterpret_cast<f16x4*>(
                        &Cv[((size_t)(bb * kH + hh) * kDH + dd) * kL + t0]) = pk;
                }
            }
        }
        return;
    }
    #pragma unroll
    for (int n = 0; n < 4; ++n) {
        const int c = bn + wc * 64 + n * 16 + fr;
        const float bv = bias[c];
        #pragma unroll
        for (int m = 0; m < 4; ++m) {
            #pragma unroll
            for (int j = 0; j < 4; ++j) {
                const int r = bm + wr * 64 + m * 16 + fq * 4 + j;
                float v = acc[m][n][j] + bv;
                if (RES)  v += Cf[(size_t)r * N + c];
                if (RELU) v = fmaxf(v, 0.f);
                if (MODE == 1) Ch[(size_t)r * N + c] = f2h(v);
                else           Cf[(size_t)r * N + c] = v;
            }
        }
    }
}

// ---------------------------------------------------------------------------
// 5. MFMA flash attention (unchanged)
// ---------------------------------------------------------------------------
__device__ __forceinline__ int swz(int row, int slot) {
    return row * 64 + ((slot ^ (row & 7)) * 8);   // ushort index, 16B-aligned
}

__global__ __launch_bounds__(256) void attn_mfma_kernel(
    const unsigned short* __restrict__ qk,   // [2048][2048] f16 (Q | K)
    const unsigned short* __restrict__ vt,   // [2][16][64][1024] f16  V^T
    unsigned short* __restrict__ o)          // [2048][1024] f16
{
    const int bid = blockIdx.x;            // 512 blocks
    const int bh  = bid & 31;
    const int qb  = ((bid >> 5) + bh) & 15;   // shear: balance causal work
    const int b   = bh >> 4;
    const int h   = bh & 15;
    const int tid  = threadIdx.x;
    const int lane = tid & 63;
    const int wv   = tid >> 6;
    const int fr = lane & 15;              // q index within wave
    const int g  = lane >> 4;              // k-group

    __shared__ __align__(16) unsigned short Qs[64 * 64];
    __shared__ __align__(16) unsigned short Ks[64 * 64];
    __shared__ __align__(16) unsigned short Vts[64 * 64];
    __shared__ __align__(16) unsigned short Ps[64 * 64];

    const int qlo = qb * 64;

    {
        const int r = tid >> 2, s = tid & 3;
        const unsigned short* qg = &qk[(size_t)(b * kL + qlo + r) * (2 * kC) + h * kDH];
        f16x8 v0 = *reinterpret_cast<const f16x8*>(&qg[s * 8]);
        f16x8 v1 = *reinterpret_cast<const f16x8*>(&qg[(s + 4) * 8]);
        #pragma unroll
        for (int i = 0; i < 8; ++i) { v0[i] *= (_Float16)0.125f; v1[i] *= (_Float16)0.125f; }
        *reinterpret_cast<f16x8*>(&Qs[swz(r, s)])     = v0;
        *reinterpret_cast<f16x8*>(&Qs[swz(r, s + 4)]) = v1;
    }
    __syncthreads();

    f16x8 qfrag[2];
    #pragma unroll
    for (int kf = 0; kf < 2; ++kf)
        qfrag[kf] = *reinterpret_cast<const f16x8*>(&Qs[swz(wv * 16 + fr, kf * 4 + g)]);

    float m = -INFINITY, l = 0.f;
    f32x4 acc_o[4] = {};
    const int qg_row = qlo + wv * 16 + fr;

    for (int k0 = 0; k0 <= qlo; k0 += 64) {
        __syncthreads();
        {
            const int r = tid >> 2, s = tid & 3;
            const unsigned short* kg = &qk[(size_t)(b * kL + k0 + r) * (2 * kC) + kC + h * kDH];
            *reinterpret_cast<f16x8*>(&Ks[swz(r, s)])     = *reinterpret_cast<const f16x8*>(&kg[s * 8]);
            *reinterpret_cast<f16x8*>(&Ks[swz(r, s + 4)]) = *reinterpret_cast<const f16x8*>(&kg[(s + 4) * 8]);
            const unsigned short* vg = &vt[((size_t)(b * kH + h) * kDH + r) * kL + k0];
            *reinterpret_cast<f16x8*>(&Vts[swz(r, s)])     = *reinterpret_cast<const f16x8*>(&vg[s * 8]);
            *reinterpret_cast<f16x8*>(&Vts[swz(r, s + 4)]) = *reinterpret_cast<const f16x8*>(&vg[(s + 4) * 8]);
        }
        __syncthreads();

        f32x4 acc_s[4] = {};
        #pragma unroll
        for (int kf = 0; kf < 2; ++kf) {
            const f16x8 qf = qfrag[kf];
            #pragma unroll
            for (int n = 0; n < 4; ++n) {
                const f16x8 kfr = *reinterpret_cast<const f16x8*>(&Ks[swz(n * 16 + fr, kf * 4 + g)]);
                acc_s[n] = __builtin_amdgcn_mfma_f32_16x16x32_f16(kfr, qf, acc_s[n], 0, 0, 0);
            }
        }

        if (k0 == qlo) {
            #pragma unroll
            for (int n = 0; n < 4; ++n)
                #pragma unroll
                for (int j = 0; j < 4; ++j)
                    if (k0 + n * 16 + g * 4 + j > qg_row) acc_s[n][j] = -INFINITY;
        }

        float mx = -INFINITY;
        #pragma unroll
        for (int n = 0; n < 4; ++n)
            #pragma unroll
            for (int j = 0; j < 4; ++j) mx = fmaxf(mx, acc_s[n][j]);
        mx = fmaxf(mx, __shfl_xor(mx, 16));
        mx = fmaxf(mx, __shfl_xor(mx, 32));
        const float mn  = fmaxf(m, mx);
        const float fac = __expf(m - mn);
        float p[4][4];
        float psum = 0.f;
        #pragma unroll
        for (int n = 0; n < 4; ++n)
            #pragma unroll
            for (int j = 0; j < 4; ++j) { p[n][j] = __expf(acc_s[n][j] - mn); psum += p[n][j]; }
        psum += __shfl_xor(psum, 16);
        psum += __shfl_xor(psum, 32);
        l = l * fac + psum;
        m = mn;
        #pragma unroll
        for (int dt = 0; dt < 4; ++dt)
            #pragma unroll
            for (int j = 0; j < 4; ++j) acc_o[dt][j] *= fac;

        #pragma unroll
        for (int n = 0; n < 4; ++n) {
            f16x4 pk;
            #pragma unroll
            for (int j = 0; j < 4; ++j) pk[j] = (_Float16)p[n][j];
            *reinterpret_cast<f16x4*>(&Ps[swz(wv * 16 + fr, 2 * n + (g >> 1)) + (g & 1) * 4]) = pk;
        }

        #pragma unroll
        for (int kf = 0; kf < 2; ++kf) {
            const f16x8 pf = *reinterpret_cast<const f16x8*>(&Ps[swz(wv * 16 + fr, kf * 4 + g)]);
            #pragma unroll
            for (int dt = 0; dt < 4; ++dt) {
                const f16x8 vf = *reinterpret_cast<const f16x8*>(&Vts[swz(dt * 16 + fr, kf * 4 + g)]);
                acc_o[dt] = __builtin_amdgcn_mfma_f32_16x16x32_f16(vf, pf, acc_o[dt], 0, 0, 0);
            }
        }
    }

    const float rl = 1.f / l;
    unsigned short* ob = &o[(size_t)(b * kL + qg_row) * kC + h * kDH];
    #pragma unroll
    for (int dt = 0; dt < 4; ++dt) {
        f16x4 pk;
        #pragma unroll
        for (int j = 0; j < 4; ++j) pk[j] = (_Float16)(acc_o[dt][j] * rl);
        *reinterpret_cast<f16x4*>(&ob[dt * 16 + g * 4]) = pk;
    }
}

// ---------------------------------------------------------------------------
// 6. Final tanh (in place on d_out)
// ---------------------------------------------------------------------------
__global__ __launch_bounds__(256) void tanh_kernel(float* __restrict__ x)
{
    const size_t i = ((size_t)blockIdx.x * 256 + threadIdx.x) * 4;
    float4 v = *reinterpret_cast<float4*>(&x[i]);
    v.x = tanhf(v.x); v.y = tanhf(v.y); v.z = tanhf(v.z); v.w = tanhf(v.w);
    *reinterpret_cast<float4*>(&x[i]) = v;
}

// ---------------------------------------------------------------------------
extern "C" void kernel_launch(void* const* d_in, const int* in_sizes, int n_in,
                              void* d_out, int out_size, void* d_ws, size_t ws_size,
                              hipStream_t stream)
{
    (void)in_sizes; (void)n_in; (void)out_size; (void)ws_size;
    const float* obs    = (const float*)d_in[0];
    const float* act    = (const float*)d_in[1];
    const float* rew    = (const float*)d_in[2];
    const float* obs_W  = (const float*)d_in[3];
    const float* obs_b  = (const float*)d_in[4];
    const float* act_W  = (const float*)d_in[5];
    const float* act_b  = (const float*)d_in[6];
    const float* rew_W  = (const float*)d_in[7];
    const float* rew_b  = (const float*)d_in[8];
    const float* tr_W   = (const float*)d_in[9];
    const float* tr_b   = (const float*)d_in[10];
    const float* bn_g   = (const float*)d_in[11];
    const float* bn_b   = (const float*)d_in[12];
    const float* ln1_w  = (const float*)d_in[13];
    const float* ln1_b  = (const float*)d_in[14];
    const float* qkv_W  = (const float*)d_in[15];
    const float* qkv_b  = (const float*)d_in[16];
    const float* out_W  = (const float*)d_in[17];
    const float* out_b  = (const float*)d_in[18];
    const float* ln2_w  = (const float*)d_in[19];
    const float* ln2_b  = (const float*)d_in[20];
    const float* fc_W   = (const float*)d_in[21];
    const float* fc_b   = (const float*)d_in[22];
    const float* pj_W   = (const float*)d_in[23];
    const float* pj_b   = (const float*)d_in[24];

    float* x  = (float*)d_out;                     // fp32 residual stream
    float* ws = (float*)d_ws;
    float* tm   = ws;                              // 64
    float* tv   = ws + 64;                         // 64
    unsigned short* wbuf  = (unsigned short*)(ws + 128);  // 12.58M f16 weights
    unsigned short* h_hf  = wbuf + 12582912;       // 2048*1024
    unsigned short* ao_hf = h_hf + (size_t)kRows * kC;    // 2048*1024
    unsigned short* ff_hf = ao_hf + (size_t)kRows * kC;   // 2048*4096
    unsigned short* qk_hf = ff_hf + (size_t)kRows * kFF;  // 2048*2048
    unsigned short* vt_hf = qk_hf + (size_t)kRows * 2 * kC; // 2*16*64*1024
    unsigned short* qWT = wbuf;                    // [3072][1024]
    unsigned short* oWT = qWT + 3 * kC * kC;       // [1024][1024]
    unsigned short* fWT = oWT + kC * kC;           // [4096][1024]
    unsigned short* pWT = fWT + kC * kFF;          // [1024][4096]

    tran_stats_kernel<<<kOBS, 256, 0, stream>>>(obs, tm, tv);
    encode_kernel<<<kRows, 256, 0, stream>>>(obs, act, rew,
        obs_W, obs_b, act_W, act_b, rew_W, rew_b, tr_W, tr_b, bn_g, bn_b, tm, tv, x);

    for (int lyr = 0; lyr < kNL; ++lyr) {
        const float* qW = qkv_W + (size_t)lyr * kC * 3 * kC;
        const float* qB = qkv_b + (size_t)lyr * 3 * kC;
        const float* oW = out_W + (size_t)lyr * kC * kC;
        const float* oB = out_b + (size_t)lyr * kC;
        const float* fW = fc_W + (size_t)lyr * kC * kFF;
        const float* fB = fc_b + (size_t)lyr * kFF;
        const float* pW = pj_W + (size_t)lyr * kFF * kC;
        const float* pB = pj_b + (size_t)lyr * kC;

        convert_layer_kernel<<<3072, 256, 0, stream>>>(
            qW, oW, fW, pW, qWT, oWT, fWT, pWT);

        ln_kernel<<<kRows, 256, 0, stream>>>(x, ln1_w + lyr * kC, ln1_b + lyr * kC, h_hf);
        gemm_f16_kernel<0,0,2><<<dim3(3 * kC / 128, kRows / 128), 256, 0, stream>>>(
            h_hf, qWT, qB, nullptr, qk_hf, vt_hf, kRows, 3 * kC, kC);
        attn_mfma_kernel<<<dim3(512), 256, 0, stream>>>(qk_hf, vt_hf, ao_hf);
        // out projection: split-K=4, atomic accumulate into residual stream
        gemm_f16_kernel<0,0,4><<<dim3(kC / 128, kRows / 128, 4), 256, 0, stream>>>(
            ao_hf, oWT, oB, x, nullptr, nullptr, kRows, kC, kC);
        ln_kernel<<<kRows, 256, 0, stream>>>(x, ln2_w + lyr * kC, ln2_b + lyr * kC, h_hf);
        gemm_f16_kernel<1,0,1><<<dim3(kFF / 128, kRows / 128), 256, 0, stream>>>(
            h_hf, fWT, fB, nullptr, ff_hf, nullptr, kRows, kFF, kC);
        // pj projection: split-K=4, atomic accumulate into residual stream
        gemm_f16_kernel<0,0,4><<<dim3(kC / 128, kRows / 128, 4), 256, 0, stream>>>(
            ff_hf, pWT, pB, x, nullptr, nullptr, kRows, kC, kFF);
    }
    tanh_kernel<<<kRows * kC / 1024, 256, 0, stream>>>(x);
}

// Round 10
// 682.775 us; speedup vs baseline: 8.8736x; 1.0044x over previous
//
#include <hip/hip_runtime.h>
#include <hip/hip_bf16.h>
#include <math.h>

// Problem constants
constexpr int kB   = 2;
constexpr int kL   = 1024;
constexpr int kOBS = 64;
constexpr int kACT = 16;
constexpr int kC   = 1024;
constexpr int kH   = 16;
constexpr int kDH  = 64;
constexpr int kFF  = 4096;
constexpr int kNL  = 4;
constexpr int kRows = kB * kL;          // 2048
constexpr int kOE = 512, kAE = 256, kRE = 128, kTE = 128;

typedef _Float16 f16x8 __attribute__((ext_vector_type(8)));
typedef _Float16 f16x4 __attribute__((ext_vector_type(4)));
typedef float    f32x4 __attribute__((ext_vector_type(4)));

__device__ __forceinline__ unsigned short f2h(float x) {
    return __builtin_bit_cast(unsigned short, (_Float16)x);
}
__device__ __forceinline__ void gload_lds16(const void* g, void* l) {
    __builtin_amdgcn_global_load_lds(
        (const __attribute__((address_space(1))) unsigned int*)g,
        (__attribute__((address_space(3))) unsigned int*)l, 16, 0, 0);
}

// ---------------------------------------------------------------------------
// 1. Transition batchnorm stats
// ---------------------------------------------------------------------------
__global__ __launch_bounds__(256) void tran_stats_kernel(
    const float* __restrict__ obs, float* __restrict__ tm, float* __restrict__ tv)
{
    const int f = blockIdx.x;
    const int tid = threadIdx.x;
    float sum = 0.f, sq = 0.f;
    for (int r = tid; r < kRows; r += 256) {
        const int t = r & (kL - 1);
        float d = 0.f;
        if (t > 0) {
            const float cur  = obs[(size_t)r * kOBS + f];
            const float prev = obs[(size_t)(r - 1) * kOBS + f];
            d = cur - prev;
        }
        sum += d; sq += d * d;
    }
    for (int off = 32; off > 0; off >>= 1) {
        sum += __shfl_down(sum, off);
        sq  += __shfl_down(sq, off);
    }
    __shared__ float sa[4], sb[4];
    if ((tid & 63) == 0) { sa[tid >> 6] = sum; sb[tid >> 6] = sq; }
    __syncthreads();
    if (tid == 0) {
        const float ts = sa[0] + sa[1] + sa[2] + sa[3];
        const float tq = sb[0] + sb[1] + sb[2] + sb[3];
        const float m = ts / (float)kRows;
        tm[f] = m;
        tv[f] = tq / (float)kRows - m * m;
    }
}

// ---------------------------------------------------------------------------
// 2. Encoder (writes fp32 residual stream)
// ---------------------------------------------------------------------------
__global__ __launch_bounds__(256) void encode_kernel(
    const float* __restrict__ obs, const float* __restrict__ act, const float* __restrict__ rew,
    const float* __restrict__ obs_W, const float* __restrict__ obs_b,
    const float* __restrict__ act_W, const float* __restrict__ act_b,
    const float* __restrict__ rew_W, const float* __restrict__ rew_b,
    const float* __restrict__ tr_W,  const float* __restrict__ tr_b,
    const float* __restrict__ bn_g,  const float* __restrict__ bn_b,
    const float* __restrict__ tm,    const float* __restrict__ tv,
    float* __restrict__ enc)
{
    const int row = blockIdx.x;
    const int t = row & (kL - 1);
    const int tid = threadIdx.x;
    __shared__ float s_obs2[kOBS];
    __shared__ float s_tran[kOBS];
    __shared__ float s_act[kACT];
    __shared__ float s_rew;
    if (tid < kOBS) {
        const float cur  = obs[(size_t)row * kOBS + tid];
        const float prev = (t > 0) ? obs[(size_t)(row - 1) * kOBS + tid] : cur;
        s_obs2[tid] = prev;
        const float tr = cur - prev;
        s_tran[tid] = (tr - tm[tid]) * rsqrtf(tv[tid] + 1e-5f) * bn_g[tid] + bn_b[tid];
    } else if (tid < kOBS + kACT) {
        s_act[tid - kOBS] = act[(size_t)row * kACT + (tid - kOBS)];
    } else if (tid == kOBS + kACT) {
        s_rew = rew[row];
    }
    __syncthreads();
    float* er = enc + (size_t)row * kC;
    #pragma unroll
    for (int s = 0; s < 4; ++s) {
        const int c = tid + s * 256;
        float v;
        if (c < kOE) {
            v = obs_b[c];
            #pragma unroll
            for (int k = 0; k < kOBS; ++k) v += s_obs2[k] * obs_W[k * kOE + c];
        } else if (c < kOE + kAE) {
            const int cc = c - kOE;
            v = act_b[cc];
            #pragma unroll
            for (int k = 0; k < kACT; ++k) v += s_act[k] * act_W[k * kAE + cc];
        } else if (c < kOE + kAE + kRE) {
            const int cc = c - (kOE + kAE);
            v = s_rew * rew_W[cc] + rew_b[cc];
        } else {
            const int cc = c - (kOE + kAE + kRE);
            v = tr_b[cc];
            #pragma unroll
            for (int k = 0; k < kOBS; ++k) v += s_tran[k] * tr_W[k * kTE + cc];
        }
        er[c] = v;
    }
}

// ---------------------------------------------------------------------------
// 3. LayerNorm: fp32 in -> fp16 out
// ---------------------------------------------------------------------------
__global__ __launch_bounds__(256) void ln_kernel(
    const float* __restrict__ x, const float* __restrict__ w,
    const float* __restrict__ b, unsigned short* __restrict__ out)
{
    const int row = blockIdx.x;
    const int tid = threadIdx.x;
    const float4 xv = *reinterpret_cast<const float4*>(&x[(size_t)row * kC + tid * 4]);
    float s = xv.x + xv.y + xv.z + xv.w;
    float q = xv.x * xv.x + xv.y * xv.y + xv.z * xv.z + xv.w * xv.w;
    for (int off = 32; off > 0; off >>= 1) {
        s += __shfl_down(s, off);
        q += __shfl_down(q, off);
    }
    __shared__ float sa[4], sb[4];
    if ((tid & 63) == 0) { sa[tid >> 6] = s; sb[tid >> 6] = q; }
    __syncthreads();
    const float ts = sa[0] + sa[1] + sa[2] + sa[3];
    const float tq = sb[0] + sb[1] + sb[2] + sb[3];
    const float mean = ts * (1.f / kC);
    const float var  = tq * (1.f / kC) - mean * mean;
    const float rstd = rsqrtf(var + 1e-5f);
    const float4 wv = *reinterpret_cast<const float4*>(&w[tid * 4]);
    const float4 bv = *reinterpret_cast<const float4*>(&b[tid * 4]);
    ushort4 o;
    o.x = f2h((xv.x - mean) * rstd * wv.x + bv.x);
    o.y = f2h((xv.y - mean) * rstd * wv.y + bv.y);
    o.z = f2h((xv.z - mean) * rstd * wv.z + bv.z);
    o.w = f2h((xv.w - mean) * rstd * wv.w + bv.w);
    *reinterpret_cast<ushort4*>(&out[(size_t)row * kC + tid * 4]) = o;
}

// ---------------------------------------------------------------------------
// 4a. Per-layer weight convert+transpose, single launch (3072 tiles).
// ---------------------------------------------------------------------------
__device__ __forceinline__ void convT_tile(
    const float* __restrict__ W, unsigned short* __restrict__ WT,
    int K, int N, int k0, int n0, int tid)
{
    __shared__ unsigned short t[64][68];
    const int r = tid >> 4, c4 = (tid & 15) * 4;
    #pragma unroll
    for (int s = 0; s < 4; ++s) {
        const int rr = r + s * 16;
        const float4 v = *reinterpret_cast<const float4*>(&W[(size_t)(k0 + rr) * N + n0 + c4]);
        t[rr][c4 + 0] = f2h(v.x);
        t[rr][c4 + 1] = f2h(v.y);
        t[rr][c4 + 2] = f2h(v.z);
        t[rr][c4 + 3] = f2h(v.w);
    }
    __syncthreads();
    #pragma unroll
    for (int s = 0; s < 4; ++s) {
        const int rn = r + s * 16;
        ushort4 o;
        o.x = t[c4 + 0][rn];
        o.y = t[c4 + 1][rn];
        o.z = t[c4 + 2][rn];
        o.w = t[c4 + 3][rn];
        *reinterpret_cast<ushort4*>(&WT[(size_t)(n0 + rn) * K + k0 + c4]) = o;
    }
}

__global__ __launch_bounds__(256) void convert_layer_kernel(
    const float* __restrict__ qW, const float* __restrict__ oW,
    const float* __restrict__ fW, const float* __restrict__ pW,
    unsigned short* __restrict__ qWT, unsigned short* __restrict__ oWT,
    unsigned short* __restrict__ fWT, unsigned short* __restrict__ pWT)
{
    int bid = blockIdx.x;                    // 3072 tiles total
    const int tid = threadIdx.x;
    if (bid < 768)  {                        // qW: K=1024, N=3072 (48 n-tiles)
        convT_tile(qW, qWT, 1024, 3072, (bid / 48) * 64, (bid % 48) * 64, tid);
    } else if (bid < 1024) {                 // oW: 1024x1024 (16)
        bid -= 768;
        convT_tile(oW, oWT, 1024, 1024, (bid / 16) * 64, (bid % 16) * 64, tid);
    } else if (bid < 2048) {                 // fW: K=1024, N=4096 (64)
        bid -= 1024;
        convT_tile(fW, fWT, 1024, 4096, (bid / 64) * 64, (bid % 64) * 64, tid);
    } else {                                 // pW: K=4096, N=1024 (16)
        bid -= 2048;
        convT_tile(pW, pWT, 4096, 1024, (bid / 16) * 64, (bid % 16) * 64, tid);
    }
}

// ---------------------------------------------------------------------------
// 4b. fp16 MFMA GEMM, BK=64, double-buffered with READ-THEN-STAGE order:
//     per K-step, ds_read ALL fragments of buf[cur] first (vmcnt==0 after the
//     barrier, so no compiler-inserted vmem wait precedes them), THEN issue
//     the next-tile global_load_lds, THEN MFMA (covers load latency), then
//     one __syncthreads. 8-slot XOR swizzle + XCD-aware block swizzle.
//     MODE 0: f32 out (+RES/RELU). MODE 1: f16 out. MODE 2: qkv special.
//     MODE 4: split-K atomicAdd into Cf.
// ---------------------------------------------------------------------------
template<int RELU, int RES, int MODE>
__global__ __launch_bounds__(256) void gemm_f16_kernel(
    const unsigned short* __restrict__ A,   // [M][K] fp16
    const unsigned short* __restrict__ BT,  // [N][K] fp16
    const float* __restrict__ bias,
    float* __restrict__ Cf, unsigned short* __restrict__ Ch,
    unsigned short* __restrict__ Cv,
    int M, int N, int K)
{
    __shared__ __align__(16) unsigned short As[2][128 * 64];   // 32 KB
    __shared__ __align__(16) unsigned short Bs[2][128 * 64];   // 32 KB
    const int tid = threadIdx.x;
    const int lane = tid & 63;
    const int wv   = tid >> 6;
    const int wr = wv >> 1, wc = wv & 1;

    // XCD-aware swizzle (bijective: all our grids are divisible by 8)
    const int nx  = gridDim.x;
    const int nxy = gridDim.x * gridDim.y;
    int flat = blockIdx.x + nx * blockIdx.y + nxy * blockIdx.z;
    const int cpx = (nxy * gridDim.z) >> 3;
    flat = (flat & 7) * cpx + (flat >> 3);
    const int bx = flat % nx;
    const int by = (flat / nx) % gridDim.y;
    const int bz = flat / nxy;

    const int bm = by * 128;
    const int bn = bx * 128;
    const int ksz  = K / gridDim.z;
    const int kbeg = bz * ksz;
    const int kend = kbeg + ksz;

    // staging: row stride 64 halves = 128 B = 8 slots of 16 B.
    const int grow = tid >> 3;                  // 0..31
    const int gs   = (tid & 7) ^ (grow & 7);    // pre-swizzled global slot

    const int fr = lane & 15;
    const int kb = lane >> 4;                   // 0..3

    auto stage = [&](int k0, int buf) {
        #pragma unroll
        for (int c = 0; c < 4; ++c) {
            gload_lds16(A  + (size_t)(bm + c * 32 + grow) * K + k0 + gs * 8,
                        (char*)&As[buf][0] + c * 4096 + wv * 1024);
            gload_lds16(BT + (size_t)(bn + c * 32 + grow) * K + k0 + gs * 8,
                        (char*)&Bs[buf][0] + c * 4096 + wv * 1024);
        }
    };

    f32x4 acc[4][4] = {};

    stage(kbeg, 0);
    __syncthreads();                 // prologue loads resident (vmcnt -> 0)
    int cur = 0;
    for (int k0 = kbeg; k0 < kend; k0 += 64) {
        // 1) ds_read all fragments of buf[cur] FIRST — vmcnt is 0 here, so no
        //    conservative vmem wait can be inserted before these reads.
        f16x8 a[2][4], b[2][4];
        #pragma unroll
        for (int kf = 0; kf < 2; ++kf) {
            #pragma unroll
            for (int m = 0; m < 4; ++m) {
                const int row = wr * 64 + m * 16 + fr;
                a[kf][m] = *reinterpret_cast<const f16x8*>(
                    &As[cur][row * 64 + (((kf * 4 + kb) ^ (row & 7)) * 8)]);
            }
            #pragma unroll
            for (int n = 0; n < 4; ++n) {
                const int row = wc * 64 + n * 16 + fr;
                b[kf][n] = *reinterpret_cast<const f16x8*>(
                    &Bs[cur][row * 64 + (((kf * 4 + kb) ^ (row & 7)) * 8)]);
            }
        }
        // 2) issue next-tile stage; its latency hides under the MFMAs below
        if (k0 + 64 < kend) stage(k0 + 64, cur ^ 1);
        // 3) MFMA (waits only on lgkmcnt for the ds_reads)
        #pragma unroll
        for (int kf = 0; kf < 2; ++kf)
            #pragma unroll
            for (int m = 0; m < 4; ++m)
                #pragma unroll
                for (int n = 0; n < 4; ++n)
                    acc[m][n] = __builtin_amdgcn_mfma_f32_16x16x32_f16(
                        a[kf][m], b[kf][n], acc[m][n], 0, 0, 0);

        __syncthreads();             // drains stage; next buf ready
        cur ^= 1;
    }

    const int fq = lane >> 4;
    if (MODE == 4) {                 // split-K atomic accumulate (RES via x)
        const bool addb = (bz == 0);
        #pragma unroll
        for (int n = 0; n < 4; ++n) {
            const int c = bn + wc * 64 + n * 16 + fr;
            const float bv = addb ? bias[c] : 0.f;
            #pragma unroll
            for (int m = 0; m < 4; ++m) {
                #pragma unroll
                for (int j = 0; j < 4; ++j) {
                    const int r = bm + wr * 64 + m * 16 + fq * 4 + j;
                    atomicAdd(&Cf[(size_t)r * N + c], acc[m][n][j] + bv);
                }
            }
        }
        return;
    }
    if (MODE == 2) {
        if (bn < 2 * kC) {          // Q,K region -> qk f16 [row][2048]
            #pragma unroll
            for (int n = 0; n < 4; ++n) {
                const int c = bn + wc * 64 + n * 16 + fr;
                const float bv = bias[c];
                #pragma unroll
                for (int m = 0; m < 4; ++m) {
                    #pragma unroll
                    for (int j = 0; j < 4; ++j) {
                        const int r = bm + wr * 64 + m * 16 + fq * 4 + j;
                        Ch[(size_t)r * (2 * kC) + c] = f2h(acc[m][n][j] + bv);
                    }
                }
            }
        } else {                    // V region -> vt[b][h][d][t] f16
            #pragma unroll
            for (int n = 0; n < 4; ++n) {
                const int c  = bn + wc * 64 + n * 16 + fr;
                const int cc = c - 2 * kC;
                const int hh = cc >> 6, dd = cc & 63;
                const float bv = bias[c];
                #pragma unroll
                for (int m = 0; m < 4; ++m) {
                    const int rr = bm + wr * 64 + m * 16 + fq * 4;
                    const int bb = rr >> 10, t0 = rr & 1023;
                    f16x4 pk;
                    #pragma unroll
                    for (int j = 0; j < 4; ++j) pk[j] = (_Float16)(acc[m][n][j] + bv);
                    *reinterpret_cast<f16x4*>(
                        &Cv[((size_t)(bb * kH + hh) * kDH + dd) * kL + t0]) = pk;
                }
            }
        }
        return;
    }
    #pragma unroll
    for (int n = 0; n < 4; ++n) {
        const int c = bn + wc * 64 + n * 16 + fr;
        const float bv = bias[c];
        #pragma unroll
        for (int m = 0; m < 4; ++m) {
            #pragma unroll
            for (int j = 0; j < 4; ++j) {
                const int r = bm + wr * 64 + m * 16 + fq * 4 + j;
                float v = acc[m][n][j] + bv;
                if (RES)  v += Cf[(size_t)r * N + c];
                if (RELU) v = fmaxf(v, 0.f);
                if (MODE == 1) Ch[(size_t)r * N + c] = f2h(v);
                else           Cf[(size_t)r * N + c] = v;
            }
        }
    }
}

// ---------------------------------------------------------------------------
// 5. MFMA flash attention (unchanged)
// ---------------------------------------------------------------------------
__device__ __forceinline__ int swz(int row, int slot) {
    return row * 64 + ((slot ^ (row & 7)) * 8);   // ushort index, 16B-aligned
}

__global__ __launch_bounds__(256) void attn_mfma_kernel(
    const unsigned short* __restrict__ qk,   // [2048][2048] f16 (Q | K)
    const unsigned short* __restrict__ vt,   // [2][16][64][1024] f16  V^T
    unsigned short* __restrict__ o)          // [2048][1024] f16
{
    const int bid = blockIdx.x;            // 512 blocks
    const int bh  = bid & 31;
    const int qb  = ((bid >> 5) + bh) & 15;   // shear: balance causal work
    const int b   = bh >> 4;
    const int h   = bh & 15;
    const int tid  = threadIdx.x;
    const int lane = tid & 63;
    const int wv   = tid >> 6;
    const int fr = lane & 15;              // q index within wave
    const int g  = lane >> 4;              // k-group

    __shared__ __align__(16) unsigned short Qs[64 * 64];
    __shared__ __align__(16) unsigned short Ks[64 * 64];
    __shared__ __align__(16) unsigned short Vts[64 * 64];
    __shared__ __align__(16) unsigned short Ps[64 * 64];

    const int qlo = qb * 64;

    {
        const int r = tid >> 2, s = tid & 3;
        const unsigned short* qg = &qk[(size_t)(b * kL + qlo + r) * (2 * kC) + h * kDH];
        f16x8 v0 = *reinterpret_cast<const f16x8*>(&qg[s * 8]);
        f16x8 v1 = *reinterpret_cast<const f16x8*>(&qg[(s + 4) * 8]);
        #pragma unroll
        for (int i = 0; i < 8; ++i) { v0[i] *= (_Float16)0.125f; v1[i] *= (_Float16)0.125f; }
        *reinterpret_cast<f16x8*>(&Qs[swz(r, s)])     = v0;
        *reinterpret_cast<f16x8*>(&Qs[swz(r, s + 4)]) = v1;
    }
    __syncthreads();

    f16x8 qfrag[2];
    #pragma unroll
    for (int kf = 0; kf < 2; ++kf)
        qfrag[kf] = *reinterpret_cast<const f16x8*>(&Qs[swz(wv * 16 + fr, kf * 4 + g)]);

    float m = -INFINITY, l = 0.f;
    f32x4 acc_o[4] = {};
    const int qg_row = qlo + wv * 16 + fr;

    for (int k0 = 0; k0 <= qlo; k0 += 64) {
        __syncthreads();
        {
            const int r = tid >> 2, s = tid & 3;
            const unsigned short* kg = &qk[(size_t)(b * kL + k0 + r) * (2 * kC) + kC + h * kDH];
            *reinterpret_cast<f16x8*>(&Ks[swz(r, s)])     = *reinterpret_cast<const f16x8*>(&kg[s * 8]);
            *reinterpret_cast<f16x8*>(&Ks[swz(r, s + 4)]) = *reinterpret_cast<const f16x8*>(&kg[(s + 4) * 8]);
            const unsigned short* vg = &vt[((size_t)(b * kH + h) * kDH + r) * kL + k0];
            *reinterpret_cast<f16x8*>(&Vts[swz(r, s)])     = *reinterpret_cast<const f16x8*>(&vg[s * 8]);
            *reinterpret_cast<f16x8*>(&Vts[swz(r, s + 4)]) = *reinterpret_cast<const f16x8*>(&vg[(s + 4) * 8]);
        }
        __syncthreads();

        f32x4 acc_s[4] = {};
        #pragma unroll
        for (int kf = 0; kf < 2; ++kf) {
            const f16x8 qf = qfrag[kf];
            #pragma unroll
            for (int n = 0; n < 4; ++n) {
                const f16x8 kfr = *reinterpret_cast<const f16x8*>(&Ks[swz(n * 16 + fr, kf * 4 + g)]);
                acc_s[n] = __builtin_amdgcn_mfma_f32_16x16x32_f16(kfr, qf, acc_s[n], 0, 0, 0);
            }
        }

        if (k0 == qlo) {
            #pragma unroll
            for (int n = 0; n < 4; ++n)
                #pragma unroll
                for (int j = 0; j < 4; ++j)
                    if (k0 + n * 16 + g * 4 + j > qg_row) acc_s[n][j] = -INFINITY;
        }

        float mx = -INFINITY;
        #pragma unroll
        for (int n = 0; n < 4; ++n)
            #pragma unroll
            for (int j = 0; j < 4; ++j) mx = fmaxf(mx, acc_s[n][j]);
        mx = fmaxf(mx, __shfl_xor(mx, 16));
        mx = fmaxf(mx, __shfl_xor(mx, 32));
        const float mn  = fmaxf(m, mx);
        const float fac = __expf(m - mn);
        float p[4][4];
        float psum = 0.f;
        #pragma unroll
        for (int n = 0; n < 4; ++n)
            #pragma unroll
            for (int j = 0; j < 4; ++j) { p[n][j] = __expf(acc_s[n][j] - mn); psum += p[n][j]; }
        psum += __shfl_xor(psum, 16);
        psum += __shfl_xor(psum, 32);
        l = l * fac + psum;
        m = mn;
        #pragma unroll
        for (int dt = 0; dt < 4; ++dt)
            #pragma unroll
            for (int j = 0; j < 4; ++j) acc_o[dt][j] *= fac;

        #pragma unroll
        for (int n = 0; n < 4; ++n) {
            f16x4 pk;
            #pragma unroll
            for (int j = 0; j < 4; ++j) pk[j] = (_Float16)p[n][j];
            *reinterpret_cast<f16x4*>(&Ps[swz(wv * 16 + fr, 2 * n + (g >> 1)) + (g & 1) * 4]) = pk;
        }

        #pragma unroll
        for (int kf = 0; kf < 2; ++kf) {
            const f16x8 pf = *reinterpret_cast<const f16x8*>(&Ps[swz(wv * 16 + fr, kf * 4 + g)]);
            #pragma unroll
            for (int dt = 0; dt < 4; ++dt) {
                const f16x8 vf = *reinterpret_cast<const f16x8*>(&Vts[swz(dt * 16 + fr, kf * 4 + g)]);
                acc_o[dt] = __builtin_amdgcn_mfma_f32_16x16x32_f16(vf, pf, acc_o[dt], 0, 0, 0);
            }
        }
    }

    const float rl = 1.f / l;
    unsigned short* ob = &o[(size_t)(b * kL + qg_row) * kC + h * kDH];
    #pragma unroll
    for (int dt = 0; dt < 4; ++dt) {
        f16x4 pk;
        #pragma unroll
        for (int j = 0; j < 4; ++j) pk[j] = (_Float16)(acc_o[dt][j] * rl);
        *reinterpret_cast<f16x4*>(&ob[dt * 16 + g * 4]) = pk;
    }
}

// ---------------------------------------------------------------------------
// 6. Final tanh (in place on d_out)
// ---------------------------------------------------------------------------
__global__ __launch_bounds__(256) void tanh_kernel(float* __restrict__ x)
{
    const size_t i = ((size_t)blockIdx.x * 256 + threadIdx.x) * 4;
    float4 v = *reinterpret_cast<float4*>(&x[i]);
    v.x = tanhf(v.x); v.y = tanhf(v.y); v.z = tanhf(v.z); v.w = tanhf(v.w);
    *reinterpret_cast<float4*>(&x[i]) = v;
}

// ---------------------------------------------------------------------------
extern "C" void kernel_launch(void* const* d_in, const int* in_sizes, int n_in,
                              void* d_out, int out_size, void* d_ws, size_t ws_size,
                              hipStream_t stream)
{
    (void)in_sizes; (void)n_in; (void)out_size; (void)ws_size;
    const float* obs    = (const float*)d_in[0];
    const float* act    = (const float*)d_in[1];
    const float* rew    = (const float*)d_in[2];
    const float* obs_W  = (const float*)d_in[3];
    const float* obs_b  = (const float*)d_in[4];
    const float* act_W  = (const float*)d_in[5];
    const float* act_b  = (const float*)d_in[6];
    const float* rew_W  = (const float*)d_in[7];
    const float* rew_b  = (const float*)d_in[8];
    const float* tr_W   = (const float*)d_in[9];
    const float* tr_b   = (const float*)d_in[10];
    const float* bn_g   = (const float*)d_in[11];
    const float* bn_b   = (const float*)d_in[12];
    const float* ln1_w  = (const float*)d_in[13];
    const float* ln1_b  = (const float*)d_in[14];
    const float* qkv_W  = (const float*)d_in[15];
    const float* qkv_b  = (const float*)d_in[16];
    const float* out_W  = (const float*)d_in[17];
    const float* out_b  = (const float*)d_in[18];
    const float* ln2_w  = (const float*)d_in[19];
    const float* ln2_b  = (const float*)d_in[20];
    const float* fc_W   = (const float*)d_in[21];
    const float* fc_b   = (const float*)d_in[22];
    const float* pj_W   = (const float*)d_in[23];
    const float* pj_b   = (const float*)d_in[24];

    float* x  = (float*)d_out;                     // fp32 residual stream
    float* ws = (float*)d_ws;
    float* tm   = ws;                              // 64
    float* tv   = ws + 64;                         // 64
    unsigned short* wbuf  = (unsigned short*)(ws + 128);  // 12.58M f16 weights
    unsigned short* h_hf  = wbuf + 12582912;       // 2048*1024
    unsigned short* ao_hf = h_hf + (size_t)kRows * kC;    // 2048*1024
    unsigned short* ff_hf = ao_hf + (size_t)kRows * kC;   // 2048*4096
    unsigned short* qk_hf = ff_hf + (size_t)kRows * kFF;  // 2048*2048
    unsigned short* vt_hf = qk_hf + (size_t)kRows * 2 * kC; // 2*16*64*1024
    unsigned short* qWT = wbuf;                    // [3072][1024]
    unsigned short* oWT = qWT + 3 * kC * kC;       // [1024][1024]
    unsigned short* fWT = oWT + kC * kC;           // [4096][1024]
    unsigned short* pWT = fWT + kC * kFF;          // [1024][4096]

    tran_stats_kernel<<<kOBS, 256, 0, stream>>>(obs, tm, tv);
    encode_kernel<<<kRows, 256, 0, stream>>>(obs, act, rew,
        obs_W, obs_b, act_W, act_b, rew_W, rew_b, tr_W, tr_b, bn_g, bn_b, tm, tv, x);

    for (int lyr = 0; lyr < kNL; ++lyr) {
        const float* qW = qkv_W + (size_t)lyr * kC * 3 * kC;
        const float* qB = qkv_b + (size_t)lyr * 3 * kC;
        const float* oW = out_W + (size_t)lyr * kC * kC;
        const float* oB = out_b + (size_t)lyr * kC;
        const float* fW = fc_W + (size_t)lyr * kC * kFF;
        const float* fB = fc_b + (size_t)lyr * kFF;
        const float* pW = pj_W + (size_t)lyr * kFF * kC;
        const float* pB = pj_b + (size_t)lyr * kC;

        convert_layer_kernel<<<3072, 256, 0, stream>>>(
            qW, oW, fW, pW, qWT, oWT, fWT, pWT);

        ln_kernel<<<kRows, 256, 0, stream>>>(x, ln1_w + lyr * kC, ln1_b + lyr * kC, h_hf);
        gemm_f16_kernel<0,0,2><<<dim3(3 * kC / 128, kRows / 128), 256, 0, stream>>>(
            h_hf, qWT, qB, nullptr, qk_hf, vt_hf, kRows, 3 * kC, kC);
        attn_mfma_kernel<<<dim3(512), 256, 0, stream>>>(qk_hf, vt_hf, ao_hf);
        // out projection: split-K=4, atomic accumulate into residual stream
        gemm_f16_kernel<0,0,4><<<dim3(kC / 128, kRows / 128, 4), 256, 0, stream>>>(
            ao_hf, oWT, oB, x, nullptr, nullptr, kRows, kC, kC);
        ln_kernel<<<kRows, 256, 0, stream>>>(x, ln2_w + lyr * kC, ln2_b + lyr * kC, h_hf);
        gemm_f16_kernel<1,0,1><<<dim3(kFF / 128, kRows / 128), 256, 0, stream>>>(
            h_hf, fWT, fB, nullptr, ff_hf, nullptr, kRows, kFF, kC);
        // pj projection: split-K=4, atomic accumulate into residual stream
        gemm_f16_kernel<0,0,4><<<dim3(kC / 128, kRows / 128, 4), 256, 0, stream>>>(
            ff_hf, pWT, pB, x, nullptr, nullptr, kRows, kC, kFF);
    }
    tanh_kernel<<<kRows * kC / 1024, 256, 0, stream>>>(x);
}